// Round 9
// baseline (31492.227 us; speedup 1.0000x reference)
//
#include <hip/hip_runtime.h>
#include <math.h>

typedef unsigned int u32;
typedef unsigned short u16;

// ---------------- xW0[8192][512] = X @ g0_Wih^T + bih + bhh (f32) ----------------
__global__ void k_xw0(float* __restrict__ XW,
                      const float* __restrict__ inp, const float* __restrict__ tag,
                      const float* __restrict__ sent, const float* __restrict__ W,
                      const float* __restrict__ bih, const float* __restrict__ bhh) {
  int gid = blockIdx.x * 256 + threadIdx.x;     // 8192*512
  int row = gid >> 9, col = gid & 511;
  int b = row >> 8, s = row & 255;
  const float* w = W + (size_t)col * 1024;
  float acc = bih[col] + bhh[col];
  if (s == 0) {
    for (int k = 0; k < 1024; ++k) acc = fmaf(sent[k], w[k], acc);
  } else {
    const float* p1 = inp + (size_t)(b * 255 + s - 1) * 768;
    for (int k = 0; k < 768; ++k) acc = fmaf(p1[k], w[k], acc);
    const float* p2 = tag + (size_t)(b * 255 + s - 1) * 256;
    for (int k = 0; k < 256; ++k) acc = fmaf(p2[k], w[768 + k], acc);
  }
  XW[(size_t)row * 512 + col] = acc;
}

// ---------------- g-RNN scan, f32, in place over XW ----------------
__global__ __launch_bounds__(512) void k_gscan(float* __restrict__ XW,
                                               const float* __restrict__ Whh,
                                               const int* __restrict__ mask, int layer) {
  __shared__ float hs[512];
  const int t = threadIdx.x, b = blockIdx.x;
  hs[t] = 0.f;
  __syncthreads();
  for (int s = 0; s < 256; ++s) {
    size_t row = (size_t)(b * 256 + s);
    float acc = XW[row * 512 + t];
    const float* w = Whh + (size_t)t * 512;
#pragma unroll 4
    for (int k = 0; k < 512; ++k) acc = fmaf(w[k], hs[k], acc);
    float hnew = tanhf(acc);
    float ov = hnew;
    if (layer) ov *= (s == 0) ? 1.f : (float)mask[b * 255 + s - 1];
    XW[row * 512 + t] = ov;        // own element; prior read done
    __syncthreads();
    hs[t] = hnew;                  // carry is UNMASKED h
    __syncthreads();
  }
}

// ---------------- xW1 = Y0 @ g1_Wih^T + b (f32) ----------------
__global__ void k_lin0(float* __restrict__ outp, const float* __restrict__ A,
                       const float* __restrict__ W,
                       const float* __restrict__ b1, const float* __restrict__ b2) {
  int gid = blockIdx.x * 256 + threadIdx.x;     // 8192*512
  int row = gid >> 9, col = gid & 511;
  const float* a = A + (size_t)row * 512;
  const float* w = W + (size_t)col * 512;
  float acc = b1[col] + b2[col];
  for (int k = 0; k < 512; ++k) acc = fmaf(a[k], w[k], acc);
  outp[(size_t)row * 512 + col] = acc;
}

// ---------------- tag heads: elu(GS @ W^T + b) -> f32 staging buffer ----------------
// stage[0..2097152) = head, stage[2097152..4194304) = dep
__global__ void k_heads(float* __restrict__ stage, const float* __restrict__ GS,
                        const float* __restrict__ htW, const float* __restrict__ htb,
                        const float* __restrict__ dtW, const float* __restrict__ dtb) {
  int gid = blockIdx.x * 256 + threadIdx.x;     // 8192*512
  int row = gid >> 9, col = gid & 511;
  const float* a = GS + (size_t)row * 512;
  const float* w; float acc;
  if (col < 256) { w = htW + (size_t)col * 512; acc = htb[col]; }
  else           { w = dtW + (size_t)(col - 256) * 512; acc = dtb[col - 256]; }
  for (int k = 0; k < 512; ++k) acc = fmaf(a[k], w[k], acc);
  float e = acc > 0.f ? acc : (expf(acc) - 1.f);
  if (col < 256) stage[(size_t)row * 256 + col] = e;
  else           stage[2097152 + (size_t)row * 256 + (col - 256)] = e;
}

// ---------------- fused edge scan: 25 steps, 8 rows/block, states in LDS f32 --------
__global__ __launch_bounds__(512, 1) void k_edge(
    const float* __restrict__ GS,
    const float* __restrict__ e0Whh, const float* __restrict__ e0Wih,
    const float* __restrict__ e0bi, const float* __restrict__ e0bh,
    const float* __restrict__ e1Wih, const float* __restrict__ e1Whh,
    const float* __restrict__ e1bi, const float* __restrict__ e1bh,
    const float* __restrict__ clsW, const float* __restrict__ clsb,
    float* __restrict__ abuf)
{
  __shared__ float h0[8][512];
  __shared__ float h1[8][512];
  __shared__ float red[64];
  __shared__ float xsh[8];
  const int t = threadIdx.x;
  const int wv = t >> 6, lane = t & 63;
  const int r0 = blockIdx.x * 8;
#pragma unroll
  for (int r = 0; r < 8; ++r) {
    h0[r][t] = GS[(size_t)(r0 + r) * 512 + t];
    h1[r][t] = 0.f;
  }
  if (t < 8) xsh[t] = 1.0f;
  const float b0 = e0bi[t] + e0bh[t];
  const float b1 = e1bi[t] + e1bh[t];
  const float wih = e0Wih[t];
  const float cw = clsW[t];
  const float cb = clsb[0];
  const float* wr0 = e0Whh + (size_t)t * 512;
  const float* wr1 = e1Wih + (size_t)t * 512;
  const float* wr2 = e1Whh + (size_t)t * 512;
  __syncthreads();

  for (int st = 0; st < 25; ++st) {
    // h0' = tanh(xe*e0_Wih[t] + b0 + h0 @ e0_Whh^T)
    float acc[8];
#pragma unroll
    for (int r = 0; r < 8; ++r) acc[r] = fmaf(xsh[r], wih, b0);
    for (int k = 0; k < 512; k += 4) {
      float4 w4 = *(const float4*)(wr0 + k);
#pragma unroll
      for (int r = 0; r < 8; ++r) {
        float4 hv = *(const float4*)(&h0[r][k]);
        acc[r] = fmaf(w4.x, hv.x, acc[r]);
        acc[r] = fmaf(w4.y, hv.y, acc[r]);
        acc[r] = fmaf(w4.z, hv.z, acc[r]);
        acc[r] = fmaf(w4.w, hv.w, acc[r]);
      }
    }
    float h0v[8];
#pragma unroll
    for (int r = 0; r < 8; ++r) h0v[r] = tanhf(acc[r]);
    __syncthreads();
#pragma unroll
    for (int r = 0; r < 8; ++r) h0[r][t] = h0v[r];
    __syncthreads();

    // h1' = tanh(b1 + h0' @ e1_Wih^T + h1 @ e1_Whh^T)
#pragma unroll
    for (int r = 0; r < 8; ++r) acc[r] = b1;
    for (int k = 0; k < 512; k += 4) {
      float4 w4 = *(const float4*)(wr1 + k);
#pragma unroll
      for (int r = 0; r < 8; ++r) {
        float4 hv = *(const float4*)(&h0[r][k]);
        acc[r] = fmaf(w4.x, hv.x, acc[r]);
        acc[r] = fmaf(w4.y, hv.y, acc[r]);
        acc[r] = fmaf(w4.z, hv.z, acc[r]);
        acc[r] = fmaf(w4.w, hv.w, acc[r]);
      }
    }
    for (int k = 0; k < 512; k += 4) {
      float4 w4 = *(const float4*)(wr2 + k);
#pragma unroll
      for (int r = 0; r < 8; ++r) {
        float4 hv = *(const float4*)(&h1[r][k]);
        acc[r] = fmaf(w4.x, hv.x, acc[r]);
        acc[r] = fmaf(w4.y, hv.y, acc[r]);
        acc[r] = fmaf(w4.z, hv.z, acc[r]);
        acc[r] = fmaf(w4.w, hv.w, acc[r]);
      }
    }
    float h1v[8];
#pragma unroll
    for (int r = 0; r < 8; ++r) h1v[r] = tanhf(acc[r]);
    __syncthreads();
#pragma unroll
    for (int r = 0; r < 8; ++r) h1[r][t] = h1v[r];

    // pred[r] = cls_b + sum_t h1v[r]*cls_W[t]
#pragma unroll
    for (int r = 0; r < 8; ++r) {
      float p = h1v[r] * cw;
      p += __shfl_xor(p, 1);  p += __shfl_xor(p, 2);  p += __shfl_xor(p, 4);
      p += __shfl_xor(p, 8);  p += __shfl_xor(p, 16); p += __shfl_xor(p, 32);
      if (lane == 0) red[wv * 8 + r] = p;
    }
    __syncthreads();
    if (t < 8) {
      float s = cb;
#pragma unroll
      for (int q = 0; q < 8; ++q) s += red[q * 8 + t];
      xsh[t] = s;
      abuf[(size_t)(r0 + t) * 26 + st + 1] = s;
    }
    __syncthreads();
  }
}

// ---------------- small helpers ----------------
__global__ void k_ainit(float* abuf) {
  int idx = blockIdx.x * 256 + threadIdx.x;     // 8192
  if (idx < 8192) abuf[(size_t)idx * 26] = 1.0f;
}
__global__ void k_arc(float* __restrict__ outp, const float* __restrict__ abuf) {
  int idx = blockIdx.x * 256 + threadIdx.x;     // 2097152
  int j = idx & 255, i = (idx >> 8) & 255, b = idx >> 16;
  int k = i - j;
  outp[idx] = (k >= 0 && k <= 25) ? abuf[(size_t)(b * 256 + i) * 26 + k] : 0.0f;
}
__global__ void k_copy(float4* __restrict__ dst, const float4* __restrict__ src) {
  size_t i = (size_t)blockIdx.x * 256 + threadIdx.x;   // 1048576 float4
  dst[i] = src[i];
}
__global__ void k_diag(float* __restrict__ outp, float code, int n) {
  int idx = blockIdx.x * 256 + threadIdx.x;
  if (idx < n) outp[idx] = (idx == 0) ? code : 0.0f;
}

extern "C" void kernel_launch(void* const* d_in, const int* in_sizes, int n_in,
                              void* d_out, int out_size, void* d_ws, size_t ws_size,
                              hipStream_t stream) {
  // dict-order size signature (confirmed round 7)
  static const int SZ[26] = {6266880, 2088960, 8160, 1024, 524288, 262144, 512, 512,
                             262144, 262144, 512, 512, 512, 262144, 512, 512,
                             262144, 262144, 512, 512, 512, 1, 131072, 256, 131072, 256};
  float diag_code = 0.0f;
  if (n_in != 26) diag_code = 4096.0f + (float)n_in;
  else {
    for (int j = 0; j < 26; ++j)
      if (in_sizes[j] != SZ[j]) { diag_code = 2048.0f + (float)j; break; }
  }
  // Workspace: H0 [0,16M) f32; ABUF [16M, +852K)
  const size_t NEED = (size_t)(16u << 20) + 851968;
  if (ws_size < NEED && diag_code == 0.0f) diag_code = 8192.0f;
  if (diag_code != 0.0f) {
    k_diag<<<(out_size + 255) / 256, 256, 0, stream>>>((float*)d_out, diag_code, out_size);
    return;
  }

  const float* inp  = (const float*)d_in[0];
  const float* tag  = (const float*)d_in[1];
  const int*   mask = (const int*)d_in[2];
  const float* sent = (const float*)d_in[3];
  const float* g0_Wih = (const float*)d_in[4];
  const float* g0_Whh = (const float*)d_in[5];
  const float* g0_bih = (const float*)d_in[6];
  const float* g0_bhh = (const float*)d_in[7];
  const float* g1_Wih = (const float*)d_in[8];
  const float* g1_Whh = (const float*)d_in[9];
  const float* g1_bih = (const float*)d_in[10];
  const float* g1_bhh = (const float*)d_in[11];
  const float* e0_Wih = (const float*)d_in[12];
  const float* e0_Whh = (const float*)d_in[13];
  const float* e0_bih = (const float*)d_in[14];
  const float* e0_bhh = (const float*)d_in[15];
  const float* e1_Wih = (const float*)d_in[16];
  const float* e1_Whh = (const float*)d_in[17];
  const float* e1_bih = (const float*)d_in[18];
  const float* e1_bhh = (const float*)d_in[19];
  const float* cls_W  = (const float*)d_in[20];
  const float* cls_b  = (const float*)d_in[21];
  const float* ht_W   = (const float*)d_in[22];
  const float* ht_b   = (const float*)d_in[23];
  const float* dt_W   = (const float*)d_in[24];
  const float* dt_b   = (const float*)d_in[25];

  float* out  = (float*)d_out;              // [arc 2097152 | head 2097152 | dep 2097152]
  char*  ws   = (char*)d_ws;
  float* H0   = (float*)(ws);               // 16 MB scratch
  float* ABUF = (float*)(ws + (16u << 20)); // [8192][26] f32
  float* GS   = out;                        // GS [8192][512] f32 lives in d_out (16 MB)

  // 1) xW0 -> H0 ; 2) layer-0 scan in place (H0 = Y0)
  k_xw0<<<16384, 256, 0, stream>>>(H0, inp, tag, sent, g0_Wih, g0_bih, g0_bhh);
  k_gscan<<<32, 512, 0, stream>>>(H0, g0_Whh, mask, 0);
  // 3) xW1 = Y0 @ g1^T -> d_out ; 4) layer-1 scan in place -> GS (masked)
  k_lin0<<<16384, 256, 0, stream>>>(GS, H0, g1_Wih, g1_bih, g1_bhh);
  k_gscan<<<32, 512, 0, stream>>>(GS, g1_Whh, mask, 1);
  // 5) tag heads from GS -> staged in H0 (Y0 dead)
  k_heads<<<16384, 256, 0, stream>>>(H0, GS, ht_W, ht_b, dt_W, dt_b);
  // 6) edge scan from GS -> ABUF
  k_ainit<<<32, 256, 0, stream>>>(ABUF);
  k_edge<<<1024, 512, 0, stream>>>(GS, e0_Whh, e0_Wih, e0_bih, e0_bhh,
                                   e1_Wih, e1_Whh, e1_bih, e1_bhh,
                                   cls_W, cls_b, ABUF);
  // 7) arc -> out[0..2M) (GS dead) ; 8) heads H0 -> out[2M..6M)
  k_arc<<<8192, 256, 0, stream>>>(out, ABUF);
  k_copy<<<4096, 256, 0, stream>>>((float4*)(out + 2097152), (const float4*)H0);
}

// Round 10
// 24252.202 us; speedup vs baseline: 1.2985x; 1.2985x over previous
//
#include <hip/hip_runtime.h>
#include <math.h>

typedef unsigned int u32;
typedef unsigned short u16;
typedef __attribute__((ext_vector_type(8))) short short8;
typedef __attribute__((ext_vector_type(4))) float f32x4;

__device__ inline u16 f2bf(float f) {
  u32 u = __float_as_uint(f);
  return (u16)((u + 0x7fffu + ((u >> 16) & 1u)) >> 16);
}
__device__ inline float fast_tanh(float x) {
  x = fminf(9.0f, fmaxf(-9.0f, x));
  float e = __builtin_amdgcn_exp2f(x * 2.8853900817779268f);
  return (e - 1.0f) * __builtin_amdgcn_rcpf(e + 1.0f);
}

// ---------------- xW0[8192][512] = X @ g0_Wih^T + bih + bhh (f32) ----------------
__global__ void k_xw0(float* __restrict__ XW,
                      const float* __restrict__ inp, const float* __restrict__ tag,
                      const float* __restrict__ sent, const float* __restrict__ W,
                      const float* __restrict__ bih, const float* __restrict__ bhh) {
  int gid = blockIdx.x * 256 + threadIdx.x;     // 8192*512
  int row = gid >> 9, col = gid & 511;
  int b = row >> 8, s = row & 255;
  const float* w = W + (size_t)col * 1024;
  float acc = bih[col] + bhh[col];
  if (s == 0) {
    for (int k = 0; k < 1024; ++k) acc = fmaf(sent[k], w[k], acc);
  } else {
    const float* p1 = inp + (size_t)(b * 255 + s - 1) * 768;
    for (int k = 0; k < 768; ++k) acc = fmaf(p1[k], w[k], acc);
    const float* p2 = tag + (size_t)(b * 255 + s - 1) * 256;
    for (int k = 0; k < 256; ++k) acc = fmaf(p2[k], w[768 + k], acc);
  }
  XW[(size_t)row * 512 + col] = acc;
}

// ---------------- g-RNN scan, f32, in place over XW ----------------
__global__ __launch_bounds__(512) void k_gscan(float* __restrict__ XW,
                                               const float* __restrict__ Whh,
                                               const int* __restrict__ mask, int layer) {
  __shared__ float hs[512];
  const int t = threadIdx.x, b = blockIdx.x;
  hs[t] = 0.f;
  __syncthreads();
  for (int s = 0; s < 256; ++s) {
    size_t row = (size_t)(b * 256 + s);
    float acc = XW[row * 512 + t];
    const float* w = Whh + (size_t)t * 512;
#pragma unroll 4
    for (int k = 0; k < 512; ++k) acc = fmaf(w[k], hs[k], acc);
    float hnew = tanhf(acc);
    float ov = hnew;
    if (layer) ov *= (s == 0) ? 1.f : (float)mask[b * 255 + s - 1];
    XW[row * 512 + t] = ov;
    __syncthreads();
    hs[t] = hnew;
    __syncthreads();
  }
}

// ---------------- xW1 = Y0 @ g1_Wih^T + b (f32) ----------------
__global__ void k_lin0(float* __restrict__ outp, const float* __restrict__ A,
                       const float* __restrict__ W,
                       const float* __restrict__ b1, const float* __restrict__ b2) {
  int gid = blockIdx.x * 256 + threadIdx.x;     // 8192*512
  int row = gid >> 9, col = gid & 511;
  const float* a = A + (size_t)row * 512;
  const float* w = W + (size_t)col * 512;
  float acc = b1[col] + b2[col];
  for (int k = 0; k < 512; ++k) acc = fmaf(a[k], w[k], acc);
  outp[(size_t)row * 512 + col] = acc;
}

// ---------------- tag heads: elu(GS @ W^T + b) -> f32 staging ----------------
__global__ void k_heads(float* __restrict__ stage, const float* __restrict__ GS,
                        const float* __restrict__ htW, const float* __restrict__ htb,
                        const float* __restrict__ dtW, const float* __restrict__ dtb) {
  int gid = blockIdx.x * 256 + threadIdx.x;     // 8192*512
  int row = gid >> 9, col = gid & 511;
  const float* a = GS + (size_t)row * 512;
  const float* w; float acc;
  if (col < 256) { w = htW + (size_t)col * 512; acc = htb[col]; }
  else           { w = dtW + (size_t)(col - 256) * 512; acc = dtb[col - 256]; }
  for (int k = 0; k < 512; ++k) acc = fmaf(a[k], w[k], acc);
  float e = acc > 0.f ? acc : (expf(acc) - 1.f);
  if (col < 256) stage[(size_t)row * 256 + col] = e;
  else           stage[2097152 + (size_t)row * 256 + (col - 256)] = e;
}

// ---------------- f32 -> bf16 weight convert ----------------
__global__ void k_cvt(u16* __restrict__ dst, const float* __restrict__ src) {
  int i = blockIdx.x * 256 + threadIdx.x;       // 262144
  dst[i] = f2bf(src[i]);
}

// -------- MFMA edge scan: 16 rows/block, 512 blocks, bf16 states in swizzled LDS --------
// Per step: h0' = tanh(xe*e0Wih + b0 + h0 @ W0^T); h1' = tanh(b1 + h0' @ W1^T + h1 @ W2^T);
// pred = cls_b + h1' . cls_W  (f32 carry xsh).
__global__ __launch_bounds__(512, 1) void k_edge_mfma(
    const float* __restrict__ GS,
    const u16* __restrict__ W0b, const u16* __restrict__ W1b, const u16* __restrict__ W2b,
    const float* __restrict__ e0Wih,
    const float* __restrict__ e0bi, const float* __restrict__ e0bh,
    const float* __restrict__ e1bi, const float* __restrict__ e1bh,
    const float* __restrict__ clsW, const float* __restrict__ clsb,
    float* __restrict__ abuf)
{
  __shared__ u16 h0b[16 * 512];   // [row][granule^(row&7)] bf16, 16B granules
  __shared__ u16 h1b[16 * 512];
  __shared__ float red[8][16];
  __shared__ float xsh[16];
  const int t = threadIdx.x;
  const int w = t >> 6, lane = t & 63;
  const int lrow = lane & 15, lk = lane >> 4;
  const int r0 = blockIdx.x * 16;
  const int c0 = w * 64;

  // initial state: h0 = GS rows, h1 = 0 (swizzled bf16)
  {
    int r = t >> 5;
    const float* src = GS + (size_t)(r0 + r) * 512 + (t & 31) * 16;
#pragma unroll
    for (int g = 0; g < 2; ++g) {
      u16 tmp[8];
#pragma unroll
      for (int j = 0; j < 8; ++j) tmp[j] = f2bf(src[g * 8 + j]);
      int sg = ((t & 31) * 2 + g) ^ (r & 7);
      *(short8*)(&h0b[r * 512 + sg * 8]) = *(const short8*)tmp;
      short8 z = {0, 0, 0, 0, 0, 0, 0, 0};
      *(short8*)(&h1b[r * 512 + sg * 8]) = z;
    }
  }
  if (t < 16) xsh[t] = 1.0f;

  float b0c[4], b1c[4], wihc[4], cwc[4];
  size_t wb[4];
#pragma unroll
  for (int n = 0; n < 4; ++n) {
    int col = c0 + n * 16 + lrow;
    b0c[n] = e0bi[col] + e0bh[col];
    b1c[n] = e1bi[col] + e1bh[col];
    wihc[n] = e0Wih[col];
    cwc[n] = clsW[col];
    wb[n] = (size_t)col * 512 + lk * 8;
  }
  const float cb = clsb[0];
  __syncthreads();

  f32x4 zero4 = {0.f, 0.f, 0.f, 0.f};
  const int r3 = lrow & 7;

  for (int st = 0; st < 25; ++st) {
    // ---- phase 1: acc = h0 @ W0^T ----
    f32x4 acc[4];
#pragma unroll
    for (int n = 0; n < 4; ++n) acc[n] = zero4;
#pragma unroll
    for (int kk = 0; kk < 16; ++kk) {
      short8 a = *(const short8*)(&h0b[lrow * 512 + (((kk * 4 + lk) ^ r3) * 8)]);
#pragma unroll
      for (int n = 0; n < 4; ++n) {
        short8 bf = *(const short8*)(W0b + wb[n] + kk * 32);
        acc[n] = __builtin_amdgcn_mfma_f32_16x16x32_bf16(a, bf, acc[n], 0, 0, 0);
      }
    }
    float hv[4][4];
#pragma unroll
    for (int n = 0; n < 4; ++n)
#pragma unroll
      for (int rr = 0; rr < 4; ++rr) {
        int row = lk * 4 + rr;
        hv[n][rr] = fast_tanh(acc[n][rr] + b0c[n] + xsh[row] * wihc[n]);
      }
    __syncthreads();                      // all K-loop reads of h0b done
#pragma unroll
    for (int n = 0; n < 4; ++n)
#pragma unroll
      for (int rr = 0; rr < 4; ++rr) {
        int row = lk * 4 + rr;
        int col = c0 + n * 16 + lrow;
        int sg = (col >> 3) ^ (row & 7);
        h0b[row * 512 + sg * 8 + (col & 7)] = f2bf(hv[n][rr]);
      }
    __syncthreads();                      // h0' visible

    // ---- phase 2: acc = h0' @ W1^T + h1 @ W2^T ----
#pragma unroll
    for (int n = 0; n < 4; ++n) acc[n] = zero4;
#pragma unroll
    for (int kk = 0; kk < 16; ++kk) {
      short8 a = *(const short8*)(&h0b[lrow * 512 + (((kk * 4 + lk) ^ r3) * 8)]);
#pragma unroll
      for (int n = 0; n < 4; ++n) {
        short8 bf = *(const short8*)(W1b + wb[n] + kk * 32);
        acc[n] = __builtin_amdgcn_mfma_f32_16x16x32_bf16(a, bf, acc[n], 0, 0, 0);
      }
    }
#pragma unroll
    for (int kk = 0; kk < 16; ++kk) {
      short8 a = *(const short8*)(&h1b[lrow * 512 + (((kk * 4 + lk) ^ r3) * 8)]);
#pragma unroll
      for (int n = 0; n < 4; ++n) {
        short8 bf = *(const short8*)(W2b + wb[n] + kk * 32);
        acc[n] = __builtin_amdgcn_mfma_f32_16x16x32_bf16(a, bf, acc[n], 0, 0, 0);
      }
    }
#pragma unroll
    for (int n = 0; n < 4; ++n)
#pragma unroll
      for (int rr = 0; rr < 4; ++rr)
        hv[n][rr] = fast_tanh(acc[n][rr] + b1c[n]);
    __syncthreads();                      // all K-loop reads of h1b done
#pragma unroll
    for (int n = 0; n < 4; ++n)
#pragma unroll
      for (int rr = 0; rr < 4; ++rr) {
        int row = lk * 4 + rr;
        int col = c0 + n * 16 + lrow;
        int sg = (col >> 3) ^ (row & 7);
        h1b[row * 512 + sg * 8 + (col & 7)] = f2bf(hv[n][rr]);
      }
    // pred partials: p[row] = sum_cols h1'*clsW
#pragma unroll
    for (int rr = 0; rr < 4; ++rr) {
      float p = 0.f;
#pragma unroll
      for (int n = 0; n < 4; ++n) p += hv[n][rr] * cwc[n];
      p += __shfl_xor(p, 1); p += __shfl_xor(p, 2);
      p += __shfl_xor(p, 4); p += __shfl_xor(p, 8);
      if (lrow == 0) red[w][lk * 4 + rr] = p;
    }
    __syncthreads();
    if (t < 16) {
      float s = cb;
#pragma unroll
      for (int q = 0; q < 8; ++q) s += red[q][t];
      xsh[t] = s;
      abuf[(size_t)(r0 + t) * 26 + st + 1] = s;
    }
    __syncthreads();
  }
}

// ---------------- small helpers ----------------
__global__ void k_ainit(float* abuf) {
  int idx = blockIdx.x * 256 + threadIdx.x;     // 8192
  if (idx < 8192) abuf[(size_t)idx * 26] = 1.0f;
}
__global__ void k_arc(float* __restrict__ outp, const float* __restrict__ abuf) {
  int idx = blockIdx.x * 256 + threadIdx.x;     // 2097152
  int j = idx & 255, i = (idx >> 8) & 255, b = idx >> 16;
  int k = i - j;
  outp[idx] = (k >= 0 && k <= 25) ? abuf[(size_t)(b * 256 + i) * 26 + k] : 0.0f;
}
__global__ void k_copy(float4* __restrict__ dst, const float4* __restrict__ src) {
  size_t i = (size_t)blockIdx.x * 256 + threadIdx.x;   // 1048576 float4
  dst[i] = src[i];
}
__global__ void k_diag(float* __restrict__ outp, float code, int n) {
  int idx = blockIdx.x * 256 + threadIdx.x;
  if (idx < n) outp[idx] = (idx == 0) ? code : 0.0f;
}

extern "C" void kernel_launch(void* const* d_in, const int* in_sizes, int n_in,
                              void* d_out, int out_size, void* d_ws, size_t ws_size,
                              hipStream_t stream) {
  static const int SZ[26] = {6266880, 2088960, 8160, 1024, 524288, 262144, 512, 512,
                             262144, 262144, 512, 512, 512, 262144, 512, 512,
                             262144, 262144, 512, 512, 512, 1, 131072, 256, 131072, 256};
  float diag_code = 0.0f;
  if (n_in != 26) diag_code = 4096.0f + (float)n_in;
  else {
    for (int j = 0; j < 26; ++j)
      if (in_sizes[j] != SZ[j]) { diag_code = 2048.0f + (float)j; break; }
  }
  const size_t NEED = (size_t)(19u << 20);
  if (ws_size < NEED && diag_code == 0.0f) diag_code = 8192.0f;
  if (diag_code != 0.0f) {
    k_diag<<<(out_size + 255) / 256, 256, 0, stream>>>((float*)d_out, diag_code, out_size);
    return;
  }

  const float* inp  = (const float*)d_in[0];
  const float* tag  = (const float*)d_in[1];
  const int*   mask = (const int*)d_in[2];
  const float* sent = (const float*)d_in[3];
  const float* g0_Wih = (const float*)d_in[4];
  const float* g0_Whh = (const float*)d_in[5];
  const float* g0_bih = (const float*)d_in[6];
  const float* g0_bhh = (const float*)d_in[7];
  const float* g1_Wih = (const float*)d_in[8];
  const float* g1_Whh = (const float*)d_in[9];
  const float* g1_bih = (const float*)d_in[10];
  const float* g1_bhh = (const float*)d_in[11];
  const float* e0_Wih = (const float*)d_in[12];
  const float* e0_Whh = (const float*)d_in[13];
  const float* e0_bih = (const float*)d_in[14];
  const float* e0_bhh = (const float*)d_in[15];
  const float* e1_Wih = (const float*)d_in[16];
  const float* e1_Whh = (const float*)d_in[17];
  const float* e1_bih = (const float*)d_in[18];
  const float* e1_bhh = (const float*)d_in[19];
  const float* cls_W  = (const float*)d_in[20];
  const float* cls_b  = (const float*)d_in[21];
  const float* ht_W   = (const float*)d_in[22];
  const float* ht_b   = (const float*)d_in[23];
  const float* dt_W   = (const float*)d_in[24];
  const float* dt_b   = (const float*)d_in[25];

  float* out  = (float*)d_out;              // [arc | head | dep] x 2097152 f32
  char*  ws   = (char*)d_ws;
  float* H0   = (float*)(ws);               // 16 MB scratch / heads staging
  float* ABUF = (float*)(ws + (16u << 20)); // [8192][26] f32
  u16*  W0b   = (u16*)(ws + (17u << 20));   // bf16 e0_Whh
  u16*  W1b   = (u16*)(ws + (17u << 20) + (512u << 10));   // bf16 e1_Wih
  u16*  W2b   = (u16*)(ws + (18u << 20));   // bf16 e1_Whh
  float* GS   = out;                        // GS [8192][512] f32 in d_out

  // bf16 weight conversion for the MFMA edge scan
  k_cvt<<<1024, 256, 0, stream>>>(W0b, e0_Whh);
  k_cvt<<<1024, 256, 0, stream>>>(W1b, e1_Wih);
  k_cvt<<<1024, 256, 0, stream>>>(W2b, e1_Whh);

  // 1) xW0 -> H0 ; 2) layer-0 scan in place (H0 = Y0)
  k_xw0<<<16384, 256, 0, stream>>>(H0, inp, tag, sent, g0_Wih, g0_bih, g0_bhh);
  k_gscan<<<32, 512, 0, stream>>>(H0, g0_Whh, mask, 0);
  // 3) xW1 -> d_out ; 4) layer-1 scan in place -> GS (masked)
  k_lin0<<<16384, 256, 0, stream>>>(GS, H0, g1_Wih, g1_bih, g1_bhh);
  k_gscan<<<32, 512, 0, stream>>>(GS, g1_Whh, mask, 1);
  // 5) tag heads from GS -> staged in H0
  k_heads<<<16384, 256, 0, stream>>>(H0, GS, ht_W, ht_b, dt_W, dt_b);
  // 6) MFMA edge scan -> ABUF
  k_ainit<<<32, 256, 0, stream>>>(ABUF);
  k_edge_mfma<<<512, 512, 0, stream>>>(GS, W0b, W1b, W2b, e0_Wih,
                                       e0_bih, e0_bhh, e1_bih, e1_bhh,
                                       cls_W, cls_b, ABUF);
  // 7) arc -> out[0..2M) ; 8) heads -> out[2M..6M)
  k_arc<<<8192, 256, 0, stream>>>(out, ABUF);
  k_copy<<<4096, 256, 0, stream>>>((float4*)(out + 2097152), (const float4*)H0);
}

// Round 12
// 13395.169 us; speedup vs baseline: 2.3510x; 1.8105x over previous
//
#include <hip/hip_runtime.h>
#include <math.h>

typedef unsigned int u32;
typedef unsigned short u16;
typedef __attribute__((ext_vector_type(8))) short short8;
typedef __attribute__((ext_vector_type(4))) float f32x4;

__device__ inline u16 f2bf(float f) {
  u32 u = __float_as_uint(f);
  return (u16)((u + 0x7fffu + ((u >> 16) & 1u)) >> 16);
}
__device__ inline float fast_tanh(float x) {
  x = fminf(9.0f, fmaxf(-9.0f, x));
  float e = __builtin_amdgcn_exp2f(x * 2.8853900817779268f);
  return (e - 1.0f) * __builtin_amdgcn_rcpf(e + 1.0f);
}

// ---------------- xW0[8192][512] = X @ g0_Wih^T + bih + bhh (f32) ----------------
__global__ void k_xw0(float* __restrict__ XW,
                      const float* __restrict__ inp, const float* __restrict__ tag,
                      const float* __restrict__ sent, const float* __restrict__ W,
                      const float* __restrict__ bih, const float* __restrict__ bhh) {
  int gid = blockIdx.x * 256 + threadIdx.x;     // 8192*512
  int row = gid >> 9, col = gid & 511;
  int b = row >> 8, s = row & 255;
  const float* w = W + (size_t)col * 1024;
  float acc = bih[col] + bhh[col];
  if (s == 0) {
    for (int k = 0; k < 1024; ++k) acc = fmaf(sent[k], w[k], acc);
  } else {
    const float* p1 = inp + (size_t)(b * 255 + s - 1) * 768;
    for (int k = 0; k < 768; ++k) acc = fmaf(p1[k], w[k], acc);
    const float* p2 = tag + (size_t)(b * 255 + s - 1) * 256;
    for (int k = 0; k < 256; ++k) acc = fmaf(p2[k], w[768 + k], acc);
  }
  XW[(size_t)row * 512 + col] = acc;
}

// ---- transpose Whh (f32 [512][512]) -> WT[k][t] = Whh[t][k] ----
__global__ void k_transw(float* __restrict__ outp, const float* __restrict__ src) {
  int idx = blockIdx.x * 256 + threadIdx.x;     // 262144
  int k = idx & 511, t = idx >> 9;
  outp[(size_t)k * 512 + t] = src[(size_t)t * 512 + k];
}

// ------- g-RNN scan, FULL f32: 216 weights/thread in VGPR + 296 rows streamed coalesced -------
// WT layout [k][t]; thread t owns output column t. Math identical to naive k-seq scan.
__global__ __launch_bounds__(512) void k_gscan_hyb(
    float* __restrict__ XW, const float* __restrict__ WT,
    const int* __restrict__ mask, int layer)
{
  __shared__ float hs[512];
  const int t = threadIdx.x, b = blockIdx.x;
  float wreg[216];
#pragma unroll
  for (int k = 0; k < 216; ++k) wreg[k] = WT[(size_t)k * 512 + t];
  hs[t] = 0.f;
  __syncthreads();
  const float4* h4 = (const float4*)hs;
#pragma unroll 1
  for (int s = 0; s < 256; ++s) {
    float acc = XW[(size_t)(b * 256 + s) * 512 + t];
    // resident part k = 0..215 (54 float4 groups)
#pragma unroll
    for (int j = 0; j < 54; ++j) {
      float4 hv = h4[j];
      acc = fmaf(wreg[j * 4 + 0], hv.x, acc);
      acc = fmaf(wreg[j * 4 + 1], hv.y, acc);
      acc = fmaf(wreg[j * 4 + 2], hv.z, acc);
      acc = fmaf(wreg[j * 4 + 3], hv.w, acc);
    }
    // streamed part k = 216..511, coalesced (lane t reads WT[k][t])
#pragma unroll 8
    for (int k = 216; k < 512; ++k)
      acc = fmaf(WT[(size_t)k * 512 + t], hs[k], acc);
    float hnew = tanhf(acc);
    float ov = hnew;
    if (layer) ov *= (s == 0) ? 1.f : (float)mask[b * 255 + s - 1];
    XW[(size_t)(b * 256 + s) * 512 + t] = ov;
    __syncthreads();
    hs[t] = hnew;
    __syncthreads();
  }
}

// ---------------- xW1 = Y0 @ g1_Wih^T + b (f32) ----------------
__global__ void k_lin0(float* __restrict__ outp, const float* __restrict__ A,
                       const float* __restrict__ W,
                       const float* __restrict__ b1, const float* __restrict__ b2) {
  int gid = blockIdx.x * 256 + threadIdx.x;     // 8192*512
  int row = gid >> 9, col = gid & 511;
  const float* a = A + (size_t)row * 512;
  const float* w = W + (size_t)col * 512;
  float acc = b1[col] + b2[col];
  for (int k = 0; k < 512; ++k) acc = fmaf(a[k], w[k], acc);
  outp[(size_t)row * 512 + col] = acc;
}

// ---------------- tag heads: elu(GS @ W^T + b) -> f32 staging ----------------
__global__ void k_heads(float* __restrict__ stage, const float* __restrict__ GS,
                        const float* __restrict__ htW, const float* __restrict__ htb,
                        const float* __restrict__ dtW, const float* __restrict__ dtb) {
  int gid = blockIdx.x * 256 + threadIdx.x;     // 8192*512
  int row = gid >> 9, col = gid & 511;
  const float* a = GS + (size_t)row * 512;
  const float* w; float acc;
  if (col < 256) { w = htW + (size_t)col * 512; acc = htb[col]; }
  else           { w = dtW + (size_t)(col - 256) * 512; acc = dtb[col - 256]; }
  for (int k = 0; k < 512; ++k) acc = fmaf(a[k], w[k], acc);
  float e = acc > 0.f ? acc : (expf(acc) - 1.f);
  if (col < 256) stage[(size_t)row * 256 + col] = e;
  else           stage[2097152 + (size_t)row * 256 + (col - 256)] = e;
}

// ---------------- f32 -> bf16 weight convert ----------------
__global__ void k_cvt(u16* __restrict__ dst, const float* __restrict__ src) {
  int i = blockIdx.x * 256 + threadIdx.x;       // 262144
  dst[i] = f2bf(src[i]);
}

// -------- MFMA edge scan (verified round 10) --------
__global__ __launch_bounds__(512, 1) void k_edge_mfma(
    const float* __restrict__ GS,
    const u16* __restrict__ W0b, const u16* __restrict__ W1b, const u16* __restrict__ W2b,
    const float* __restrict__ e0Wih,
    const float* __restrict__ e0bi, const float* __restrict__ e0bh,
    const float* __restrict__ e1bi, const float* __restrict__ e1bh,
    const float* __restrict__ clsW, const float* __restrict__ clsb,
    float* __restrict__ abuf)
{
  __shared__ u16 h0b[16 * 512];
  __shared__ u16 h1b[16 * 512];
  __shared__ float red[8][16];
  __shared__ float xsh[16];
  const int t = threadIdx.x;
  const int w = t >> 6, lane = t & 63;
  const int lrow = lane & 15, lk = lane >> 4;
  const int r0 = blockIdx.x * 16;
  const int c0 = w * 64;

  {
    int r = t >> 5;
    const float* src = GS + (size_t)(r0 + r) * 512 + (t & 31) * 16;
#pragma unroll
    for (int g = 0; g < 2; ++g) {
      u16 tmp[8];
#pragma unroll
      for (int j = 0; j < 8; ++j) tmp[j] = f2bf(src[g * 8 + j]);
      int sg = ((t & 31) * 2 + g) ^ (r & 7);
      *(short8*)(&h0b[r * 512 + sg * 8]) = *(const short8*)tmp;
      short8 z = {0, 0, 0, 0, 0, 0, 0, 0};
      *(short8*)(&h1b[r * 512 + sg * 8]) = z;
    }
  }
  if (t < 16) xsh[t] = 1.0f;

  float b0c[4], b1c[4], wihc[4], cwc[4];
  size_t wb[4];
#pragma unroll
  for (int n = 0; n < 4; ++n) {
    int col = c0 + n * 16 + lrow;
    b0c[n] = e0bi[col] + e0bh[col];
    b1c[n] = e1bi[col] + e1bh[col];
    wihc[n] = e0Wih[col];
    cwc[n] = clsW[col];
    wb[n] = (size_t)col * 512 + lk * 8;
  }
  const float cb = clsb[0];
  __syncthreads();

  f32x4 zero4 = {0.f, 0.f, 0.f, 0.f};
  const int r3 = lrow & 7;

  for (int st = 0; st < 25; ++st) {
    f32x4 acc[4];
#pragma unroll
    for (int n = 0; n < 4; ++n) acc[n] = zero4;
#pragma unroll
    for (int kk = 0; kk < 16; ++kk) {
      short8 a = *(const short8*)(&h0b[lrow * 512 + (((kk * 4 + lk) ^ r3) * 8)]);
#pragma unroll
      for (int n = 0; n < 4; ++n) {
        short8 bf = *(const short8*)(W0b + wb[n] + kk * 32);
        acc[n] = __builtin_amdgcn_mfma_f32_16x16x32_bf16(a, bf, acc[n], 0, 0, 0);
      }
    }
    float hv[4][4];
#pragma unroll
    for (int n = 0; n < 4; ++n)
#pragma unroll
      for (int rr = 0; rr < 4; ++rr) {
        int row = lk * 4 + rr;
        hv[n][rr] = fast_tanh(acc[n][rr] + b0c[n] + xsh[row] * wihc[n]);
      }
    __syncthreads();
#pragma unroll
    for (int n = 0; n < 4; ++n)
#pragma unroll
      for (int rr = 0; rr < 4; ++rr) {
        int row = lk * 4 + rr;
        int col = c0 + n * 16 + lrow;
        int sg = (col >> 3) ^ (row & 7);
        h0b[row * 512 + sg * 8 + (col & 7)] = f2bf(hv[n][rr]);
      }
    __syncthreads();

#pragma unroll
    for (int n = 0; n < 4; ++n) acc[n] = zero4;
#pragma unroll
    for (int kk = 0; kk < 16; ++kk) {
      short8 a = *(const short8*)(&h0b[lrow * 512 + (((kk * 4 + lk) ^ r3) * 8)]);
#pragma unroll
      for (int n = 0; n < 4; ++n) {
        short8 bf = *(const short8*)(W1b + wb[n] + kk * 32);
        acc[n] = __builtin_amdgcn_mfma_f32_16x16x32_bf16(a, bf, acc[n], 0, 0, 0);
      }
    }
#pragma unroll
    for (int kk = 0; kk < 16; ++kk) {
      short8 a = *(const short8*)(&h1b[lrow * 512 + (((kk * 4 + lk) ^ r3) * 8)]);
#pragma unroll
      for (int n = 0; n < 4; ++n) {
        short8 bf = *(const short8*)(W2b + wb[n] + kk * 32);
        acc[n] = __builtin_amdgcn_mfma_f32_16x16x32_bf16(a, bf, acc[n], 0, 0, 0);
      }
    }
#pragma unroll
    for (int n = 0; n < 4; ++n)
#pragma unroll
      for (int rr = 0; rr < 4; ++rr)
        hv[n][rr] = fast_tanh(acc[n][rr] + b1c[n]);
    __syncthreads();
#pragma unroll
    for (int n = 0; n < 4; ++n)
#pragma unroll
      for (int rr = 0; rr < 4; ++rr) {
        int row = lk * 4 + rr;
        int col = c0 + n * 16 + lrow;
        int sg = (col >> 3) ^ (row & 7);
        h1b[row * 512 + sg * 8 + (col & 7)] = f2bf(hv[n][rr]);
      }
#pragma unroll
    for (int rr = 0; rr < 4; ++rr) {
      float p = 0.f;
#pragma unroll
      for (int n = 0; n < 4; ++n) p += hv[n][rr] * cwc[n];
      p += __shfl_xor(p, 1); p += __shfl_xor(p, 2);
      p += __shfl_xor(p, 4); p += __shfl_xor(p, 8);
      if (lrow == 0) red[w][lk * 4 + rr] = p;
    }
    __syncthreads();
    if (t < 16) {
      float s = cb;
#pragma unroll
      for (int q = 0; q < 8; ++q) s += red[q][t];
      xsh[t] = s;
      abuf[(size_t)(r0 + t) * 26 + st + 1] = s;
    }
    __syncthreads();
  }
}

// ---------------- small helpers ----------------
__global__ void k_ainit(float* abuf) {
  int idx = blockIdx.x * 256 + threadIdx.x;     // 8192
  if (idx < 8192) abuf[(size_t)idx * 26] = 1.0f;
}
__global__ void k_arc(float* __restrict__ outp, const float* __restrict__ abuf) {
  int idx = blockIdx.x * 256 + threadIdx.x;     // 2097152
  int j = idx & 255, i = (idx >> 8) & 255, b = idx >> 16;
  int k = i - j;
  outp[idx] = (k >= 0 && k <= 25) ? abuf[(size_t)(b * 256 + i) * 26 + k] : 0.0f;
}
__global__ void k_copy(float4* __restrict__ dst, const float4* __restrict__ src) {
  size_t i = (size_t)blockIdx.x * 256 + threadIdx.x;   // 1048576 float4
  dst[i] = src[i];
}
__global__ void k_diag(float* __restrict__ outp, float code, int n) {
  int idx = blockIdx.x * 256 + threadIdx.x;
  if (idx < n) outp[idx] = (idx == 0) ? code : 0.0f;
}

extern "C" void kernel_launch(void* const* d_in, const int* in_sizes, int n_in,
                              void* d_out, int out_size, void* d_ws, size_t ws_size,
                              hipStream_t stream) {
  static const int SZ[26] = {6266880, 2088960, 8160, 1024, 524288, 262144, 512, 512,
                             262144, 262144, 512, 512, 512, 262144, 512, 512,
                             262144, 262144, 512, 512, 512, 1, 131072, 256, 131072, 256};
  float diag_code = 0.0f;
  if (n_in != 26) diag_code = 4096.0f + (float)n_in;
  else {
    for (int j = 0; j < 26; ++j)
      if (in_sizes[j] != SZ[j]) { diag_code = 2048.0f + (float)j; break; }
  }
  const size_t NEED = (size_t)(21u << 20);
  if (ws_size < NEED && diag_code == 0.0f) diag_code = 8192.0f;
  if (diag_code != 0.0f) {
    k_diag<<<(out_size + 255) / 256, 256, 0, stream>>>((float*)d_out, diag_code, out_size);
    return;
  }

  const float* inp  = (const float*)d_in[0];
  const float* tag  = (const float*)d_in[1];
  const int*   mask = (const int*)d_in[2];
  const float* sent = (const float*)d_in[3];
  const float* g0_Wih = (const float*)d_in[4];
  const float* g0_Whh = (const float*)d_in[5];
  const float* g0_bih = (const float*)d_in[6];
  const float* g0_bhh = (const float*)d_in[7];
  const float* g1_Wih = (const float*)d_in[8];
  const float* g1_Whh = (const float*)d_in[9];
  const float* g1_bih = (const float*)d_in[10];
  const float* g1_bhh = (const float*)d_in[11];
  const float* e0_Wih = (const float*)d_in[12];
  const float* e0_Whh = (const float*)d_in[13];
  const float* e0_bih = (const float*)d_in[14];
  const float* e0_bhh = (const float*)d_in[15];
  const float* e1_Wih = (const float*)d_in[16];
  const float* e1_Whh = (const float*)d_in[17];
  const float* e1_bih = (const float*)d_in[18];
  const float* e1_bhh = (const float*)d_in[19];
  const float* cls_W  = (const float*)d_in[20];
  const float* cls_b  = (const float*)d_in[21];
  const float* ht_W   = (const float*)d_in[22];
  const float* ht_b   = (const float*)d_in[23];
  const float* dt_W   = (const float*)d_in[24];
  const float* dt_b   = (const float*)d_in[25];

  float* out  = (float*)d_out;              // [arc | head | dep] x 2097152 f32
  char*  ws   = (char*)d_ws;
  float* H0   = (float*)(ws);               // 16 MB scratch / heads staging
  float* ABUF = (float*)(ws + (16u << 20)); // [8192][26] f32
  u16*  W0b   = (u16*)(ws + (17u << 20));
  u16*  W1b   = (u16*)(ws + (17u << 20) + (512u << 10));
  u16*  W2b   = (u16*)(ws + (18u << 20));
  float* WT0  = (float*)(ws + (18u << 20) + (512u << 10));   // 1 MB transposed g0_Whh
  float* WT1  = (float*)(ws + (19u << 20) + (512u << 10));   // 1 MB transposed g1_Whh
  float* GS   = out;                        // GS [8192][512] f32 in d_out

  // weight conversions / transposes
  k_cvt<<<1024, 256, 0, stream>>>(W0b, e0_Whh);
  k_cvt<<<1024, 256, 0, stream>>>(W1b, e1_Wih);
  k_cvt<<<1024, 256, 0, stream>>>(W2b, e1_Whh);
  k_transw<<<1024, 256, 0, stream>>>(WT0, g0_Whh);
  k_transw<<<1024, 256, 0, stream>>>(WT1, g1_Whh);

  // 1) xW0 -> H0 ; 2) layer-0 scan in place (H0 = Y0)
  k_xw0<<<16384, 256, 0, stream>>>(H0, inp, tag, sent, g0_Wih, g0_bih, g0_bhh);
  k_gscan_hyb<<<32, 512, 0, stream>>>(H0, WT0, mask, 0);
  // 3) xW1 -> d_out ; 4) layer-1 scan in place -> GS (masked)
  k_lin0<<<16384, 256, 0, stream>>>(GS, H0, g1_Wih, g1_bih, g1_bhh);
  k_gscan_hyb<<<32, 512, 0, stream>>>(GS, WT1, mask, 1);
  // 5) tag heads from GS -> staged in H0
  k_heads<<<16384, 256, 0, stream>>>(H0, GS, ht_W, ht_b, dt_W, dt_b);
  // 6) MFMA edge scan -> ABUF
  k_ainit<<<32, 256, 0, stream>>>(ABUF);
  k_edge_mfma<<<512, 512, 0, stream>>>(GS, W0b, W1b, W2b, e0_Wih,
                                       e0_bih, e0_bhh, e1_bih, e1_bhh,
                                       cls_W, cls_b, ABUF);
  // 7) arc -> out[0..2M) ; 8) heads -> out[2M..6M)
  k_arc<<<8192, 256, 0, stream>>>(out, ABUF);
  k_copy<<<4096, 256, 0, stream>>>((float4*)(out + 2097152), (const float4*)H0);
}

// Round 13
// 9085.220 us; speedup vs baseline: 3.4663x; 1.4744x over previous
//
#include <hip/hip_runtime.h>
#include <math.h>

typedef unsigned int u32;
typedef unsigned short u16;
typedef __attribute__((ext_vector_type(8))) short short8;
typedef __attribute__((ext_vector_type(4))) float f32x4;

__device__ inline u16 f2bf(float f) {
  u32 u = __float_as_uint(f);
  return (u16)((u + 0x7fffu + ((u >> 16) & 1u)) >> 16);
}
__device__ inline float fast_tanh(float x) {
  x = fminf(9.0f, fmaxf(-9.0f, x));
  float e = __builtin_amdgcn_exp2f(x * 2.8853900817779268f);
  return (e - 1.0f) * __builtin_amdgcn_rcpf(e + 1.0f);
}

// ---------------- xW0[8192][512] = X @ g0_Wih^T + bih + bhh (f32) ----------------
__global__ void k_xw0(float* __restrict__ XW,
                      const float* __restrict__ inp, const float* __restrict__ tag,
                      const float* __restrict__ sent, const float* __restrict__ W,
                      const float* __restrict__ bih, const float* __restrict__ bhh) {
  int gid = blockIdx.x * 256 + threadIdx.x;     // 8192*512
  int row = gid >> 9, col = gid & 511;
  int b = row >> 8, s = row & 255;
  const float* w = W + (size_t)col * 1024;
  float acc = bih[col] + bhh[col];
  if (s == 0) {
    for (int k = 0; k < 1024; ++k) acc = fmaf(sent[k], w[k], acc);
  } else {
    const float* p1 = inp + (size_t)(b * 255 + s - 1) * 768;
    for (int k = 0; k < 768; ++k) acc = fmaf(p1[k], w[k], acc);
    const float* p2 = tag + (size_t)(b * 255 + s - 1) * 256;
    for (int k = 0; k < 256; ++k) acc = fmaf(p2[k], w[768 + k], acc);
  }
  XW[(size_t)row * 512 + col] = acc;
}

// ---- transpose Whh (f32 [512][512]) -> WT[k][t] = Whh[t][k] ----
__global__ void k_transw(float* __restrict__ outp, const float* __restrict__ src) {
  int idx = blockIdx.x * 256 + threadIdx.x;     // 262144
  int k = idx & 511, t = idx >> 9;
  outp[(size_t)k * 512 + t] = src[(size_t)t * 512 + k];
}

// ------- g-RNN scan, f32: 216 weights/thread resident (256-VGPR budget) + streamed rest -------
__global__ __launch_bounds__(512, 1) void k_gscan_hyb(
    float* __restrict__ XW, const float* __restrict__ WT,
    const int* __restrict__ mask, int layer)
{
  __shared__ float hs[512];
  const int t = threadIdx.x, b = blockIdx.x;
  float wreg[216];
#pragma unroll
  for (int k = 0; k < 216; ++k) wreg[k] = WT[(size_t)k * 512 + t];
  hs[t] = 0.f;
  __syncthreads();
  const float4* h4 = (const float4*)hs;
#pragma unroll 1
  for (int s = 0; s < 256; ++s) {
    float acc = XW[(size_t)(b * 256 + s) * 512 + t];
#pragma unroll
    for (int j = 0; j < 54; ++j) {
      float4 hv = h4[j];
      acc = fmaf(wreg[j * 4 + 0], hv.x, acc);
      acc = fmaf(wreg[j * 4 + 1], hv.y, acc);
      acc = fmaf(wreg[j * 4 + 2], hv.z, acc);
      acc = fmaf(wreg[j * 4 + 3], hv.w, acc);
    }
#pragma unroll 8
    for (int k = 216; k < 512; ++k)
      acc = fmaf(WT[(size_t)k * 512 + t], hs[k], acc);
    float hnew = tanhf(acc);
    float ov = hnew;
    if (layer) ov *= (s == 0) ? 1.f : (float)mask[b * 255 + s - 1];
    XW[(size_t)(b * 256 + s) * 512 + t] = ov;
    __syncthreads();
    hs[t] = hnew;
    __syncthreads();
  }
}

// ---------------- xW1 = Y0 @ g1_Wih^T + b (f32) ----------------
__global__ void k_lin0(float* __restrict__ outp, const float* __restrict__ A,
                       const float* __restrict__ W,
                       const float* __restrict__ b1, const float* __restrict__ b2) {
  int gid = blockIdx.x * 256 + threadIdx.x;     // 8192*512
  int row = gid >> 9, col = gid & 511;
  const float* a = A + (size_t)row * 512;
  const float* w = W + (size_t)col * 512;
  float acc = b1[col] + b2[col];
  for (int k = 0; k < 512; ++k) acc = fmaf(a[k], w[k], acc);
  outp[(size_t)row * 512 + col] = acc;
}

// ---------------- f32 -> bf16 convert ----------------
__global__ void k_cvt(u16* __restrict__ dst, const float* __restrict__ src) {
  int i = blockIdx.x * 256 + threadIdx.x;
  dst[i] = f2bf(src[i]);
}
__global__ void k_zero(uint4* p) {
  p[(size_t)blockIdx.x * 256 + threadIdx.x] = uint4{0u, 0u, 0u, 0u};
}

// ======== Validated bf16 MFMA GEMM (round-5 structure, cross-checked vs naive f32) ========
// C[8192 x 512] tiles 128x64, grid (8,64), 256 thr. A bf16 stride 512 (Ag k<512, Ag2 k>=512).
// W bf16 stride 512 (Wg k<512 / W2g k>=512; MODE1: Wg=ht_W rows, W2g=dt_W rows).
// MODE 1: elu -> f32 outh[row*256+col] (col<256) / outd (col>=256); bias b1/b2 per half.
// MODE 2: tanh(acc + b1+b2 + xe[row]*vecw[col]) -> bf16 outb stride 512.
// MODE 3: tanh(acc + b1+b2) -> bf16 outb; pred partial*vecw -> atomicAdd abuf[row][estep+1].
template<int MODE, int KD>
__global__ __launch_bounds__(256, 2) void gemm_k(
    const u16* __restrict__ Ag, const u16* __restrict__ Ag2,
    const u16* __restrict__ Wg, const u16* __restrict__ W2g,
    const float* __restrict__ b1, const float* __restrict__ b2,
    u16* __restrict__ outb, float* __restrict__ outh, float* __restrict__ outd,
    float* __restrict__ abuf, const float* __restrict__ vecw, int estep)
{
  __shared__ __attribute__((aligned(16))) u16 As[128 * 72];
  __shared__ __attribute__((aligned(16))) u16 Ws[64 * 72];
  __shared__ float xes[128];
  const int tid = threadIdx.x;
  const int lane = tid & 63, wid = tid >> 6;
  const int wr = wid >> 1, wc = wid & 1;
  const int m0 = blockIdx.y * 128, n0 = blockIdx.x * 64;

  if constexpr (MODE == 2) {
    if (tid < 128) xes[tid] = abuf[(size_t)(m0 + tid) * 26 + estep];
  }

  f32x4 zero4 = {0.f, 0.f, 0.f, 0.f};
  f32x4 acc[4][2];
#pragma unroll
  for (int i = 0; i < 4; ++i)
#pragma unroll
    for (int j = 0; j < 2; ++j) acc[i][j] = zero4;

  for (int kt = 0; kt < KD / 64; ++kt) {
    const u16* Asrc; int ka;
    if (kt < 8) { Asrc = Ag;  ka = kt; }
    else        { Asrc = Ag2; ka = kt - 8; }
    const u16* Wsrc; int kw, rowoff;
    if constexpr (MODE == 1) {
      if (n0 >= 256) { Wsrc = W2g; rowoff = n0 - 256; }
      else           { Wsrc = Wg;  rowoff = n0; }
      kw = kt;
    } else {
      if (kt < 8) { Wsrc = Wg;  kw = kt; }
      else        { Wsrc = W2g; kw = kt - 8; }
      rowoff = n0;
    }
    __syncthreads();
#pragma unroll
    for (int i = 0; i < 4; ++i) {
      int c = tid + i * 256;
      int row = c >> 3, c8 = c & 7;
      uint4 v = *(const uint4*)(Asrc + (size_t)(m0 + row) * 512 + ka * 64 + c8 * 8);
      *(uint4*)(&As[row * 72 + c8 * 8]) = v;
    }
#pragma unroll
    for (int i = 0; i < 2; ++i) {
      int c = tid + i * 256;
      int row = c >> 3, c8 = c & 7;
      uint4 v = *(const uint4*)(Wsrc + (size_t)(rowoff + row) * 512 + kw * 64 + c8 * 8);
      *(uint4*)(&Ws[row * 72 + c8 * 8]) = v;
    }
    __syncthreads();
#pragma unroll
    for (int ks = 0; ks < 2; ++ks) {
      short8 af[4], bfv[2];
#pragma unroll
      for (int mm = 0; mm < 4; ++mm) {
        int row = wr * 64 + mm * 16 + (lane & 15);
        af[mm] = *(const short8*)(As + row * 72 + ks * 32 + ((lane >> 4) << 3));
      }
#pragma unroll
      for (int nn = 0; nn < 2; ++nn) {
        int row = wc * 32 + nn * 16 + (lane & 15);
        bfv[nn] = *(const short8*)(Ws + row * 72 + ks * 32 + ((lane >> 4) << 3));
      }
#pragma unroll
      for (int mm = 0; mm < 4; ++mm)
#pragma unroll
        for (int nn = 0; nn < 2; ++nn)
          acc[mm][nn] = __builtin_amdgcn_mfma_f32_16x16x32_bf16(af[mm], bfv[nn], acc[mm][nn], 0, 0, 0);
    }
  }

  float bcol[2], vcol[2];
#pragma unroll
  for (int nn = 0; nn < 2; ++nn) {
    int col = n0 + wc * 32 + nn * 16 + (lane & 15);
    if constexpr (MODE == 1) bcol[nn] = (col < 256) ? b1[col] : b2[col - 256];
    else                     bcol[nn] = b1[col] + b2[col];
    vcol[nn] = 0.0f;
    if constexpr (MODE == 2 || MODE == 3) vcol[nn] = vecw[col];
  }
  float pp[4][4];
#pragma unroll
  for (int i = 0; i < 4; ++i)
#pragma unroll
    for (int j = 0; j < 4; ++j) pp[i][j] = 0.0f;

#pragma unroll
  for (int mm = 0; mm < 4; ++mm) {
#pragma unroll
    for (int r = 0; r < 4; ++r) {
      int lrow = wr * 64 + mm * 16 + ((lane >> 4) << 2) + r;
      int grow = m0 + lrow;
#pragma unroll
      for (int nn = 0; nn < 2; ++nn) {
        int col = n0 + wc * 32 + nn * 16 + (lane & 15);
        float v = acc[mm][nn][r] + bcol[nn];
        if constexpr (MODE == 1) {
          float e = v > 0.f ? v : (expf(v) - 1.f);
          if (col < 256) outh[(size_t)grow * 256 + col] = e;
          else           outd[(size_t)grow * 256 + (col - 256)] = e;
        } else if constexpr (MODE == 2) {
          v += xes[lrow] * vcol[nn];
          outb[(size_t)grow * 512 + col] = f2bf(fast_tanh(v));
        } else {
          float h = fast_tanh(v);
          outb[(size_t)grow * 512 + col] = f2bf(h);
          pp[mm][r] += h * vcol[nn];
        }
      }
    }
  }
  if constexpr (MODE == 3) {
#pragma unroll
    for (int mm = 0; mm < 4; ++mm)
#pragma unroll
      for (int r = 0; r < 4; ++r) {
        float p = pp[mm][r];
        p += __shfl_xor(p, 1); p += __shfl_xor(p, 2);
        p += __shfl_xor(p, 4); p += __shfl_xor(p, 8);
        if ((lane & 15) == 0) {
          int grow = m0 + wr * 64 + mm * 16 + ((lane >> 4) << 2) + r;
          atomicAdd(&abuf[(size_t)grow * 26 + estep + 1], p);
        }
      }
  }
}

// ---------------- small helpers ----------------
__global__ void k_ainit(float* abuf, const float* clsb) {
  int idx = blockIdx.x * 256 + threadIdx.x;     // 212992 = 8192*26
  if (idx >= 212992) return;
  abuf[idx] = ((idx % 26) == 0) ? 1.0f : clsb[0];
}
__global__ void k_arc(float* __restrict__ outp, const float* __restrict__ abuf) {
  int idx = blockIdx.x * 256 + threadIdx.x;     // 2097152
  int j = idx & 255, i = (idx >> 8) & 255, b = idx >> 16;
  int k = i - j;
  outp[idx] = (k >= 0 && k <= 25) ? abuf[(size_t)(b * 256 + i) * 26 + k] : 0.0f;
}
__global__ void k_diag(float* __restrict__ outp, float code, int n) {
  int idx = blockIdx.x * 256 + threadIdx.x;
  if (idx < n) outp[idx] = (idx == 0) ? code : 0.0f;
}

extern "C" void kernel_launch(void* const* d_in, const int* in_sizes, int n_in,
                              void* d_out, int out_size, void* d_ws, size_t ws_size,
                              hipStream_t stream) {
  static const int SZ[26] = {6266880, 2088960, 8160, 1024, 524288, 262144, 512, 512,
                             262144, 262144, 512, 512, 512, 262144, 512, 512,
                             262144, 262144, 512, 512, 512, 1, 131072, 256, 131072, 256};
  float diag_code = 0.0f;
  if (n_in != 26) diag_code = 4096.0f + (float)n_in;
  else {
    for (int j = 0; j < 26; ++j)
      if (in_sizes[j] != SZ[j]) { diag_code = 2048.0f + (float)j; break; }
  }
  const size_t NEED = 26017792;   // S0+S1+S2 (25.17M) + ABUF (852K)
  if (ws_size < NEED && diag_code == 0.0f) diag_code = 8192.0f;
  if (diag_code != 0.0f) {
    k_diag<<<(out_size + 255) / 256, 256, 0, stream>>>((float*)d_out, diag_code, out_size);
    return;
  }

  const float* inp  = (const float*)d_in[0];
  const float* tag  = (const float*)d_in[1];
  const int*   mask = (const int*)d_in[2];
  const float* sent = (const float*)d_in[3];
  const float* g0_Wih = (const float*)d_in[4];
  const float* g0_Whh = (const float*)d_in[5];
  const float* g0_bih = (const float*)d_in[6];
  const float* g0_bhh = (const float*)d_in[7];
  const float* g1_Wih = (const float*)d_in[8];
  const float* g1_Whh = (const float*)d_in[9];
  const float* g1_bih = (const float*)d_in[10];
  const float* g1_bhh = (const float*)d_in[11];
  const float* e0_Wih = (const float*)d_in[12];
  const float* e0_Whh = (const float*)d_in[13];
  const float* e0_bih = (const float*)d_in[14];
  const float* e0_bhh = (const float*)d_in[15];
  const float* e1_Wih = (const float*)d_in[16];
  const float* e1_Whh = (const float*)d_in[17];
  const float* e1_bih = (const float*)d_in[18];
  const float* e1_bhh = (const float*)d_in[19];
  const float* cls_W  = (const float*)d_in[20];
  const float* cls_b  = (const float*)d_in[21];
  const float* ht_W   = (const float*)d_in[22];
  const float* ht_b   = (const float*)d_in[23];
  const float* dt_W   = (const float*)d_in[24];
  const float* dt_b   = (const float*)d_in[25];

  float* out = (float*)d_out;               // [arc | head | dep] x 2097152 f32
  char*  ws  = (char*)d_ws;
  // ws layout (26.0 MB): sequential-lifetime overlays
  float* H0  = (float*)(ws);                        // [0,16.78M) f32: xW0 -> Y0
  u16*  S0   = (u16*)(ws);                          // [0,8.39M)  bf16 state (after H0 dead)
  u16*  S1   = (u16*)(ws + 8388608);                // [8.39,16.78M)
  u16*  S2   = (u16*)(ws + 16777216);               // [16.78,25.17M)
  float* WT0 = (float*)(ws + 16777216);             // 1MB, dead before S2 use
  float* WT1 = (float*)(ws + 17825792);             // 1MB
  u16*  W3b  = (u16*)(ws + 18874368);               // ht_W bf16 (256KB), dead before S2 use
  u16*  W4b  = (u16*)(ws + 19136512);               // dt_W bf16 (256KB)
  float* ABUF = (float*)(ws + 25165824);            // [8192][26] f32
  // edge weights live in d_out's arc region (dead until k_arc)
  u16*  W0b  = (u16*)d_out;                         // e0_Whh bf16 (512KB)
  u16*  W1b  = W0b + 262144;                        // e1_Wih bf16
  u16*  W2b  = W0b + 524288;                        // e1_Whh bf16
  float* GS  = out;                                 // GS f32 [8192][512] in d_out[0:16.78M)

  dim3 grid(8, 64);

  // transposes for gscan (into S2 region, dead later)
  k_transw<<<1024, 256, 0, stream>>>(WT0, g0_Whh);
  k_transw<<<1024, 256, 0, stream>>>(WT1, g1_Whh);

  // 1) xW0 -> H0 ; 2) layer-0 scan in place (H0 = Y0)
  k_xw0<<<16384, 256, 0, stream>>>(H0, inp, tag, sent, g0_Wih, g0_bih, g0_bhh);
  k_gscan_hyb<<<32, 512, 0, stream>>>(H0, WT0, mask, 0);
  // 3) xW1 -> d_out ; 4) layer-1 scan in place -> GS (masked)
  k_lin0<<<16384, 256, 0, stream>>>(GS, H0, g1_Wih, g1_bih, g1_bhh);
  k_gscan_hyb<<<32, 512, 0, stream>>>(GS, WT1, mask, 1);

  // 5) GS -> bf16 S0 (H0/Y0 dead); S1 = 0
  k_cvt<<<16384, 256, 0, stream>>>(S0, GS);
  k_zero<<<2048, 256, 0, stream>>>((uint4*)S1);
  // 6) weight converts (GS f32 now dead -> arc region usable for W0b/W1b/W2b)
  k_cvt<<<1024, 256, 0, stream>>>(W0b, e0_Whh);
  k_cvt<<<1024, 256, 0, stream>>>(W1b, e1_Wih);
  k_cvt<<<1024, 256, 0, stream>>>(W2b, e1_Whh);
  k_cvt<<<512, 256, 0, stream>>>(W3b, ht_W);
  k_cvt<<<512, 256, 0, stream>>>(W4b, dt_W);

  // 7) tag heads: MFMA GEMM -> f32 head/dep directly in d_out
  gemm_k<1, 512><<<grid, 256, 0, stream>>>(S0, nullptr, W3b, W4b, ht_b, dt_b,
                                           nullptr, out + 2097152, out + 4194304,
                                           nullptr, nullptr, 0);

  // 8) edge scan: 25 x (E0, E1) with triple-buffer rotation
  k_ainit<<<832, 256, 0, stream>>>(ABUF, cls_b);
  u16* r0 = S0;   // h0 (= GS)
  u16* r1 = S1;   // h1 (= 0)
  u16* r2 = S2;   // free
  for (int st = 0; st < 25; ++st) {
    gemm_k<2, 512><<<grid, 256, 0, stream>>>(r0, nullptr, W0b, nullptr, e0_bih, e0_bhh,
                                             r2, nullptr, nullptr, ABUF, e0_Wih, st);
    gemm_k<3, 1024><<<grid, 256, 0, stream>>>(r2, r1, W1b, W2b, e1_bih, e1_bhh,
                                              r0, nullptr, nullptr, ABUF, cls_W, st);
    u16* t0 = r2; u16* t1 = r0; u16* t2 = r1;
    r0 = t0; r1 = t1; r2 = t2;
  }
  // 9) arc gather (overwrites W0b/W1b/W2b region — they're dead)
  k_arc<<<8192, 256, 0, stream>>>(out, ABUF);
}

// Round 14
// 5736.179 us; speedup vs baseline: 5.4901x; 1.5838x over previous
//
#include <hip/hip_runtime.h>
#include <math.h>

typedef unsigned int u32;
typedef unsigned short u16;
typedef __attribute__((ext_vector_type(8))) short short8;
typedef __attribute__((ext_vector_type(4))) float f32x4;

__device__ inline float bf2f(u16 v) { return __uint_as_float(((u32)v) << 16); }
__device__ inline u16 f2bf(float f) {
  u32 u = __float_as_uint(f);
  return (u16)((u + 0x7fffu + ((u >> 16) & 1u)) >> 16);
}
__device__ inline float fast_tanh(float x) {
  x = fminf(9.0f, fmaxf(-9.0f, x));
  float e = __builtin_amdgcn_exp2f(x * 2.8853900817779268f);
  return (e - 1.0f) * __builtin_amdgcn_rcpf(e + 1.0f);
}

// ---- transpose Whh (f32 [512][512]) -> WT[k][t] ----
__global__ void k_transw(float* __restrict__ outp, const float* __restrict__ src) {
  int idx = blockIdx.x * 256 + threadIdx.x;     // 262144
  int k = idx & 511, t = idx >> 9;
  outp[(size_t)k * 512 + t] = src[(size_t)t * 512 + k];
}

// ---- hi/lo bf16 split of an f32 array ----
__global__ void k_split(u16* __restrict__ hi, u16* __restrict__ lo,
                        const float* __restrict__ src, int n) {
  int i = blockIdx.x * 256 + threadIdx.x;
  if (i >= n) return;
  float v = src[i];
  u16 h = f2bf(v);
  hi[i] = h;
  lo[i] = f2bf(v - bf2f(h));
}

// ---- concat + split: X[8192][1024] = [sent | inp|tag] -> Xhi/Xlo bf16 ----
__global__ void k_concat_split(u16* __restrict__ xhi, u16* __restrict__ xlo,
                               const float* __restrict__ inp, const float* __restrict__ tag,
                               const float* __restrict__ sent) {
  int gid = blockIdx.x * 256 + threadIdx.x;     // 8388608
  int row = gid >> 10, c = gid & 1023;
  int b = row >> 8, s = row & 255;
  float v;
  if (s == 0) v = sent[c];
  else if (c < 768) v = inp[(size_t)(b * 255 + s - 1) * 768 + c];
  else v = tag[(size_t)(b * 255 + s - 1) * 256 + (c - 768)];
  u16 h = f2bf(v);
  xhi[gid] = h;
  xlo[gid] = f2bf(v - bf2f(h));
}

// ------- g-RNN scan, f32: 216 weights/thread resident + streamed rest -------
__global__ __launch_bounds__(512, 1) void k_gscan_hyb(
    float* __restrict__ XW, const float* __restrict__ WT,
    const int* __restrict__ mask, int layer)
{
  __shared__ float hs[512];
  const int t = threadIdx.x, b = blockIdx.x;
  float wreg[216];
#pragma unroll
  for (int k = 0; k < 216; ++k) wreg[k] = WT[(size_t)k * 512 + t];
  hs[t] = 0.f;
  __syncthreads();
  const float4* h4 = (const float4*)hs;
#pragma unroll 1
  for (int s = 0; s < 256; ++s) {
    float acc = XW[(size_t)(b * 256 + s) * 512 + t];
#pragma unroll
    for (int j = 0; j < 54; ++j) {
      float4 hv = h4[j];
      acc = fmaf(wreg[j * 4 + 0], hv.x, acc);
      acc = fmaf(wreg[j * 4 + 1], hv.y, acc);
      acc = fmaf(wreg[j * 4 + 2], hv.z, acc);
      acc = fmaf(wreg[j * 4 + 3], hv.w, acc);
    }
#pragma unroll 8
    for (int k = 216; k < 512; ++k)
      acc = fmaf(WT[(size_t)k * 512 + t], hs[k], acc);
    float hnew = tanhf(acc);
    float ov = hnew;
    if (layer) ov *= (s == 0) ? 1.f : (float)mask[b * 255 + s - 1];
    XW[(size_t)(b * 256 + s) * 512 + t] = ov;
    __syncthreads();
    hs[t] = hnew;
    __syncthreads();
  }
}

// ---------------- f32 -> bf16 convert / zero ----------------
__global__ void k_cvt(u16* __restrict__ dst, const float* __restrict__ src) {
  int i = blockIdx.x * 256 + threadIdx.x;
  dst[i] = f2bf(src[i]);
}
__global__ void k_zero(uint4* p) {
  p[(size_t)blockIdx.x * 256 + threadIdx.x] = uint4{0u, 0u, 0u, 0u};
}

// ======== Split-precision MFMA GEMM: C f32 = (Ahi+Alo)@(Whi+Wlo)^T + b1 + b2 ========
// Error ~2^-18 relative (f32-equivalent). Tiles 128x64, grid (8,64).
template<int KD>
__global__ __launch_bounds__(256, 2) void gemm_s(
    const u16* __restrict__ Ahi, const u16* __restrict__ Alo,
    const u16* __restrict__ Whi, const u16* __restrict__ Wlo,
    const float* __restrict__ b1, const float* __restrict__ b2,
    float* __restrict__ outf)
{
  __shared__ __attribute__((aligned(16))) u16 Ah[128 * 72];
  __shared__ __attribute__((aligned(16))) u16 Al[128 * 72];
  __shared__ __attribute__((aligned(16))) u16 Wh[64 * 72];
  __shared__ __attribute__((aligned(16))) u16 Wl[64 * 72];
  const int tid = threadIdx.x;
  const int lane = tid & 63, wid = tid >> 6;
  const int wr = wid >> 1, wc = wid & 1;
  const int m0 = blockIdx.y * 128, n0 = blockIdx.x * 64;

  f32x4 zero4 = {0.f, 0.f, 0.f, 0.f};
  f32x4 acc[4][2];
#pragma unroll
  for (int i = 0; i < 4; ++i)
#pragma unroll
    for (int j = 0; j < 2; ++j) acc[i][j] = zero4;

  for (int kt = 0; kt < KD / 64; ++kt) {
    __syncthreads();
#pragma unroll
    for (int i = 0; i < 4; ++i) {
      int c = tid + i * 256;
      int row = c >> 3, c8 = c & 7;
      size_t g = (size_t)(m0 + row) * KD + kt * 64 + c8 * 8;
      *(uint4*)(&Ah[row * 72 + c8 * 8]) = *(const uint4*)(Ahi + g);
      *(uint4*)(&Al[row * 72 + c8 * 8]) = *(const uint4*)(Alo + g);
    }
#pragma unroll
    for (int i = 0; i < 2; ++i) {
      int c = tid + i * 256;
      int row = c >> 3, c8 = c & 7;
      size_t g = (size_t)(n0 + row) * KD + kt * 64 + c8 * 8;
      *(uint4*)(&Wh[row * 72 + c8 * 8]) = *(const uint4*)(Whi + g);
      *(uint4*)(&Wl[row * 72 + c8 * 8]) = *(const uint4*)(Wlo + g);
    }
    __syncthreads();
#pragma unroll
    for (int ks = 0; ks < 2; ++ks) {
      short8 ah[4], al[4], wh[2], wl[2];
#pragma unroll
      for (int mm = 0; mm < 4; ++mm) {
        int row = wr * 64 + mm * 16 + (lane & 15);
        int off = row * 72 + ks * 32 + ((lane >> 4) << 3);
        ah[mm] = *(const short8*)(Ah + off);
        al[mm] = *(const short8*)(Al + off);
      }
#pragma unroll
      for (int nn = 0; nn < 2; ++nn) {
        int row = wc * 32 + nn * 16 + (lane & 15);
        int off = row * 72 + ks * 32 + ((lane >> 4) << 3);
        wh[nn] = *(const short8*)(Wh + off);
        wl[nn] = *(const short8*)(Wl + off);
      }
#pragma unroll
      for (int mm = 0; mm < 4; ++mm)
#pragma unroll
        for (int nn = 0; nn < 2; ++nn) {
          acc[mm][nn] = __builtin_amdgcn_mfma_f32_16x16x32_bf16(ah[mm], wh[nn], acc[mm][nn], 0, 0, 0);
          acc[mm][nn] = __builtin_amdgcn_mfma_f32_16x16x32_bf16(ah[mm], wl[nn], acc[mm][nn], 0, 0, 0);
          acc[mm][nn] = __builtin_amdgcn_mfma_f32_16x16x32_bf16(al[mm], wh[nn], acc[mm][nn], 0, 0, 0);
        }
    }
  }

  float bcol[2];
#pragma unroll
  for (int nn = 0; nn < 2; ++nn) {
    int col = n0 + wc * 32 + nn * 16 + (lane & 15);
    bcol[nn] = b1[col] + b2[col];
  }
#pragma unroll
  for (int mm = 0; mm < 4; ++mm)
#pragma unroll
    for (int r = 0; r < 4; ++r) {
      int grow = m0 + wr * 64 + mm * 16 + ((lane >> 4) << 2) + r;
#pragma unroll
      for (int nn = 0; nn < 2; ++nn) {
        int col = n0 + wc * 32 + nn * 16 + (lane & 15);
        outf[(size_t)grow * 512 + col] = acc[mm][nn][r] + bcol[nn];
      }
    }
}

// ======== Validated bf16 MFMA GEMM (modes 1/2/3), unchanged from round 13 ========
template<int MODE, int KD>
__global__ __launch_bounds__(256, 2) void gemm_k(
    const u16* __restrict__ Ag, const u16* __restrict__ Ag2,
    const u16* __restrict__ Wg, const u16* __restrict__ W2g,
    const float* __restrict__ b1, const float* __restrict__ b2,
    u16* __restrict__ outb, float* __restrict__ outh, float* __restrict__ outd,
    float* __restrict__ abuf, const float* __restrict__ vecw, int estep)
{
  __shared__ __attribute__((aligned(16))) u16 As[128 * 72];
  __shared__ __attribute__((aligned(16))) u16 Ws[64 * 72];
  __shared__ float xes[128];
  const int tid = threadIdx.x;
  const int lane = tid & 63, wid = tid >> 6;
  const int wr = wid >> 1, wc = wid & 1;
  const int m0 = blockIdx.y * 128, n0 = blockIdx.x * 64;

  if constexpr (MODE == 2) {
    if (tid < 128) xes[tid] = abuf[(size_t)(m0 + tid) * 26 + estep];
  }

  f32x4 zero4 = {0.f, 0.f, 0.f, 0.f};
  f32x4 acc[4][2];
#pragma unroll
  for (int i = 0; i < 4; ++i)
#pragma unroll
    for (int j = 0; j < 2; ++j) acc[i][j] = zero4;

  for (int kt = 0; kt < KD / 64; ++kt) {
    const u16* Asrc; int ka;
    if (kt < 8) { Asrc = Ag;  ka = kt; }
    else        { Asrc = Ag2; ka = kt - 8; }
    const u16* Wsrc; int kw, rowoff;
    if constexpr (MODE == 1) {
      if (n0 >= 256) { Wsrc = W2g; rowoff = n0 - 256; }
      else           { Wsrc = Wg;  rowoff = n0; }
      kw = kt;
    } else {
      if (kt < 8) { Wsrc = Wg;  kw = kt; }
      else        { Wsrc = W2g; kw = kt - 8; }
      rowoff = n0;
    }
    __syncthreads();
#pragma unroll
    for (int i = 0; i < 4; ++i) {
      int c = tid + i * 256;
      int row = c >> 3, c8 = c & 7;
      uint4 v = *(const uint4*)(Asrc + (size_t)(m0 + row) * 512 + ka * 64 + c8 * 8);
      *(uint4*)(&As[row * 72 + c8 * 8]) = v;
    }
#pragma unroll
    for (int i = 0; i < 2; ++i) {
      int c = tid + i * 256;
      int row = c >> 3, c8 = c & 7;
      uint4 v = *(const uint4*)(Wsrc + (size_t)(rowoff + row) * 512 + kw * 64 + c8 * 8);
      *(uint4*)(&Ws[row * 72 + c8 * 8]) = v;
    }
    __syncthreads();
#pragma unroll
    for (int ks = 0; ks < 2; ++ks) {
      short8 af[4], bfv[2];
#pragma unroll
      for (int mm = 0; mm < 4; ++mm) {
        int row = wr * 64 + mm * 16 + (lane & 15);
        af[mm] = *(const short8*)(As + row * 72 + ks * 32 + ((lane >> 4) << 3));
      }
#pragma unroll
      for (int nn = 0; nn < 2; ++nn) {
        int row = wc * 32 + nn * 16 + (lane & 15);
        bfv[nn] = *(const short8*)(Ws + row * 72 + ks * 32 + ((lane >> 4) << 3));
      }
#pragma unroll
      for (int mm = 0; mm < 4; ++mm)
#pragma unroll
        for (int nn = 0; nn < 2; ++nn)
          acc[mm][nn] = __builtin_amdgcn_mfma_f32_16x16x32_bf16(af[mm], bfv[nn], acc[mm][nn], 0, 0, 0);
    }
  }

  float bcol[2], vcol[2];
#pragma unroll
  for (int nn = 0; nn < 2; ++nn) {
    int col = n0 + wc * 32 + nn * 16 + (lane & 15);
    if constexpr (MODE == 1) bcol[nn] = (col < 256) ? b1[col] : b2[col - 256];
    else                     bcol[nn] = b1[col] + b2[col];
    vcol[nn] = 0.0f;
    if constexpr (MODE == 2 || MODE == 3) vcol[nn] = vecw[col];
  }
  float pp[4][4];
#pragma unroll
  for (int i = 0; i < 4; ++i)
#pragma unroll
    for (int j = 0; j < 4; ++j) pp[i][j] = 0.0f;

#pragma unroll
  for (int mm = 0; mm < 4; ++mm) {
#pragma unroll
    for (int r = 0; r < 4; ++r) {
      int lrow = wr * 64 + mm * 16 + ((lane >> 4) << 2) + r;
      int grow = m0 + lrow;
#pragma unroll
      for (int nn = 0; nn < 2; ++nn) {
        int col = n0 + wc * 32 + nn * 16 + (lane & 15);
        float v = acc[mm][nn][r] + bcol[nn];
        if constexpr (MODE == 1) {
          float e = v > 0.f ? v : (expf(v) - 1.f);
          if (col < 256) outh[(size_t)grow * 256 + col] = e;
          else           outd[(size_t)grow * 256 + (col - 256)] = e;
        } else if constexpr (MODE == 2) {
          v += xes[lrow] * vcol[nn];
          outb[(size_t)grow * 512 + col] = f2bf(fast_tanh(v));
        } else {
          float h = fast_tanh(v);
          outb[(size_t)grow * 512 + col] = f2bf(h);
          pp[mm][r] += h * vcol[nn];
        }
      }
    }
  }
  if constexpr (MODE == 3) {
#pragma unroll
    for (int mm = 0; mm < 4; ++mm)
#pragma unroll
      for (int r = 0; r < 4; ++r) {
        float p = pp[mm][r];
        p += __shfl_xor(p, 1); p += __shfl_xor(p, 2);
        p += __shfl_xor(p, 4); p += __shfl_xor(p, 8);
        if ((lane & 15) == 0) {
          int grow = m0 + wr * 64 + mm * 16 + ((lane >> 4) << 2) + r;
          atomicAdd(&abuf[(size_t)grow * 26 + estep + 1], p);
        }
      }
  }
}

// ---------------- small helpers ----------------
__global__ void k_ainit(float* abuf, const float* clsb) {
  int idx = blockIdx.x * 256 + threadIdx.x;     // 212992
  if (idx >= 212992) return;
  abuf[idx] = ((idx % 26) == 0) ? 1.0f : clsb[0];
}
__global__ void k_arc(float* __restrict__ outp, const float* __restrict__ abuf) {
  int idx = blockIdx.x * 256 + threadIdx.x;     // 2097152
  int j = idx & 255, i = (idx >> 8) & 255, b = idx >> 16;
  int k = i - j;
  outp[idx] = (k >= 0 && k <= 25) ? abuf[(size_t)(b * 256 + i) * 26 + k] : 0.0f;
}
__global__ void k_diag(float* __restrict__ outp, float code, int n) {
  int idx = blockIdx.x * 256 + threadIdx.x;
  if (idx < n) outp[idx] = (idx == 0) ? code : 0.0f;
}

extern "C" void kernel_launch(void* const* d_in, const int* in_sizes, int n_in,
                              void* d_out, int out_size, void* d_ws, size_t ws_size,
                              hipStream_t stream) {
  static const int SZ[26] = {6266880, 2088960, 8160, 1024, 524288, 262144, 512, 512,
                             262144, 262144, 512, 512, 512, 262144, 512, 512,
                             262144, 262144, 512, 512, 512, 1, 131072, 256, 131072, 256};
  float diag_code = 0.0f;
  if (n_in != 26) diag_code = 4096.0f + (float)n_in;
  else {
    for (int j = 0; j < 26; ++j)
      if (in_sizes[j] != SZ[j]) { diag_code = 2048.0f + (float)j; break; }
  }
  const size_t NEED = (size_t)(32u << 20);   // round 8 proved ws >= 34.4 MB
  if (ws_size < NEED && diag_code == 0.0f) diag_code = 8192.0f;
  if (diag_code != 0.0f) {
    k_diag<<<(out_size + 255) / 256, 256, 0, stream>>>((float*)d_out, diag_code, out_size);
    return;
  }

  const float* inp  = (const float*)d_in[0];
  const float* tag  = (const float*)d_in[1];
  const int*   mask = (const int*)d_in[2];
  const float* sent = (const float*)d_in[3];
  const float* g0_Wih = (const float*)d_in[4];
  const float* g0_Whh = (const float*)d_in[5];
  const float* g0_bih = (const float*)d_in[6];
  const float* g0_bhh = (const float*)d_in[7];
  const float* g1_Wih = (const float*)d_in[8];
  const float* g1_Whh = (const float*)d_in[9];
  const float* g1_bih = (const float*)d_in[10];
  const float* g1_bhh = (const float*)d_in[11];
  const float* e0_Wih = (const float*)d_in[12];
  const float* e0_Whh = (const float*)d_in[13];
  const float* e0_bih = (const float*)d_in[14];
  const float* e0_bhh = (const float*)d_in[15];
  const float* e1_Wih = (const float*)d_in[16];
  const float* e1_Whh = (const float*)d_in[17];
  const float* e1_bih = (const float*)d_in[18];
  const float* e1_bhh = (const float*)d_in[19];
  const float* cls_W  = (const float*)d_in[20];
  const float* cls_b  = (const float*)d_in[21];
  const float* ht_W   = (const float*)d_in[22];
  const float* ht_b   = (const float*)d_in[23];
  const float* dt_W   = (const float*)d_in[24];
  const float* dt_b   = (const float*)d_in[25];

  float* out = (float*)d_out;               // 24 MB: [arc | head | dep] f32
  char*  ob  = (char*)d_out;
  char*  ws  = (char*)d_ws;

  // ---- d_out overlays (pre-output lifetimes) ----
  u16*  W0hi = (u16*)(ob);                  // [0,1M) g0_Wih hi [512][1024]
  u16*  W0lo = (u16*)(ob + (1u << 20));     // [1,2M)
  float* XW0 = (float*)(ob + (2u << 20));   // [2,18M) xW0 -> Y0 -> GS (f32 [8192][512])
  float* WT0 = (float*)(ob + (18u << 20));  // [18,19M)
  float* WT1 = (float*)(ob + (19u << 20));  // [19,20M)
  u16*  G1hi = (u16*)(ob + (20u << 20));    // [20,20.5M) g1_Wih hi [512][512]
  u16*  G1lo = (u16*)(ob + (20u << 20) + (512u << 10));
  // ---- ws overlays ----
  u16*  Xhi  = (u16*)(ws);                  // [0,16M)  X hi [8192][1024]
  u16*  Xlo  = (u16*)(ws + (16u << 20));    // [16,32M)
  u16*  Y0hi = (u16*)(ws);                  // [0,8M)   after X dead; later S0
  u16*  Y0lo = (u16*)(ws + (8u << 20));     // [8,16M)  later S1
  u16*  S0   = Y0hi;
  u16*  S1   = Y0lo;
  u16*  S2   = (u16*)(ws + (16u << 20));    // [16,24M)
  float* ABUF = (float*)(ws + (24u << 20)); // 852 KB
  u16*  W0b  = (u16*)(ws + (25u << 20));                      // e0_Whh bf16
  u16*  W1b  = (u16*)(ws + (25u << 20) + (512u << 10));       // e1_Wih
  u16*  W2b  = (u16*)(ws + (26u << 20));                      // e1_Whh
  u16*  W3b  = (u16*)(ws + (26u << 20) + (512u << 10));       // ht_W
  u16*  W4b  = (u16*)(ws + (26u << 20) + (768u << 10));       // dt_W

  dim3 grid(8, 64);

  // 1) splits + transposes
  k_concat_split<<<32768, 256, 0, stream>>>(Xhi, Xlo, inp, tag, sent);
  k_split<<<2048, 256, 0, stream>>>(W0hi, W0lo, g0_Wih, 524288);
  k_transw<<<1024, 256, 0, stream>>>(WT0, g0_Whh);
  k_transw<<<1024, 256, 0, stream>>>(WT1, g1_Whh);
  k_split<<<1024, 256, 0, stream>>>(G1hi, G1lo, g1_Wih, 262144);

  // 2) xW0 = X @ g0_Wih^T + b (split-precision MFMA) -> XW0; scan0 in place -> Y0
  gemm_s<1024><<<grid, 256, 0, stream>>>(Xhi, Xlo, W0hi, W0lo, g0_bih, g0_bhh, XW0);
  k_gscan_hyb<<<32, 512, 0, stream>>>(XW0, WT0, mask, 0);

  // 3) split Y0 (X dead); xW1 -> XW0 region; scan1 in place -> GS (masked)
  k_split<<<16384, 256, 0, stream>>>(Y0hi, Y0lo, XW0, 4194304);
  gemm_s<512><<<grid, 256, 0, stream>>>(Y0hi, Y0lo, G1hi, G1lo, g1_bih, g1_bhh, XW0);
  k_gscan_hyb<<<32, 512, 0, stream>>>(XW0, WT1, mask, 1);

  // 4) GS -> bf16 S0 (Y0hi dead); S1 = 0; edge/head weights -> bf16
  k_cvt<<<16384, 256, 0, stream>>>(S0, XW0);
  k_zero<<<2048, 256, 0, stream>>>((uint4*)S1);
  k_cvt<<<1024, 256, 0, stream>>>(W0b, e0_Whh);
  k_cvt<<<1024, 256, 0, stream>>>(W1b, e1_Wih);
  k_cvt<<<1024, 256, 0, stream>>>(W2b, e1_Whh);
  k_cvt<<<512, 256, 0, stream>>>(W3b, ht_W);
  k_cvt<<<512, 256, 0, stream>>>(W4b, dt_W);

  // 5) tag heads -> f32 head/dep in d_out (GS f32 dead)
  gemm_k<1, 512><<<grid, 256, 0, stream>>>(S0, nullptr, W3b, W4b, ht_b, dt_b,
                                           nullptr, out + 2097152, out + 4194304,
                                           nullptr, nullptr, 0);

  // 6) edge scan: 25 x (E0, E1), triple-buffer rotation
  k_ainit<<<832, 256, 0, stream>>>(ABUF, cls_b);
  u16* r0 = S0; u16* r1 = S1; u16* r2 = S2;
  for (int st = 0; st < 25; ++st) {
    gemm_k<2, 512><<<grid, 256, 0, stream>>>(r0, nullptr, W0b, nullptr, e0_bih, e0_bhh,
                                             r2, nullptr, nullptr, ABUF, e0_Wih, st);
    gemm_k<3, 1024><<<grid, 256, 0, stream>>>(r2, r1, W1b, W2b, e1_bih, e1_bhh,
                                              r0, nullptr, nullptr, ABUF, cls_W, st);
    u16* t0 = r2; u16* t1 = r0; u16* t2 = r1;
    r0 = t0; r1 = t1; r2 = t2;
  }
  // 7) arc gather
  k_arc<<<8192, 256, 0, stream>>>(out, ABUF);
}

// Round 15
// 4255.802 us; speedup vs baseline: 7.3998x; 1.3478x over previous
//
#include <hip/hip_runtime.h>
#include <math.h>

typedef unsigned int u32;
typedef unsigned short u16;
typedef __attribute__((ext_vector_type(8))) short short8;
typedef __attribute__((ext_vector_type(4))) float f32x4;

__device__ inline float bf2f(u16 v) { return __uint_as_float(((u32)v) << 16); }
__device__ inline u16 f2bf(float f) {
  u32 u = __float_as_uint(f);
  return (u16)((u + 0x7fffu + ((u >> 16) & 1u)) >> 16);
}
__device__ inline float fast_tanh(float x) {
  x = fminf(9.0f, fmaxf(-9.0f, x));
  float e = __builtin_amdgcn_exp2f(x * 2.8853900817779268f);
  return (e - 1.0f) * __builtin_amdgcn_rcpf(e + 1.0f);
}

// ---- transpose Whh (f32 [512][512]) -> WT[k][t] ----
__global__ void k_transw(float* __restrict__ outp, const float* __restrict__ src) {
  int idx = blockIdx.x * 256 + threadIdx.x;     // 262144
  int k = idx & 511, t = idx >> 9;
  outp[(size_t)k * 512 + t] = src[(size_t)t * 512 + k];
}

// ---- hi/lo bf16 split of an f32 array ----
__global__ void k_split(u16* __restrict__ hi, u16* __restrict__ lo,
                        const float* __restrict__ src, int n) {
  int i = blockIdx.x * 256 + threadIdx.x;
  if (i >= n) return;
  float v = src[i];
  u16 h = f2bf(v);
  hi[i] = h;
  lo[i] = f2bf(v - bf2f(h));
}

// ---- concat + split: X[8192][1024] = [sent | inp|tag] -> Xhi/Xlo bf16 ----
__global__ void k_concat_split(u16* __restrict__ xhi, u16* __restrict__ xlo,
                               const float* __restrict__ inp, const float* __restrict__ tag,
                               const float* __restrict__ sent) {
  int gid = blockIdx.x * 256 + threadIdx.x;     // 8388608
  int row = gid >> 10, c = gid & 1023;
  int b = row >> 8, s = row & 255;
  float v;
  if (s == 0) v = sent[c];
  else if (c < 768) v = inp[(size_t)(b * 255 + s - 1) * 768 + c];
  else v = tag[(size_t)(b * 255 + s - 1) * 256 + (c - 768)];
  u16 h = f2bf(v);
  xhi[gid] = h;
  xlo[gid] = f2bf(v - bf2f(h));
}

// ---- init h double-buffer (zeros) + flags (=1: h_0 ready) ----
__global__ void k_syncinit(float* hbuf, u32* flags) {
  int i = blockIdx.x * 256 + threadIdx.x;       // 32768 = 32*2*512
  if (i < 32768) hbuf[i] = 0.f;
  if (i < 128) flags[i] = 1u;
}

// ======== multi-block g-RNN scan: 4 blocks/batch, weights fully on-chip ========
// Block = (b, q): owns cols [q*128, q*128+128). Thread: col = q*128 + (tid&127),
// k-slice p = tid>>7 (128 k-values: 96 in VGPR + 32 in LDS). Per step, blocks
// exchange h segments via hbuf[b][s&1][512] + release/acquire flags (agent scope).
__global__ __launch_bounds__(512, 1) void k_gscan_mb(
    float* __restrict__ XW, const float* __restrict__ WT,
    const int* __restrict__ mask, int layer,
    float* hbuf, u32* flags)
{
  __shared__ float hls[512];
  __shared__ float wlds[4][32][128];
  __shared__ float part[4][128];
  const int blk = blockIdx.x;
  const int b = blk >> 2, q = blk & 3;
  const int tid = threadIdx.x;
  const int col = tid & 127;
  const int p = tid >> 7;
  const int c = (q << 7) + col;
  float wreg[96];
#pragma unroll
  for (int i = 0; i < 96; ++i)
    wreg[i] = WT[(size_t)(p * 128 + i) * 512 + c];
#pragma unroll 4
  for (int i = 0; i < 32; ++i)
    wlds[p][i][col] = WT[(size_t)(p * 128 + 96 + i) * 512 + c];
  float* hb = hbuf + b * 1024;
  u32* flg = flags + b * 4;
  __syncthreads();

  for (int s = 0; s < 256; ++s) {
    // wait for h_s (all 4 producer blocks of batch b)
    if (tid < 4) {
      while (__hip_atomic_load(&flg[tid], __ATOMIC_ACQUIRE, __HIP_MEMORY_SCOPE_AGENT)
             < (u32)(s + 1)) { }
    }
    __syncthreads();
    // load h_s -> LDS (relaxed agent atomic: reads coherence point, no stale L1/L2)
    hls[tid] = __hip_atomic_load(&hb[(s & 1) * 512 + tid], __ATOMIC_RELAXED,
                                 __HIP_MEMORY_SCOPE_AGENT);
    __syncthreads();
    const float* hk = &hls[p * 128];
    float a0 = 0.f, a1 = 0.f, a2 = 0.f, a3 = 0.f;
#pragma unroll
    for (int i = 0; i < 96; i += 4) {
      a0 = fmaf(wreg[i],     hk[i],     a0);
      a1 = fmaf(wreg[i + 1], hk[i + 1], a1);
      a2 = fmaf(wreg[i + 2], hk[i + 2], a2);
      a3 = fmaf(wreg[i + 3], hk[i + 3], a3);
    }
#pragma unroll
    for (int i = 0; i < 32; i += 4) {
      a0 = fmaf(wlds[p][i][col],     hk[96 + i],     a0);
      a1 = fmaf(wlds[p][i + 1][col], hk[96 + i + 1], a1);
      a2 = fmaf(wlds[p][i + 2][col], hk[96 + i + 2], a2);
      a3 = fmaf(wlds[p][i + 3][col], hk[96 + i + 3], a3);
    }
    part[p][col] = (a0 + a1) + (a2 + a3);
    __syncthreads();
    if (tid < 128) {
      size_t xwoff = (size_t)(b * 256 + s) * 512 + (q << 7) + tid;
      float v = part[0][tid] + part[1][tid] + part[2][tid] + part[3][tid] + XW[xwoff];
      float h = tanhf(v);
      float ov = h;
      if (layer) ov *= (s == 0) ? 1.f : (float)mask[b * 255 + s - 1];
      XW[xwoff] = ov;
      __hip_atomic_store(&hb[((s + 1) & 1) * 512 + (q << 7) + tid], h,
                         __ATOMIC_RELAXED, __HIP_MEMORY_SCOPE_AGENT);
    }
    __syncthreads();          // drains vmcnt: all h stores issued & complete
    if (tid == 0) {
      __hip_atomic_store(&flg[q], (u32)(s + 2), __ATOMIC_RELEASE,
                         __HIP_MEMORY_SCOPE_AGENT);
    }
  }
}

// ---------------- f32 -> bf16 convert / zero ----------------
__global__ void k_cvt(u16* __restrict__ dst, const float* __restrict__ src) {
  int i = blockIdx.x * 256 + threadIdx.x;
  dst[i] = f2bf(src[i]);
}
__global__ void k_zero(uint4* p) {
  p[(size_t)blockIdx.x * 256 + threadIdx.x] = uint4{0u, 0u, 0u, 0u};
}

// ======== Split-precision MFMA GEMM: C f32 = (Ahi+Alo)@(Whi+Wlo)^T + b1 + b2 ========
template<int KD>
__global__ __launch_bounds__(256, 2) void gemm_s(
    const u16* __restrict__ Ahi, const u16* __restrict__ Alo,
    const u16* __restrict__ Whi, const u16* __restrict__ Wlo,
    const float* __restrict__ b1, const float* __restrict__ b2,
    float* __restrict__ outf)
{
  __shared__ __attribute__((aligned(16))) u16 Ah[128 * 72];
  __shared__ __attribute__((aligned(16))) u16 Al[128 * 72];
  __shared__ __attribute__((aligned(16))) u16 Wh[64 * 72];
  __shared__ __attribute__((aligned(16))) u16 Wl[64 * 72];
  const int tid = threadIdx.x;
  const int lane = tid & 63, wid = tid >> 6;
  const int wr = wid >> 1, wc = wid & 1;
  const int m0 = blockIdx.y * 128, n0 = blockIdx.x * 64;

  f32x4 zero4 = {0.f, 0.f, 0.f, 0.f};
  f32x4 acc[4][2];
#pragma unroll
  for (int i = 0; i < 4; ++i)
#pragma unroll
    for (int j = 0; j < 2; ++j) acc[i][j] = zero4;

  for (int kt = 0; kt < KD / 64; ++kt) {
    __syncthreads();
#pragma unroll
    for (int i = 0; i < 4; ++i) {
      int c = tid + i * 256;
      int row = c >> 3, c8 = c & 7;
      size_t g = (size_t)(m0 + row) * KD + kt * 64 + c8 * 8;
      *(uint4*)(&Ah[row * 72 + c8 * 8]) = *(const uint4*)(Ahi + g);
      *(uint4*)(&Al[row * 72 + c8 * 8]) = *(const uint4*)(Alo + g);
    }
#pragma unroll
    for (int i = 0; i < 2; ++i) {
      int c = tid + i * 256;
      int row = c >> 3, c8 = c & 7;
      size_t g = (size_t)(n0 + row) * KD + kt * 64 + c8 * 8;
      *(uint4*)(&Wh[row * 72 + c8 * 8]) = *(const uint4*)(Whi + g);
      *(uint4*)(&Wl[row * 72 + c8 * 8]) = *(const uint4*)(Wlo + g);
    }
    __syncthreads();
#pragma unroll
    for (int ks = 0; ks < 2; ++ks) {
      short8 ah[4], al[4], wh[2], wl[2];
#pragma unroll
      for (int mm = 0; mm < 4; ++mm) {
        int row = wr * 64 + mm * 16 + (lane & 15);
        int off = row * 72 + ks * 32 + ((lane >> 4) << 3);
        ah[mm] = *(const short8*)(Ah + off);
        al[mm] = *(const short8*)(Al + off);
      }
#pragma unroll
      for (int nn = 0; nn < 2; ++nn) {
        int row = wc * 32 + nn * 16 + (lane & 15);
        int off = row * 72 + ks * 32 + ((lane >> 4) << 3);
        wh[nn] = *(const short8*)(Wh + off);
        wl[nn] = *(const short8*)(Wl + off);
      }
#pragma unroll
      for (int mm = 0; mm < 4; ++mm)
#pragma unroll
        for (int nn = 0; nn < 2; ++nn) {
          acc[mm][nn] = __builtin_amdgcn_mfma_f32_16x16x32_bf16(ah[mm], wh[nn], acc[mm][nn], 0, 0, 0);
          acc[mm][nn] = __builtin_amdgcn_mfma_f32_16x16x32_bf16(ah[mm], wl[nn], acc[mm][nn], 0, 0, 0);
          acc[mm][nn] = __builtin_amdgcn_mfma_f32_16x16x32_bf16(al[mm], wh[nn], acc[mm][nn], 0, 0, 0);
        }
    }
  }

  float bcol[2];
#pragma unroll
  for (int nn = 0; nn < 2; ++nn) {
    int col = n0 + wc * 32 + nn * 16 + (lane & 15);
    bcol[nn] = b1[col] + b2[col];
  }
#pragma unroll
  for (int mm = 0; mm < 4; ++mm)
#pragma unroll
    for (int r = 0; r < 4; ++r) {
      int grow = m0 + wr * 64 + mm * 16 + ((lane >> 4) << 2) + r;
#pragma unroll
      for (int nn = 0; nn < 2; ++nn) {
        int col = n0 + wc * 32 + nn * 16 + (lane & 15);
        outf[(size_t)grow * 512 + col] = acc[mm][nn][r] + bcol[nn];
      }
    }
}

// ======== Validated bf16 MFMA GEMM (modes 1/2/3) ========
template<int MODE, int KD>
__global__ __launch_bounds__(256, 2) void gemm_k(
    const u16* __restrict__ Ag, const u16* __restrict__ Ag2,
    const u16* __restrict__ Wg, const u16* __restrict__ W2g,
    const float* __restrict__ b1, const float* __restrict__ b2,
    u16* __restrict__ outb, float* __restrict__ outh, float* __restrict__ outd,
    float* __restrict__ abuf, const float* __restrict__ vecw, int estep)
{
  __shared__ __attribute__((aligned(16))) u16 As[128 * 72];
  __shared__ __attribute__((aligned(16))) u16 Ws[64 * 72];
  __shared__ float xes[128];
  const int tid = threadIdx.x;
  const int lane = tid & 63, wid = tid >> 6;
  const int wr = wid >> 1, wc = wid & 1;
  const int m0 = blockIdx.y * 128, n0 = blockIdx.x * 64;

  if constexpr (MODE == 2) {
    if (tid < 128) xes[tid] = abuf[(size_t)(m0 + tid) * 26 + estep];
  }

  f32x4 zero4 = {0.f, 0.f, 0.f, 0.f};
  f32x4 acc[4][2];
#pragma unroll
  for (int i = 0; i < 4; ++i)
#pragma unroll
    for (int j = 0; j < 2; ++j) acc[i][j] = zero4;

  for (int kt = 0; kt < KD / 64; ++kt) {
    const u16* Asrc; int ka;
    if (kt < 8) { Asrc = Ag;  ka = kt; }
    else        { Asrc = Ag2; ka = kt - 8; }
    const u16* Wsrc; int kw, rowoff;
    if constexpr (MODE == 1) {
      if (n0 >= 256) { Wsrc = W2g; rowoff = n0 - 256; }
      else           { Wsrc = Wg;  rowoff = n0; }
      kw = kt;
    } else {
      if (kt < 8) { Wsrc = Wg;  kw = kt; }
      else        { Wsrc = W2g; kw = kt - 8; }
      rowoff = n0;
    }
    __syncthreads();
#pragma unroll
    for (int i = 0; i < 4; ++i) {
      int c = tid + i * 256;
      int row = c >> 3, c8 = c & 7;
      uint4 v = *(const uint4*)(Asrc + (size_t)(m0 + row) * 512 + ka * 64 + c8 * 8);
      *(uint4*)(&As[row * 72 + c8 * 8]) = v;
    }
#pragma unroll
    for (int i = 0; i < 2; ++i) {
      int c = tid + i * 256;
      int row = c >> 3, c8 = c & 7;
      uint4 v = *(const uint4*)(Wsrc + (size_t)(rowoff + row) * 512 + kw * 64 + c8 * 8);
      *(uint4*)(&Ws[row * 72 + c8 * 8]) = v;
    }
    __syncthreads();
#pragma unroll
    for (int ks = 0; ks < 2; ++ks) {
      short8 af[4], bfv[2];
#pragma unroll
      for (int mm = 0; mm < 4; ++mm) {
        int row = wr * 64 + mm * 16 + (lane & 15);
        af[mm] = *(const short8*)(As + row * 72 + ks * 32 + ((lane >> 4) << 3));
      }
#pragma unroll
      for (int nn = 0; nn < 2; ++nn) {
        int row = wc * 32 + nn * 16 + (lane & 15);
        bfv[nn] = *(const short8*)(Ws + row * 72 + ks * 32 + ((lane >> 4) << 3));
      }
#pragma unroll
      for (int mm = 0; mm < 4; ++mm)
#pragma unroll
        for (int nn = 0; nn < 2; ++nn)
          acc[mm][nn] = __builtin_amdgcn_mfma_f32_16x16x32_bf16(af[mm], bfv[nn], acc[mm][nn], 0, 0, 0);
    }
  }

  float bcol[2], vcol[2];
#pragma unroll
  for (int nn = 0; nn < 2; ++nn) {
    int col = n0 + wc * 32 + nn * 16 + (lane & 15);
    if constexpr (MODE == 1) bcol[nn] = (col < 256) ? b1[col] : b2[col - 256];
    else                     bcol[nn] = b1[col] + b2[col];
    vcol[nn] = 0.0f;
    if constexpr (MODE == 2 || MODE == 3) vcol[nn] = vecw[col];
  }
  float pp[4][4];
#pragma unroll
  for (int i = 0; i < 4; ++i)
#pragma unroll
    for (int j = 0; j < 4; ++j) pp[i][j] = 0.0f;

#pragma unroll
  for (int mm = 0; mm < 4; ++mm) {
#pragma unroll
    for (int r = 0; r < 4; ++r) {
      int lrow = wr * 64 + mm * 16 + ((lane >> 4) << 2) + r;
      int grow = m0 + lrow;
#pragma unroll
      for (int nn = 0; nn < 2; ++nn) {
        int col = n0 + wc * 32 + nn * 16 + (lane & 15);
        float v = acc[mm][nn][r] + bcol[nn];
        if constexpr (MODE == 1) {
          float e = v > 0.f ? v : (expf(v) - 1.f);
          if (col < 256) outh[(size_t)grow * 256 + col] = e;
          else           outd[(size_t)grow * 256 + (col - 256)] = e;
        } else if constexpr (MODE == 2) {
          v += xes[lrow] * vcol[nn];
          outb[(size_t)grow * 512 + col] = f2bf(fast_tanh(v));
        } else {
          float h = fast_tanh(v);
          outb[(size_t)grow * 512 + col] = f2bf(h);
          pp[mm][r] += h * vcol[nn];
        }
      }
    }
  }
  if constexpr (MODE == 3) {
#pragma unroll
    for (int mm = 0; mm < 4; ++mm)
#pragma unroll
      for (int r = 0; r < 4; ++r) {
        float p = pp[mm][r];
        p += __shfl_xor(p, 1); p += __shfl_xor(p, 2);
        p += __shfl_xor(p, 4); p += __shfl_xor(p, 8);
        if ((lane & 15) == 0) {
          int grow = m0 + wr * 64 + mm * 16 + ((lane >> 4) << 2) + r;
          atomicAdd(&abuf[(size_t)grow * 26 + estep + 1], p);
        }
      }
  }
}

// ---------------- small helpers ----------------
__global__ void k_ainit(float* abuf, const float* clsb) {
  int idx = blockIdx.x * 256 + threadIdx.x;     // 212992
  if (idx >= 212992) return;
  abuf[idx] = ((idx % 26) == 0) ? 1.0f : clsb[0];
}
__global__ void k_arc(float* __restrict__ outp, const float* __restrict__ abuf) {
  int idx = blockIdx.x * 256 + threadIdx.x;     // 2097152
  int j = idx & 255, i = (idx >> 8) & 255, b = idx >> 16;
  int k = i - j;
  outp[idx] = (k >= 0 && k <= 25) ? abuf[(size_t)(b * 256 + i) * 26 + k] : 0.0f;
}
__global__ void k_diag(float* __restrict__ outp, float code, int n) {
  int idx = blockIdx.x * 256 + threadIdx.x;
  if (idx < n) outp[idx] = (idx == 0) ? code : 0.0f;
}

extern "C" void kernel_launch(void* const* d_in, const int* in_sizes, int n_in,
                              void* d_out, int out_size, void* d_ws, size_t ws_size,
                              hipStream_t stream) {
  static const int SZ[26] = {6266880, 2088960, 8160, 1024, 524288, 262144, 512, 512,
                             262144, 262144, 512, 512, 512, 262144, 512, 512,
                             262144, 262144, 512, 512, 512, 1, 131072, 256, 131072, 256};
  float diag_code = 0.0f;
  if (n_in != 26) diag_code = 4096.0f + (float)n_in;
  else {
    for (int j = 0; j < 26; ++j)
      if (in_sizes[j] != SZ[j]) { diag_code = 2048.0f + (float)j; break; }
  }
  const size_t NEED = (size_t)(32u << 20);   // round 8 proved ws >= 34.4 MB
  if (ws_size < NEED && diag_code == 0.0f) diag_code = 8192.0f;
  if (diag_code != 0.0f) {
    k_diag<<<(out_size + 255) / 256, 256, 0, stream>>>((float*)d_out, diag_code, out_size);
    return;
  }

  const float* inp  = (const float*)d_in[0];
  const float* tag  = (const float*)d_in[1];
  const int*   mask = (const int*)d_in[2];
  const float* sent = (const float*)d_in[3];
  const float* g0_Wih = (const float*)d_in[4];
  const float* g0_Whh = (const float*)d_in[5];
  const float* g0_bih = (const float*)d_in[6];
  const float* g0_bhh = (const float*)d_in[7];
  const float* g1_Wih = (const float*)d_in[8];
  const float* g1_Whh = (const float*)d_in[9];
  const float* g1_bih = (const float*)d_in[10];
  const float* g1_bhh = (const float*)d_in[11];
  const float* e0_Wih = (const float*)d_in[12];
  const float* e0_Whh = (const float*)d_in[13];
  const float* e0_bih = (const float*)d_in[14];
  const float* e0_bhh = (const float*)d_in[15];
  const float* e1_Wih = (const float*)d_in[16];
  const float* e1_Whh = (const float*)d_in[17];
  const float* e1_bih = (const float*)d_in[18];
  const float* e1_bhh = (const float*)d_in[19];
  const float* cls_W  = (const float*)d_in[20];
  const float* cls_b  = (const float*)d_in[21];
  const float* ht_W   = (const float*)d_in[22];
  const float* ht_b   = (const float*)d_in[23];
  const float* dt_W   = (const float*)d_in[24];
  const float* dt_b   = (const float*)d_in[25];

  float* out = (float*)d_out;               // 24 MB: [arc | head | dep] f32
  char*  ob  = (char*)d_out;
  char*  ws  = (char*)d_ws;

  // ---- d_out overlays (pre-output lifetimes) ----
  u16*  W0hi = (u16*)(ob);                  // [0,1M) g0_Wih hi
  u16*  W0lo = (u16*)(ob + (1u << 20));     // [1,2M)
  float* XW0 = (float*)(ob + (2u << 20));   // [2,18M) xW0 -> Y0 -> GS
  float* WT0 = (float*)(ob + (18u << 20));  // [18,19M)
  float* WT1 = (float*)(ob + (19u << 20));  // [19,20M)
  u16*  G1hi = (u16*)(ob + (20u << 20));    // [20,20.5M)
  u16*  G1lo = (u16*)(ob + (20u << 20) + (512u << 10));
  // ---- ws overlays ----
  u16*  Xhi  = (u16*)(ws);                  // [0,16M)
  u16*  Xlo  = (u16*)(ws + (16u << 20));    // [16,32M)
  u16*  Y0hi = (u16*)(ws);                  // [0,8M)   after X dead; later S0
  u16*  Y0lo = (u16*)(ws + (8u << 20));     // [8,16M)  later S1
  u16*  S0   = Y0hi;
  u16*  S1   = Y0lo;
  u16*  S2   = (u16*)(ws + (16u << 20));    // [16,24M)
  float* ABUF = (float*)(ws + (24u << 20)); // 852 KB
  u16*  W0b  = (u16*)(ws + (25u << 20));                      // e0_Whh bf16
  u16*  W1b  = (u16*)(ws + (25u << 20) + (512u << 10));       // e1_Wih
  u16*  W2b  = (u16*)(ws + (26u << 20));                      // e1_Whh
  u16*  W3b  = (u16*)(ws + (26u << 20) + (512u << 10));       // ht_W
  u16*  W4b  = (u16*)(ws + (26u << 20) + (768u << 10));       // dt_W
  float* HBUF = (float*)(ws + (28u << 20));                   // [32][2][512] f32
  u32*  FLG  = (u32*)(ws + (28u << 20) + 131072);             // [32][4]

  dim3 grid(8, 64);

  // 1) splits + transposes
  k_concat_split<<<32768, 256, 0, stream>>>(Xhi, Xlo, inp, tag, sent);
  k_split<<<2048, 256, 0, stream>>>(W0hi, W0lo, g0_Wih, 524288);
  k_transw<<<1024, 256, 0, stream>>>(WT0, g0_Whh);
  k_transw<<<1024, 256, 0, stream>>>(WT1, g1_Whh);
  k_split<<<1024, 256, 0, stream>>>(G1hi, G1lo, g1_Wih, 262144);

  // 2) xW0 (split-precision MFMA) -> XW0 ; multi-block scan0 in place -> Y0
  gemm_s<1024><<<grid, 256, 0, stream>>>(Xhi, Xlo, W0hi, W0lo, g0_bih, g0_bhh, XW0);
  k_syncinit<<<128, 256, 0, stream>>>(HBUF, FLG);
  k_gscan_mb<<<128, 512, 0, stream>>>(XW0, WT0, mask, 0, HBUF, FLG);

  // 3) split Y0 (X dead); xW1 -> XW0; multi-block scan1 in place -> GS (masked)
  k_split<<<16384, 256, 0, stream>>>(Y0hi, Y0lo, XW0, 4194304);
  gemm_s<512><<<grid, 256, 0, stream>>>(Y0hi, Y0lo, G1hi, G1lo, g1_bih, g1_bhh, XW0);
  k_syncinit<<<128, 256, 0, stream>>>(HBUF, FLG);
  k_gscan_mb<<<128, 512, 0, stream>>>(XW0, WT1, mask, 1, HBUF, FLG);

  // 4) GS -> bf16 S0; S1 = 0; edge/head weights -> bf16
  k_cvt<<<16384, 256, 0, stream>>>(S0, XW0);
  k_zero<<<2048, 256, 0, stream>>>((uint4*)S1);
  k_cvt<<<1024, 256, 0, stream>>>(W0b, e0_Whh);
  k_cvt<<<1024, 256, 0, stream>>>(W1b, e1_Wih);
  k_cvt<<<1024, 256, 0, stream>>>(W2b, e1_Whh);
  k_cvt<<<512, 256, 0, stream>>>(W3b, ht_W);
  k_cvt<<<512, 256, 0, stream>>>(W4b, dt_W);

  // 5) tag heads -> f32 head/dep in d_out (GS f32 dead)
  gemm_k<1, 512><<<grid, 256, 0, stream>>>(S0, nullptr, W3b, W4b, ht_b, dt_b,
                                           nullptr, out + 2097152, out + 4194304,
                                           nullptr, nullptr, 0);

  // 6) edge scan: 25 x (E0, E1), triple-buffer rotation
  k_ainit<<<832, 256, 0, stream>>>(ABUF, cls_b);
  u16* r0 = S0; u16* r1 = S1; u16* r2 = S2;
  for (int st = 0; st < 25; ++st) {
    gemm_k<2, 512><<<grid, 256, 0, stream>>>(r0, nullptr, W0b, nullptr, e0_bih, e0_bhh,
                                             r2, nullptr, nullptr, ABUF, e0_Wih, st);
    gemm_k<3, 1024><<<grid, 256, 0, stream>>>(r2, r1, W1b, W2b, e1_bih, e1_bhh,
                                              r0, nullptr, nullptr, ABUF, cls_W, st);
    u16* t0 = r2; u16* t1 = r0; u16* t2 = r1;
    r0 = t0; r1 = t1; r2 = t2;
  }
  // 7) arc gather
  k_arc<<<8192, 256, 0, stream>>>(out, ABUF);
}

// Round 16
// 2950.428 us; speedup vs baseline: 10.6738x; 1.4424x over previous
//
#include <hip/hip_runtime.h>
#include <math.h>

typedef unsigned int u32;
typedef unsigned short u16;
typedef unsigned long long u64;
typedef __attribute__((ext_vector_type(8))) short short8;
typedef __attribute__((ext_vector_type(4))) float f32x4;

__device__ inline float bf2f(u16 v) { return __uint_as_float(((u32)v) << 16); }
__device__ inline u16 f2bf(float f) {
  u32 u = __float_as_uint(f);
  return (u16)((u + 0x7fffu + ((u >> 16) & 1u)) >> 16);
}
__device__ inline float fast_tanh(float x) {
  x = fminf(9.0f, fmaxf(-9.0f, x));
  float e = __builtin_amdgcn_exp2f(x * 2.8853900817779268f);
  return (e - 1.0f) * __builtin_amdgcn_rcpf(e + 1.0f);
}

// ---- transpose Whh (f32 [512][512]) -> WT[k][t] ----
__global__ void k_transw(float* __restrict__ outp, const float* __restrict__ src) {
  int idx = blockIdx.x * 256 + threadIdx.x;     // 262144
  int k = idx & 511, t = idx >> 9;
  outp[(size_t)k * 512 + t] = src[(size_t)t * 512 + k];
}

// ---- hi/lo bf16 split of an f32 array ----
__global__ void k_split(u16* __restrict__ hi, u16* __restrict__ lo,
                        const float* __restrict__ src, int n) {
  int i = blockIdx.x * 256 + threadIdx.x;
  if (i >= n) return;
  float v = src[i];
  u16 h = f2bf(v);
  hi[i] = h;
  lo[i] = f2bf(v - bf2f(h));
}

// ---- concat + split: X[8192][1024] = [sent | inp|tag] -> Xhi/Xlo bf16 ----
__global__ void k_concat_split(u16* __restrict__ xhi, u16* __restrict__ xlo,
                               const float* __restrict__ inp, const float* __restrict__ tag,
                               const float* __restrict__ sent) {
  int gid = blockIdx.x * 256 + threadIdx.x;     // 8388608
  int row = gid >> 10, c = gid & 1023;
  int b = row >> 8, s = row & 255;
  float v;
  if (s == 0) v = sent[c];
  else if (c < 768) v = inp[(size_t)(b * 255 + s - 1) * 768 + c];
  else v = tag[(size_t)(b * 255 + s - 1) * 256 + (c - 768)];
  u16 h = f2bf(v);
  xhi[gid] = h;
  xlo[gid] = f2bf(v - bf2f(h));
}

// ---- init tagged h double-buffer: slot0 = (tag1, h=0), slot1 = tag0 ----
__global__ void k_syncinit(u64* hbuf) {
  int i = blockIdx.x * 256 + threadIdx.x;       // 32768 = 32*2*512
  if (i < 32768) {
    int pos = i & 1023;
    hbuf[i] = (pos < 512) ? (1ull << 32) : 0ull;
  }
}

// ======== multi-block g-RNN scan, single-round-trip tagged sync ========
// Block = (b, q): owns cols [q*128, q*128+128). hbuf[b][s&1][512] u64 = (tag, h bits).
// Tag of h_s is s+1. Consumer thread polls its own element until tag >= s+1.
__global__ __launch_bounds__(512, 1) void k_gscan_mb(
    float* __restrict__ XW, const float* __restrict__ WT,
    const int* __restrict__ mask, int layer, u64* hbuf)
{
  __shared__ float hls[512];
  __shared__ float wlds[4][32][128];
  __shared__ float part[4][128];
  const int blk = blockIdx.x;
  const int b = blk >> 2, q = blk & 3;
  const int tid = threadIdx.x;
  const int col = tid & 127;
  const int p = tid >> 7;
  const int c = (q << 7) + col;
  float wreg[96];
#pragma unroll
  for (int i = 0; i < 96; ++i)
    wreg[i] = WT[(size_t)(p * 128 + i) * 512 + c];
#pragma unroll 4
  for (int i = 0; i < 32; ++i)
    wlds[p][i][col] = WT[(size_t)(p * 128 + 96 + i) * 512 + c];
  u64* hb = hbuf + b * 1024;
  __syncthreads();

  for (int s = 0; s < 256; ++s) {
    // prefetch XW row element (independent of the poll)
    float xwv = 0.f;
    size_t xwoff = 0;
    if (tid < 128) {
      xwoff = (size_t)(b * 256 + s) * 512 + (q << 7) + tid;
      xwv = XW[xwoff];
    }
    // poll own h element: tag == data (one round trip)
    const u32 want = (u32)(s + 1);
    u64 v;
    do {
      v = __hip_atomic_load(&hb[(s & 1) * 512 + tid], __ATOMIC_RELAXED,
                            __HIP_MEMORY_SCOPE_AGENT);
    } while ((u32)(v >> 32) < want);
    hls[tid] = __uint_as_float((u32)v);
    __syncthreads();
    const float* hk = &hls[p * 128];
    float a0 = 0.f, a1 = 0.f, a2 = 0.f, a3 = 0.f;
#pragma unroll
    for (int i = 0; i < 96; i += 4) {
      a0 = fmaf(wreg[i],     hk[i],     a0);
      a1 = fmaf(wreg[i + 1], hk[i + 1], a1);
      a2 = fmaf(wreg[i + 2], hk[i + 2], a2);
      a3 = fmaf(wreg[i + 3], hk[i + 3], a3);
    }
#pragma unroll
    for (int i = 0; i < 32; i += 4) {
      a0 = fmaf(wlds[p][i][col],     hk[96 + i],     a0);
      a1 = fmaf(wlds[p][i + 1][col], hk[96 + i + 1], a1);
      a2 = fmaf(wlds[p][i + 2][col], hk[96 + i + 2], a2);
      a3 = fmaf(wlds[p][i + 3][col], hk[96 + i + 3], a3);
    }
    part[p][col] = (a0 + a1) + (a2 + a3);
    __syncthreads();
    if (tid < 128) {
      float vsum = part[0][tid] + part[1][tid] + part[2][tid] + part[3][tid] + xwv;
      float h = tanhf(vsum);
      float ov = h;
      if (layer) ov *= (s == 0) ? 1.f : (float)mask[b * 255 + s - 1];
      XW[xwoff] = ov;
      u64 pk = ((u64)(u32)(s + 2) << 32) | (u64)__float_as_uint(h);
      __hip_atomic_store(&hb[((s + 1) & 1) * 512 + (q << 7) + tid], pk,
                         __ATOMIC_RELAXED, __HIP_MEMORY_SCOPE_AGENT);
    }
  }
}

// ---------------- f32 -> bf16 convert / zero ----------------
__global__ void k_cvt(u16* __restrict__ dst, const float* __restrict__ src) {
  int i = blockIdx.x * 256 + threadIdx.x;
  dst[i] = f2bf(src[i]);
}
__global__ void k_zero(uint4* p) {
  p[(size_t)blockIdx.x * 256 + threadIdx.x] = uint4{0u, 0u, 0u, 0u};
}

// ======== Split-precision MFMA GEMM: C f32 = (Ahi+Alo)@(Whi+Wlo)^T + b1 + b2 ========
template<int KD>
__global__ __launch_bounds__(256, 2) void gemm_s(
    const u16* __restrict__ Ahi, const u16* __restrict__ Alo,
    const u16* __restrict__ Whi, const u16* __restrict__ Wlo,
    const float* __restrict__ b1, const float* __restrict__ b2,
    float* __restrict__ outf)
{
  __shared__ __attribute__((aligned(16))) u16 Ah[128 * 72];
  __shared__ __attribute__((aligned(16))) u16 Al[128 * 72];
  __shared__ __attribute__((aligned(16))) u16 Wh[64 * 72];
  __shared__ __attribute__((aligned(16))) u16 Wl[64 * 72];
  const int tid = threadIdx.x;
  const int lane = tid & 63, wid = tid >> 6;
  const int wr = wid >> 1, wc = wid & 1;
  const int m0 = blockIdx.y * 128, n0 = blockIdx.x * 64;

  f32x4 zero4 = {0.f, 0.f, 0.f, 0.f};
  f32x4 acc[4][2];
#pragma unroll
  for (int i = 0; i < 4; ++i)
#pragma unroll
    for (int j = 0; j < 2; ++j) acc[i][j] = zero4;

  for (int kt = 0; kt < KD / 64; ++kt) {
    __syncthreads();
#pragma unroll
    for (int i = 0; i < 4; ++i) {
      int c = tid + i * 256;
      int row = c >> 3, c8 = c & 7;
      size_t g = (size_t)(m0 + row) * KD + kt * 64 + c8 * 8;
      *(uint4*)(&Ah[row * 72 + c8 * 8]) = *(const uint4*)(Ahi + g);
      *(uint4*)(&Al[row * 72 + c8 * 8]) = *(const uint4*)(Alo + g);
    }
#pragma unroll
    for (int i = 0; i < 2; ++i) {
      int c = tid + i * 256;
      int row = c >> 3, c8 = c & 7;
      size_t g = (size_t)(n0 + row) * KD + kt * 64 + c8 * 8;
      *(uint4*)(&Wh[row * 72 + c8 * 8]) = *(const uint4*)(Whi + g);
      *(uint4*)(&Wl[row * 72 + c8 * 8]) = *(const uint4*)(Wlo + g);
    }
    __syncthreads();
#pragma unroll
    for (int ks = 0; ks < 2; ++ks) {
      short8 ah[4], al[4], wh[2], wl[2];
#pragma unroll
      for (int mm = 0; mm < 4; ++mm) {
        int row = wr * 64 + mm * 16 + (lane & 15);
        int off = row * 72 + ks * 32 + ((lane >> 4) << 3);
        ah[mm] = *(const short8*)(Ah + off);
        al[mm] = *(const short8*)(Al + off);
      }
#pragma unroll
      for (int nn = 0; nn < 2; ++nn) {
        int row = wc * 32 + nn * 16 + (lane & 15);
        int off = row * 72 + ks * 32 + ((lane >> 4) << 3);
        wh[nn] = *(const short8*)(Wh + off);
        wl[nn] = *(const short8*)(Wl + off);
      }
#pragma unroll
      for (int mm = 0; mm < 4; ++mm)
#pragma unroll
        for (int nn = 0; nn < 2; ++nn) {
          acc[mm][nn] = __builtin_amdgcn_mfma_f32_16x16x32_bf16(ah[mm], wh[nn], acc[mm][nn], 0, 0, 0);
          acc[mm][nn] = __builtin_amdgcn_mfma_f32_16x16x32_bf16(ah[mm], wl[nn], acc[mm][nn], 0, 0, 0);
          acc[mm][nn] = __builtin_amdgcn_mfma_f32_16x16x32_bf16(al[mm], wh[nn], acc[mm][nn], 0, 0, 0);
        }
    }
  }

  float bcol[2];
#pragma unroll
  for (int nn = 0; nn < 2; ++nn) {
    int col = n0 + wc * 32 + nn * 16 + (lane & 15);
    bcol[nn] = b1[col] + b2[col];
  }
#pragma unroll
  for (int mm = 0; mm < 4; ++mm)
#pragma unroll
    for (int r = 0; r < 4; ++r) {
      int grow = m0 + wr * 64 + mm * 16 + ((lane >> 4) << 2) + r;
#pragma unroll
      for (int nn = 0; nn < 2; ++nn) {
        int col = n0 + wc * 32 + nn * 16 + (lane & 15);
        outf[(size_t)grow * 512 + col] = acc[mm][nn][r] + bcol[nn];
      }
    }
}

// ======== Validated bf16 MFMA GEMM (modes 1/2/3) ========
template<int MODE, int KD>
__global__ __launch_bounds__(256, 2) void gemm_k(
    const u16* __restrict__ Ag, const u16* __restrict__ Ag2,
    const u16* __restrict__ Wg, const u16* __restrict__ W2g,
    const float* __restrict__ b1, const float* __restrict__ b2,
    u16* __restrict__ outb, float* __restrict__ outh, float* __restrict__ outd,
    float* __restrict__ abuf, const float* __restrict__ vecw, int estep)
{
  __shared__ __attribute__((aligned(16))) u16 As[128 * 72];
  __shared__ __attribute__((aligned(16))) u16 Ws[64 * 72];
  __shared__ float xes[128];
  const int tid = threadIdx.x;
  const int lane = tid & 63, wid = tid >> 6;
  const int wr = wid >> 1, wc = wid & 1;
  const int m0 = blockIdx.y * 128, n0 = blockIdx.x * 64;

  if constexpr (MODE == 2) {
    if (tid < 128) xes[tid] = abuf[(size_t)(m0 + tid) * 26 + estep];
  }

  f32x4 zero4 = {0.f, 0.f, 0.f, 0.f};
  f32x4 acc[4][2];
#pragma unroll
  for (int i = 0; i < 4; ++i)
#pragma unroll
    for (int j = 0; j < 2; ++j) acc[i][j] = zero4;

  for (int kt = 0; kt < KD / 64; ++kt) {
    const u16* Asrc; int ka;
    if (kt < 8) { Asrc = Ag;  ka = kt; }
    else        { Asrc = Ag2; ka = kt - 8; }
    const u16* Wsrc; int kw, rowoff;
    if constexpr (MODE == 1) {
      if (n0 >= 256) { Wsrc = W2g; rowoff = n0 - 256; }
      else           { Wsrc = Wg;  rowoff = n0; }
      kw = kt;
    } else {
      if (kt < 8) { Wsrc = Wg;  kw = kt; }
      else        { Wsrc = W2g; kw = kt - 8; }
      rowoff = n0;
    }
    __syncthreads();
#pragma unroll
    for (int i = 0; i < 4; ++i) {
      int c = tid + i * 256;
      int row = c >> 3, c8 = c & 7;
      uint4 v = *(const uint4*)(Asrc + (size_t)(m0 + row) * 512 + ka * 64 + c8 * 8);
      *(uint4*)(&As[row * 72 + c8 * 8]) = v;
    }
#pragma unroll
    for (int i = 0; i < 2; ++i) {
      int c = tid + i * 256;
      int row = c >> 3, c8 = c & 7;
      uint4 v = *(const uint4*)(Wsrc + (size_t)(rowoff + row) * 512 + kw * 64 + c8 * 8);
      *(uint4*)(&Ws[row * 72 + c8 * 8]) = v;
    }
    __syncthreads();
#pragma unroll
    for (int ks = 0; ks < 2; ++ks) {
      short8 af[4], bfv[2];
#pragma unroll
      for (int mm = 0; mm < 4; ++mm) {
        int row = wr * 64 + mm * 16 + (lane & 15);
        af[mm] = *(const short8*)(As + row * 72 + ks * 32 + ((lane >> 4) << 3));
      }
#pragma unroll
      for (int nn = 0; nn < 2; ++nn) {
        int row = wc * 32 + nn * 16 + (lane & 15);
        bfv[nn] = *(const short8*)(Ws + row * 72 + ks * 32 + ((lane >> 4) << 3));
      }
#pragma unroll
      for (int mm = 0; mm < 4; ++mm)
#pragma unroll
        for (int nn = 0; nn < 2; ++nn)
          acc[mm][nn] = __builtin_amdgcn_mfma_f32_16x16x32_bf16(af[mm], bfv[nn], acc[mm][nn], 0, 0, 0);
    }
  }

  float bcol[2], vcol[2];
#pragma unroll
  for (int nn = 0; nn < 2; ++nn) {
    int col = n0 + wc * 32 + nn * 16 + (lane & 15);
    if constexpr (MODE == 1) bcol[nn] = (col < 256) ? b1[col] : b2[col - 256];
    else                     bcol[nn] = b1[col] + b2[col];
    vcol[nn] = 0.0f;
    if constexpr (MODE == 2 || MODE == 3) vcol[nn] = vecw[col];
  }
  float pp[4][4];
#pragma unroll
  for (int i = 0; i < 4; ++i)
#pragma unroll
    for (int j = 0; j < 4; ++j) pp[i][j] = 0.0f;

#pragma unroll
  for (int mm = 0; mm < 4; ++mm) {
#pragma unroll
    for (int r = 0; r < 4; ++r) {
      int lrow = wr * 64 + mm * 16 + ((lane >> 4) << 2) + r;
      int grow = m0 + lrow;
#pragma unroll
      for (int nn = 0; nn < 2; ++nn) {
        int col = n0 + wc * 32 + nn * 16 + (lane & 15);
        float v = acc[mm][nn][r] + bcol[nn];
        if constexpr (MODE == 1) {
          float e = v > 0.f ? v : (expf(v) - 1.f);
          if (col < 256) outh[(size_t)grow * 256 + col] = e;
          else           outd[(size_t)grow * 256 + (col - 256)] = e;
        } else if constexpr (MODE == 2) {
          v += xes[lrow] * vcol[nn];
          outb[(size_t)grow * 512 + col] = f2bf(fast_tanh(v));
        } else {
          float h = fast_tanh(v);
          outb[(size_t)grow * 512 + col] = f2bf(h);
          pp[mm][r] += h * vcol[nn];
        }
      }
    }
  }
  if constexpr (MODE == 3) {
#pragma unroll
    for (int mm = 0; mm < 4; ++mm)
#pragma unroll
      for (int r = 0; r < 4; ++r) {
        float p = pp[mm][r];
        p += __shfl_xor(p, 1); p += __shfl_xor(p, 2);
        p += __shfl_xor(p, 4); p += __shfl_xor(p, 8);
        if ((lane & 15) == 0) {
          int grow = m0 + wr * 64 + mm * 16 + ((lane >> 4) << 2) + r;
          atomicAdd(&abuf[(size_t)grow * 26 + estep + 1], p);
        }
      }
  }
}

// ---------------- small helpers ----------------
__global__ void k_ainit(float* abuf, const float* clsb) {
  int idx = blockIdx.x * 256 + threadIdx.x;     // 212992
  if (idx >= 212992) return;
  abuf[idx] = ((idx % 26) == 0) ? 1.0f : clsb[0];
}
__global__ void k_arc(float* __restrict__ outp, const float* __restrict__ abuf) {
  int idx = blockIdx.x * 256 + threadIdx.x;     // 2097152
  int j = idx & 255, i = (idx >> 8) & 255, b = idx >> 16;
  int k = i - j;
  outp[idx] = (k >= 0 && k <= 25) ? abuf[(size_t)(b * 256 + i) * 26 + k] : 0.0f;
}
__global__ void k_diag(float* __restrict__ outp, float code, int n) {
  int idx = blockIdx.x * 256 + threadIdx.x;
  if (idx < n) outp[idx] = (idx == 0) ? code : 0.0f;
}

extern "C" void kernel_launch(void* const* d_in, const int* in_sizes, int n_in,
                              void* d_out, int out_size, void* d_ws, size_t ws_size,
                              hipStream_t stream) {
  static const int SZ[26] = {6266880, 2088960, 8160, 1024, 524288, 262144, 512, 512,
                             262144, 262144, 512, 512, 512, 262144, 512, 512,
                             262144, 262144, 512, 512, 512, 1, 131072, 256, 131072, 256};
  float diag_code = 0.0f;
  if (n_in != 26) diag_code = 4096.0f + (float)n_in;
  else {
    for (int j = 0; j < 26; ++j)
      if (in_sizes[j] != SZ[j]) { diag_code = 2048.0f + (float)j; break; }
  }
  const size_t NEED = (size_t)(32u << 20);   // round 8 proved ws >= 34.4 MB
  if (ws_size < NEED && diag_code == 0.0f) diag_code = 8192.0f;
  if (diag_code != 0.0f) {
    k_diag<<<(out_size + 255) / 256, 256, 0, stream>>>((float*)d_out, diag_code, out_size);
    return;
  }

  const float* inp  = (const float*)d_in[0];
  const float* tag  = (const float*)d_in[1];
  const int*   mask = (const int*)d_in[2];
  const float* sent = (const float*)d_in[3];
  const float* g0_Wih = (const float*)d_in[4];
  const float* g0_Whh = (const float*)d_in[5];
  const float* g0_bih = (const float*)d_in[6];
  const float* g0_bhh = (const float*)d_in[7];
  const float* g1_Wih = (const float*)d_in[8];
  const float* g1_Whh = (const float*)d_in[9];
  const float* g1_bih = (const float*)d_in[10];
  const float* g1_bhh = (const float*)d_in[11];
  const float* e0_Wih = (const float*)d_in[12];
  const float* e0_Whh = (const float*)d_in[13];
  const float* e0_bih = (const float*)d_in[14];
  const float* e0_bhh = (const float*)d_in[15];
  const float* e1_Wih = (const float*)d_in[16];
  const float* e1_Whh = (const float*)d_in[17];
  const float* e1_bih = (const float*)d_in[18];
  const float* e1_bhh = (const float*)d_in[19];
  const float* cls_W  = (const float*)d_in[20];
  const float* cls_b  = (const float*)d_in[21];
  const float* ht_W   = (const float*)d_in[22];
  const float* ht_b   = (const float*)d_in[23];
  const float* dt_W   = (const float*)d_in[24];
  const float* dt_b   = (const float*)d_in[25];

  float* out = (float*)d_out;               // 24 MB: [arc | head | dep] f32
  char*  ob  = (char*)d_out;
  char*  ws  = (char*)d_ws;

  // ---- d_out overlays (pre-output lifetimes) ----
  u16*  W0hi = (u16*)(ob);                  // [0,1M) g0_Wih hi
  u16*  W0lo = (u16*)(ob + (1u << 20));     // [1,2M)
  float* XW0 = (float*)(ob + (2u << 20));   // [2,18M) xW0 -> Y0 -> GS
  float* WT0 = (float*)(ob + (18u << 20));  // [18,19M)
  float* WT1 = (float*)(ob + (19u << 20));  // [19,20M)
  u16*  G1hi = (u16*)(ob + (20u << 20));    // [20,20.5M)
  u16*  G1lo = (u16*)(ob + (20u << 20) + (512u << 10));
  // ---- ws overlays ----
  u16*  Xhi  = (u16*)(ws);                  // [0,16M)
  u16*  Xlo  = (u16*)(ws + (16u << 20));    // [16,32M)
  u16*  Y0hi = (u16*)(ws);                  // [0,8M)   after X dead; later S0
  u16*  Y0lo = (u16*)(ws + (8u << 20));     // [8,16M)  later S1
  u16*  S0   = Y0hi;
  u16*  S1   = Y0lo;
  u16*  S2   = (u16*)(ws + (16u << 20));    // [16,24M)
  float* ABUF = (float*)(ws + (24u << 20)); // 852 KB
  u16*  W0b  = (u16*)(ws + (25u << 20));                      // e0_Whh bf16
  u16*  W1b  = (u16*)(ws + (25u << 20) + (512u << 10));       // e1_Wih
  u16*  W2b  = (u16*)(ws + (26u << 20));                      // e1_Whh
  u16*  W3b  = (u16*)(ws + (26u << 20) + (512u << 10));       // ht_W
  u16*  W4b  = (u16*)(ws + (26u << 20) + (768u << 10));       // dt_W
  u64*  HBUF = (u64*)(ws + (28u << 20));                      // [32][2][512] u64

  dim3 grid(8, 64);

  // 1) splits + transposes
  k_concat_split<<<32768, 256, 0, stream>>>(Xhi, Xlo, inp, tag, sent);
  k_split<<<2048, 256, 0, stream>>>(W0hi, W0lo, g0_Wih, 524288);
  k_transw<<<1024, 256, 0, stream>>>(WT0, g0_Whh);
  k_transw<<<1024, 256, 0, stream>>>(WT1, g1_Whh);
  k_split<<<1024, 256, 0, stream>>>(G1hi, G1lo, g1_Wih, 262144);

  // 2) xW0 (split-precision MFMA) -> XW0 ; multi-block scan0 in place -> Y0
  gemm_s<1024><<<grid, 256, 0, stream>>>(Xhi, Xlo, W0hi, W0lo, g0_bih, g0_bhh, XW0);
  k_syncinit<<<128, 256, 0, stream>>>(HBUF);
  k_gscan_mb<<<128, 512, 0, stream>>>(XW0, WT0, mask, 0, HBUF);

  // 3) split Y0 (X dead); xW1 -> XW0; multi-block scan1 in place -> GS (masked)
  k_split<<<16384, 256, 0, stream>>>(Y0hi, Y0lo, XW0, 4194304);
  gemm_s<512><<<grid, 256, 0, stream>>>(Y0hi, Y0lo, G1hi, G1lo, g1_bih, g1_bhh, XW0);
  k_syncinit<<<128, 256, 0, stream>>>(HBUF);
  k_gscan_mb<<<128, 512, 0, stream>>>(XW0, WT1, mask, 1, HBUF);

  // 4) GS -> bf16 S0; S1 = 0; edge/head weights -> bf16
  k_cvt<<<16384, 256, 0, stream>>>(S0, XW0);
  k_zero<<<2048, 256, 0, stream>>>((uint4*)S1);
  k_cvt<<<1024, 256, 0, stream>>>(W0b, e0_Whh);
  k_cvt<<<1024, 256, 0, stream>>>(W1b, e1_Wih);
  k_cvt<<<1024, 256, 0, stream>>>(W2b, e1_Whh);
  k_cvt<<<512, 256, 0, stream>>>(W3b, ht_W);
  k_cvt<<<512, 256, 0, stream>>>(W4b, dt_W);

  // 5) tag heads -> f32 head/dep in d_out (GS f32 dead)
  gemm_k<1, 512><<<grid, 256, 0, stream>>>(S0, nullptr, W3b, W4b, ht_b, dt_b,
                                           nullptr, out + 2097152, out + 4194304,
                                           nullptr, nullptr, 0);

  // 6) edge scan: 25 x (E0, E1), triple-buffer rotation
  k_ainit<<<832, 256, 0, stream>>>(ABUF, cls_b);
  u16* r0 = S0; u16* r1 = S1; u16* r2 = S2;
  for (int st = 0; st < 25; ++st) {
    gemm_k<2, 512><<<grid, 256, 0, stream>>>(r0, nullptr, W0b, nullptr, e0_bih, e0_bhh,
                                             r2, nullptr, nullptr, ABUF, e0_Wih, st);
    gemm_k<3, 1024><<<grid, 256, 0, stream>>>(r2, r1, W1b, W2b, e1_bih, e1_bhh,
                                              r0, nullptr, nullptr, ABUF, cls_W, st);
    u16* t0 = r2; u16* t1 = r0; u16* t2 = r1;
    r0 = t0; r1 = t1; r2 = t2;
  }
  // 7) arc gather
  k_arc<<<8192, 256, 0, stream>>>(out, ABUF);
}

// Round 17
// 2202.282 us; speedup vs baseline: 14.2998x; 1.3397x over previous
//
#include <hip/hip_runtime.h>
#include <math.h>

typedef unsigned int u32;
typedef unsigned short u16;
typedef unsigned long long u64;
typedef __attribute__((ext_vector_type(8))) short short8;
typedef __attribute__((ext_vector_type(4))) float f32x4;

__device__ inline float bf2f(u16 v) { return __uint_as_float(((u32)v) << 16); }
__device__ inline u16 f2bf(float f) {
  u32 u = __float_as_uint(f);
  return (u16)((u + 0x7fffu + ((u >> 16) & 1u)) >> 16);
}
__device__ inline float fast_tanh(float x) {
  x = fminf(9.0f, fmaxf(-9.0f, x));
  float e = __builtin_amdgcn_exp2f(x * 2.8853900817779268f);
  return (e - 1.0f) * __builtin_amdgcn_rcpf(e + 1.0f);
}
__device__ inline void gload16(const void* g, void* l) {
  __builtin_amdgcn_global_load_lds((const __attribute__((address_space(1))) u32*)g,
                                   (__attribute__((address_space(3))) u32*)l, 16, 0, 0);
}

// ---- transpose Whh (f32 [512][512]) -> WT[k][t] ----
__global__ void k_transw(float* __restrict__ outp, const float* __restrict__ src) {
  int idx = blockIdx.x * 256 + threadIdx.x;     // 262144
  int k = idx & 511, t = idx >> 9;
  outp[(size_t)k * 512 + t] = src[(size_t)t * 512 + k];
}

// ---- hi/lo bf16 split of an f32 array ----
__global__ void k_split(u16* __restrict__ hi, u16* __restrict__ lo,
                        const float* __restrict__ src, int n) {
  int i = blockIdx.x * 256 + threadIdx.x;
  if (i >= n) return;
  float v = src[i];
  u16 h = f2bf(v);
  hi[i] = h;
  lo[i] = f2bf(v - bf2f(h));
}

// ---- concat + split: X[8192][1024] = [sent | inp|tag] -> Xhi/Xlo bf16 ----
__global__ void k_concat_split(u16* __restrict__ xhi, u16* __restrict__ xlo,
                               const float* __restrict__ inp, const float* __restrict__ tag,
                               const float* __restrict__ sent) {
  int gid = blockIdx.x * 256 + threadIdx.x;     // 8388608
  int row = gid >> 10, c = gid & 1023;
  int b = row >> 8, s = row & 255;
  float v;
  if (s == 0) v = sent[c];
  else if (c < 768) v = inp[(size_t)(b * 255 + s - 1) * 768 + c];
  else v = tag[(size_t)(b * 255 + s - 1) * 256 + (c - 768)];
  u16 h = f2bf(v);
  xhi[gid] = h;
  xlo[gid] = f2bf(v - bf2f(h));
}

// ---- init tagged h double-buffer: slot0 = (tag1, h=0), slot1 = tag0 ----
__global__ void k_syncinit(u64* hbuf) {
  int i = blockIdx.x * 256 + threadIdx.x;       // 32768 = 32*2*512
  if (i < 32768) {
    int pos = i & 1023;
    hbuf[i] = (pos < 512) ? (1ull << 32) : 0ull;
  }
}

// ======== multi-block g-RNN scan, tagged sync + wave-internal k-slices ========
// Block (b,q) owns cols [q*128,q*128+128). Wave wv: cols wv*16+(lane&15); p=(lane>>4)&3
// is the k-slice (128 k each, all in VGPR). Reduce across p via shfl_xor(16/32).
__global__ __launch_bounds__(512, 1) void k_gscan_mb(
    float* __restrict__ XW, const float* __restrict__ WT,
    const int* __restrict__ mask, int layer, u64* hbuf)
{
  __shared__ float hls[512];
  const int blk = blockIdx.x;
  const int b = blk >> 2, q = blk & 3;
  const int tid = threadIdx.x;
  const int lane = tid & 63;
  const int wv = tid >> 6;
  const int colL = wv * 16 + (lane & 15);       // 0..127
  const int p = (lane >> 4) & 3;                // k-slice
  const int c = (q << 7) + colL;                // global col
  const bool fin = (p == 0);
  float wreg[128];
#pragma unroll
  for (int i = 0; i < 128; ++i)
    wreg[i] = WT[(size_t)(p * 128 + i) * 512 + c];
  u64* hb = hbuf + b * 1024;
  __syncthreads();

  for (int s = 0; s < 256; ++s) {
    // prefetch XW element (finishing lanes only), independent of the poll
    float xwv = 0.f;
    size_t xwoff = 0;
    if (fin) {
      xwoff = (size_t)(b * 256 + s) * 512 + c;
      xwv = XW[xwoff];
    }
    // poll own h element: tag travels with data (single round trip)
    const u32 want = (u32)(s + 1);
    u64 v;
    do {
      v = __hip_atomic_load(&hb[(s & 1) * 512 + tid], __ATOMIC_RELAXED,
                            __HIP_MEMORY_SCOPE_AGENT);
    } while ((u32)(v >> 32) < want);
    hls[tid] = __uint_as_float((u32)v);
    __syncthreads();
    const float* hk = &hls[p * 128];
    float a0 = 0.f, a1 = 0.f, a2 = 0.f, a3 = 0.f;
#pragma unroll
    for (int i = 0; i < 128; i += 4) {
      a0 = fmaf(wreg[i],     hk[i],     a0);
      a1 = fmaf(wreg[i + 1], hk[i + 1], a1);
      a2 = fmaf(wreg[i + 2], hk[i + 2], a2);
      a3 = fmaf(wreg[i + 3], hk[i + 3], a3);
    }
    float r = (a0 + a1) + (a2 + a3);
    r += __shfl_xor(r, 16);
    r += __shfl_xor(r, 32);
    if (fin) {
      float h = tanhf(r + xwv);
      u64 pk = ((u64)(u32)(s + 2) << 32) | (u64)__float_as_uint(h);
      __hip_atomic_store(&hb[((s + 1) & 1) * 512 + c], pk,
                         __ATOMIC_RELAXED, __HIP_MEMORY_SCOPE_AGENT);
      float ov = h;
      if (layer) ov *= (s == 0) ? 1.f : (float)mask[b * 255 + s - 1];
      XW[xwoff] = ov;
    }
    __syncthreads();   // hls stable until all lanes finished reading
  }
}

// ---------------- f32 -> bf16 convert / zero ----------------
__global__ void k_cvt(u16* __restrict__ dst, const float* __restrict__ src) {
  int i = blockIdx.x * 256 + threadIdx.x;
  dst[i] = f2bf(src[i]);
}
__global__ void k_zero(uint4* p) {
  p[(size_t)blockIdx.x * 256 + threadIdx.x] = uint4{0u, 0u, 0u, 0u};
}

// ======== Split-precision MFMA GEMM (gload_lds + XOR-swizzle staging) ========
template<int KD>
__global__ __launch_bounds__(256, 2) void gemm_s(
    const u16* __restrict__ Ahi, const u16* __restrict__ Alo,
    const u16* __restrict__ Whi, const u16* __restrict__ Wlo,
    const float* __restrict__ b1, const float* __restrict__ b2,
    float* __restrict__ outf)
{
  __shared__ __attribute__((aligned(16))) u16 Ah[128 * 64];
  __shared__ __attribute__((aligned(16))) u16 Al[128 * 64];
  __shared__ __attribute__((aligned(16))) u16 Wh[64 * 64];
  __shared__ __attribute__((aligned(16))) u16 Wl[64 * 64];
  const int tid = threadIdx.x;
  const int lane = tid & 63, wid = tid >> 6;
  const int wr = wid >> 1, wc = wid & 1;
  const int m0 = blockIdx.y * 128, n0 = blockIdx.x * 64;
  const int rsub = lane >> 3;
  const int swz = (((lane & 7) ^ rsub) << 3);   // source col offset (elements)

  f32x4 zero4 = {0.f, 0.f, 0.f, 0.f};
  f32x4 acc[4][2];
#pragma unroll
  for (int i = 0; i < 4; ++i)
#pragma unroll
    for (int j = 0; j < 2; ++j) acc[i][j] = zero4;

  for (int kt = 0; kt < KD / 64; ++kt) {
    __syncthreads();
#pragma unroll
    for (int cc = 0; cc < 4; ++cc) {
      int row = wid * 32 + cc * 8 + rsub;
      size_t g = (size_t)(m0 + row) * KD + kt * 64 + swz;
      gload16(Ahi + g, &Ah[(wid * 32 + cc * 8) * 64]);
      gload16(Alo + g, &Al[(wid * 32 + cc * 8) * 64]);
    }
#pragma unroll
    for (int cc = 0; cc < 2; ++cc) {
      int row = wid * 16 + cc * 8 + rsub;
      size_t g = (size_t)(n0 + row) * KD + kt * 64 + swz;
      gload16(Whi + g, &Wh[(wid * 16 + cc * 8) * 64]);
      gload16(Wlo + g, &Wl[(wid * 16 + cc * 8) * 64]);
    }
    __syncthreads();
#pragma unroll
    for (int ks = 0; ks < 2; ++ks) {
      short8 ah[4], al[4], wh[2], wl[2];
#pragma unroll
      for (int mm = 0; mm < 4; ++mm) {
        int row = wr * 64 + mm * 16 + (lane & 15);
        int kb = (ks * 64 + ((lane >> 4) << 4)) ^ ((row & 7) << 4);
        ah[mm] = *(const short8*)((const char*)Ah + row * 128 + kb);
        al[mm] = *(const short8*)((const char*)Al + row * 128 + kb);
      }
#pragma unroll
      for (int nn = 0; nn < 2; ++nn) {
        int row = wc * 32 + nn * 16 + (lane & 15);
        int kb = (ks * 64 + ((lane >> 4) << 4)) ^ ((row & 7) << 4);
        wh[nn] = *(const short8*)((const char*)Wh + row * 128 + kb);
        wl[nn] = *(const short8*)((const char*)Wl + row * 128 + kb);
      }
#pragma unroll
      for (int mm = 0; mm < 4; ++mm)
#pragma unroll
        for (int nn = 0; nn < 2; ++nn) {
          acc[mm][nn] = __builtin_amdgcn_mfma_f32_16x16x32_bf16(ah[mm], wh[nn], acc[mm][nn], 0, 0, 0);
          acc[mm][nn] = __builtin_amdgcn_mfma_f32_16x16x32_bf16(ah[mm], wl[nn], acc[mm][nn], 0, 0, 0);
          acc[mm][nn] = __builtin_amdgcn_mfma_f32_16x16x32_bf16(al[mm], wh[nn], acc[mm][nn], 0, 0, 0);
        }
    }
  }

  float bcol[2];
#pragma unroll
  for (int nn = 0; nn < 2; ++nn) {
    int col = n0 + wc * 32 + nn * 16 + (lane & 15);
    bcol[nn] = b1[col] + b2[col];
  }
#pragma unroll
  for (int mm = 0; mm < 4; ++mm)
#pragma unroll
    for (int r = 0; r < 4; ++r) {
      int grow = m0 + wr * 64 + mm * 16 + ((lane >> 4) << 2) + r;
#pragma unroll
      for (int nn = 0; nn < 2; ++nn) {
        int col = n0 + wc * 32 + nn * 16 + (lane & 15);
        outf[(size_t)grow * 512 + col] = acc[mm][nn][r] + bcol[nn];
      }
    }
}

// ======== bf16 MFMA GEMM modes 1/2/3 (gload_lds + XOR-swizzle staging) ========
template<int MODE, int KD>
__global__ __launch_bounds__(256, 2) void gemm_k(
    const u16* __restrict__ Ag, const u16* __restrict__ Ag2,
    const u16* __restrict__ Wg, const u16* __restrict__ W2g,
    const float* __restrict__ b1, const float* __restrict__ b2,
    u16* __restrict__ outb, float* __restrict__ outh, float* __restrict__ outd,
    float* __restrict__ abuf, const float* __restrict__ vecw, int estep)
{
  __shared__ __attribute__((aligned(16))) u16 As[128 * 64];
  __shared__ __attribute__((aligned(16))) u16 Ws[64 * 64];
  __shared__ float xes[128];
  const int tid = threadIdx.x;
  const int lane = tid & 63, wid = tid >> 6;
  const int wr = wid >> 1, wc = wid & 1;
  const int m0 = blockIdx.y * 128, n0 = blockIdx.x * 64;
  const int rsub = lane >> 3;
  const int swz = (((lane & 7) ^ rsub) << 3);

  if constexpr (MODE == 2) {
    if (tid < 128) xes[tid] = abuf[(size_t)(m0 + tid) * 26 + estep];
  }

  f32x4 zero4 = {0.f, 0.f, 0.f, 0.f};
  f32x4 acc[4][2];
#pragma unroll
  for (int i = 0; i < 4; ++i)
#pragma unroll
    for (int j = 0; j < 2; ++j) acc[i][j] = zero4;

  for (int kt = 0; kt < KD / 64; ++kt) {
    const u16* Asrc; int ka;
    if (kt < 8) { Asrc = Ag;  ka = kt; }
    else        { Asrc = Ag2; ka = kt - 8; }
    const u16* Wsrc; int kw, rowoff;
    if constexpr (MODE == 1) {
      if (n0 >= 256) { Wsrc = W2g; rowoff = n0 - 256; }
      else           { Wsrc = Wg;  rowoff = n0; }
      kw = kt;
    } else {
      if (kt < 8) { Wsrc = Wg;  kw = kt; }
      else        { Wsrc = W2g; kw = kt - 8; }
      rowoff = n0;
    }
    __syncthreads();
#pragma unroll
    for (int cc = 0; cc < 4; ++cc) {
      int row = wid * 32 + cc * 8 + rsub;
      gload16(Asrc + (size_t)(m0 + row) * 512 + ka * 64 + swz, &As[(wid * 32 + cc * 8) * 64]);
    }
#pragma unroll
    for (int cc = 0; cc < 2; ++cc) {
      int row = wid * 16 + cc * 8 + rsub;
      gload16(Wsrc + (size_t)(rowoff + row) * 512 + kw * 64 + swz, &Ws[(wid * 16 + cc * 8) * 64]);
    }
    __syncthreads();
#pragma unroll
    for (int ks = 0; ks < 2; ++ks) {
      short8 af[4], bfv[2];
#pragma unroll
      for (int mm = 0; mm < 4; ++mm) {
        int row = wr * 64 + mm * 16 + (lane & 15);
        int kb = (ks * 64 + ((lane >> 4) << 4)) ^ ((row & 7) << 4);
        af[mm] = *(const short8*)((const char*)As + row * 128 + kb);
      }
#pragma unroll
      for (int nn = 0; nn < 2; ++nn) {
        int row = wc * 32 + nn * 16 + (lane & 15);
        int kb = (ks * 64 + ((lane >> 4) << 4)) ^ ((row & 7) << 4);
        bfv[nn] = *(const short8*)((const char*)Ws + row * 128 + kb);
      }
#pragma unroll
      for (int mm = 0; mm < 4; ++mm)
#pragma unroll
        for (int nn = 0; nn < 2; ++nn)
          acc[mm][nn] = __builtin_amdgcn_mfma_f32_16x16x32_bf16(af[mm], bfv[nn], acc[mm][nn], 0, 0, 0);
    }
  }

  float bcol[2], vcol[2];
#pragma unroll
  for (int nn = 0; nn < 2; ++nn) {
    int col = n0 + wc * 32 + nn * 16 + (lane & 15);
    if constexpr (MODE == 1) bcol[nn] = (col < 256) ? b1[col] : b2[col - 256];
    else                     bcol[nn] = b1[col] + b2[col];
    vcol[nn] = 0.0f;
    if constexpr (MODE == 2 || MODE == 3) vcol[nn] = vecw[col];
  }
  float pp[4][4];
#pragma unroll
  for (int i = 0; i < 4; ++i)
#pragma unroll
    for (int j = 0; j < 4; ++j) pp[i][j] = 0.0f;

#pragma unroll
  for (int mm = 0; mm < 4; ++mm) {
#pragma unroll
    for (int r = 0; r < 4; ++r) {
      int lrow = wr * 64 + mm * 16 + ((lane >> 4) << 2) + r;
      int grow = m0 + lrow;
#pragma unroll
      for (int nn = 0; nn < 2; ++nn) {
        int col = n0 + wc * 32 + nn * 16 + (lane & 15);
        float v = acc[mm][nn][r] + bcol[nn];
        if constexpr (MODE == 1) {
          float e = v > 0.f ? v : (expf(v) - 1.f);
          if (col < 256) outh[(size_t)grow * 256 + col] = e;
          else           outd[(size_t)grow * 256 + (col - 256)] = e;
        } else if constexpr (MODE == 2) {
          v += xes[lrow] * vcol[nn];
          outb[(size_t)grow * 512 + col] = f2bf(fast_tanh(v));
        } else {
          float h = fast_tanh(v);
          outb[(size_t)grow * 512 + col] = f2bf(h);
          pp[mm][r] += h * vcol[nn];
        }
      }
    }
  }
  if constexpr (MODE == 3) {
#pragma unroll
    for (int mm = 0; mm < 4; ++mm)
#pragma unroll
      for (int r = 0; r < 4; ++r) {
        float p = pp[mm][r];
        p += __shfl_xor(p, 1); p += __shfl_xor(p, 2);
        p += __shfl_xor(p, 4); p += __shfl_xor(p, 8);
        if ((lane & 15) == 0) {
          int grow = m0 + wr * 64 + mm * 16 + ((lane >> 4) << 2) + r;
          atomicAdd(&abuf[(size_t)grow * 26 + estep + 1], p);
        }
      }
  }
}

// ---------------- small helpers ----------------
__global__ void k_ainit(float* abuf, const float* clsb) {
  int idx = blockIdx.x * 256 + threadIdx.x;     // 212992
  if (idx >= 212992) return;
  abuf[idx] = ((idx % 26) == 0) ? 1.0f : clsb[0];
}
__global__ void k_arc(float* __restrict__ outp, const float* __restrict__ abuf) {
  int idx = blockIdx.x * 256 + threadIdx.x;     // 2097152
  int j = idx & 255, i = (idx >> 8) & 255, b = idx >> 16;
  int k = i - j;
  outp[idx] = (k >= 0 && k <= 25) ? abuf[(size_t)(b * 256 + i) * 26 + k] : 0.0f;
}
__global__ void k_diag(float* __restrict__ outp, float code, int n) {
  int idx = blockIdx.x * 256 + threadIdx.x;
  if (idx < n) outp[idx] = (idx == 0) ? code : 0.0f;
}

extern "C" void kernel_launch(void* const* d_in, const int* in_sizes, int n_in,
                              void* d_out, int out_size, void* d_ws, size_t ws_size,
                              hipStream_t stream) {
  static const int SZ[26] = {6266880, 2088960, 8160, 1024, 524288, 262144, 512, 512,
                             262144, 262144, 512, 512, 512, 262144, 512, 512,
                             262144, 262144, 512, 512, 512, 1, 131072, 256, 131072, 256};
  float diag_code = 0.0f;
  if (n_in != 26) diag_code = 4096.0f + (float)n_in;
  else {
    for (int j = 0; j < 26; ++j)
      if (in_sizes[j] != SZ[j]) { diag_code = 2048.0f + (float)j; break; }
  }
  const size_t NEED = (size_t)(32u << 20);   // round 8 proved ws >= 34.4 MB
  if (ws_size < NEED && diag_code == 0.0f) diag_code = 8192.0f;
  if (diag_code != 0.0f) {
    k_diag<<<(out_size + 255) / 256, 256, 0, stream>>>((float*)d_out, diag_code, out_size);
    return;
  }

  const float* inp  = (const float*)d_in[0];
  const float* tag  = (const float*)d_in[1];
  const int*   mask = (const int*)d_in[2];
  const float* sent = (const float*)d_in[3];
  const float* g0_Wih = (const float*)d_in[4];
  const float* g0_Whh = (const float*)d_in[5];
  const float* g0_bih = (const float*)d_in[6];
  const float* g0_bhh = (const float*)d_in[7];
  const float* g1_Wih = (const float*)d_in[8];
  const float* g1_Whh = (const float*)d_in[9];
  const float* g1_bih = (const float*)d_in[10];
  const float* g1_bhh = (const float*)d_in[11];
  const float* e0_Wih = (const float*)d_in[12];
  const float* e0_Whh = (const float*)d_in[13];
  const float* e0_bih = (const float*)d_in[14];
  const float* e0_bhh = (const float*)d_in[15];
  const float* e1_Wih = (const float*)d_in[16];
  const float* e1_Whh = (const float*)d_in[17];
  const float* e1_bih = (const float*)d_in[18];
  const float* e1_bhh = (const float*)d_in[19];
  const float* cls_W  = (const float*)d_in[20];
  const float* cls_b  = (const float*)d_in[21];
  const float* ht_W   = (const float*)d_in[22];
  const float* ht_b   = (const float*)d_in[23];
  const float* dt_W   = (const float*)d_in[24];
  const float* dt_b   = (const float*)d_in[25];

  float* out = (float*)d_out;               // 24 MB: [arc | head | dep] f32
  char*  ob  = (char*)d_out;
  char*  ws  = (char*)d_ws;

  // ---- d_out overlays (pre-output lifetimes) ----
  u16*  W0hi = (u16*)(ob);                  // [0,1M) g0_Wih hi
  u16*  W0lo = (u16*)(ob + (1u << 20));     // [1,2M)
  float* XW0 = (float*)(ob + (2u << 20));   // [2,18M) xW0 -> Y0 -> GS
  float* WT0 = (float*)(ob + (18u << 20));  // [18,19M)
  float* WT1 = (float*)(ob + (19u << 20));  // [19,20M)
  u16*  G1hi = (u16*)(ob + (20u << 20));    // [20,20.5M)
  u16*  G1lo = (u16*)(ob + (20u << 20) + (512u << 10));
  // ---- ws overlays ----
  u16*  Xhi  = (u16*)(ws);                  // [0,16M)
  u16*  Xlo  = (u16*)(ws + (16u << 20));    // [16,32M)
  u16*  Y0hi = (u16*)(ws);                  // [0,8M)   after X dead; later S0
  u16*  Y0lo = (u16*)(ws + (8u << 20));     // [8,16M)  later S1
  u16*  S0   = Y0hi;
  u16*  S1   = Y0lo;
  u16*  S2   = (u16*)(ws + (16u << 20));    // [16,24M)
  float* ABUF = (float*)(ws + (24u << 20)); // 852 KB
  u16*  W0b  = (u16*)(ws + (25u << 20));                      // e0_Whh bf16
  u16*  W1b  = (u16*)(ws + (25u << 20) + (512u << 10));       // e1_Wih
  u16*  W2b  = (u16*)(ws + (26u << 20));                      // e1_Whh
  u16*  W3b  = (u16*)(ws + (26u << 20) + (512u << 10));       // ht_W
  u16*  W4b  = (u16*)(ws + (26u << 20) + (768u << 10));       // dt_W
  u64*  HBUF = (u64*)(ws + (28u << 20));                      // [32][2][512] u64

  dim3 grid(8, 64);

  // 1) splits + transposes
  k_concat_split<<<32768, 256, 0, stream>>>(Xhi, Xlo, inp, tag, sent);
  k_split<<<2048, 256, 0, stream>>>(W0hi, W0lo, g0_Wih, 524288);
  k_transw<<<1024, 256, 0, stream>>>(WT0, g0_Whh);
  k_transw<<<1024, 256, 0, stream>>>(WT1, g1_Whh);
  k_split<<<1024, 256, 0, stream>>>(G1hi, G1lo, g1_Wih, 262144);

  // 2) xW0 (split-precision MFMA) -> XW0 ; multi-block scan0 in place -> Y0
  gemm_s<1024><<<grid, 256, 0, stream>>>(Xhi, Xlo, W0hi, W0lo, g0_bih, g0_bhh, XW0);
  k_syncinit<<<128, 256, 0, stream>>>(HBUF);
  k_gscan_mb<<<128, 512, 0, stream>>>(XW0, WT0, mask, 0, HBUF);

  // 3) split Y0 (X dead); xW1 -> XW0; multi-block scan1 in place -> GS (masked)
  k_split<<<16384, 256, 0, stream>>>(Y0hi, Y0lo, XW0, 4194304);
  gemm_s<512><<<grid, 256, 0, stream>>>(Y0hi, Y0lo, G1hi, G1lo, g1_bih, g1_bhh, XW0);
  k_syncinit<<<128, 256, 0, stream>>>(HBUF);
  k_gscan_mb<<<128, 512, 0, stream>>>(XW0, WT1, mask, 1, HBUF);

  // 4) GS -> bf16 S0; S1 = 0; edge/head weights -> bf16
  k_cvt<<<16384, 256, 0, stream>>>(S0, XW0);
  k_zero<<<2048, 256, 0, stream>>>((uint4*)S1);
  k_cvt<<<1024, 256, 0, stream>>>(W0b, e0_Whh);
  k_cvt<<<1024, 256, 0, stream>>>(W1b, e1_Wih);
  k_cvt<<<1024, 256, 0, stream>>>(W2b, e1_Whh);
  k_cvt<<<512, 256, 0, stream>>>(W3b, ht_W);
  k_cvt<<<512, 256, 0, stream>>>(W4b, dt_W);

  // 5) tag heads -> f32 head/dep in d_out (GS f32 dead)
  gemm_k<1, 512><<<grid, 256, 0, stream>>>(S0, nullptr, W3b, W4b, ht_b, dt_b,
                                           nullptr, out + 2097152, out + 4194304,
                                           nullptr, nullptr, 0);

  // 6) edge scan: 25 x (E0, E1), triple-buffer rotation
  k_ainit<<<832, 256, 0, stream>>>(ABUF, cls_b);
  u16* r0 = S0; u16* r1 = S1; u16* r2 = S2;
  for (int st = 0; st < 25; ++st) {
    gemm_k<2, 512><<<grid, 256, 0, stream>>>(r0, nullptr, W0b, nullptr, e0_bih, e0_bhh,
                                             r2, nullptr, nullptr, ABUF, e0_Wih, st);
    gemm_k<3, 1024><<<grid, 256, 0, stream>>>(r2, r1, W1b, W2b, e1_bih, e1_bhh,
                                              r0, nullptr, nullptr, ABUF, cls_W, st);
    u16* t0 = r2; u16* t1 = r0; u16* t2 = r1;
    r0 = t0; r1 = t1; r2 = t2;
  }
  // 7) arc gather
  k_arc<<<8192, 256, 0, stream>>>(out, ABUF);
}

// Round 18
// 1797.761 us; speedup vs baseline: 17.5175x; 1.2250x over previous
//
#include <hip/hip_runtime.h>
#include <math.h>

typedef unsigned int u32;
typedef unsigned short u16;
typedef unsigned long long u64;
typedef __attribute__((ext_vector_type(8))) short short8;
typedef __attribute__((ext_vector_type(4))) float f32x4;

__device__ inline float bf2f(u16 v) { return __uint_as_float(((u32)v) << 16); }
__device__ inline u16 f2bf(float f) {
  u32 u = __float_as_uint(f);
  return (u16)((u + 0x7fffu + ((u >> 16) & 1u)) >> 16);
}
__device__ inline float fast_tanh(float x) {
  x = fminf(9.0f, fmaxf(-9.0f, x));
  float e = __builtin_amdgcn_exp2f(x * 2.8853900817779268f);
  return (e - 1.0f) * __builtin_amdgcn_rcpf(e + 1.0f);
}
__device__ inline void gload16(const void* g, void* l) {
  __builtin_amdgcn_global_load_lds((const __attribute__((address_space(1))) u32*)g,
                                   (__attribute__((address_space(3))) u32*)l, 16, 0, 0);
}

// ---- transpose Whh (f32 [512][512]) -> WT[k][t] ----
__global__ void k_transw(float* __restrict__ outp, const float* __restrict__ src) {
  int idx = blockIdx.x * 256 + threadIdx.x;     // 262144
  int k = idx & 511, t = idx >> 9;
  outp[(size_t)k * 512 + t] = src[(size_t)t * 512 + k];
}

// ---- hi/lo bf16 split of an f32 array ----
__global__ void k_split(u16* __restrict__ hi, u16* __restrict__ lo,
                        const float* __restrict__ src, int n) {
  int i = blockIdx.x * 256 + threadIdx.x;
  if (i >= n) return;
  float v = src[i];
  u16 h = f2bf(v);
  hi[i] = h;
  lo[i] = f2bf(v - bf2f(h));
}

// ---- concat + split: X[8192][1024] = [sent | inp|tag] -> Xhi/Xlo bf16 ----
__global__ void k_concat_split(u16* __restrict__ xhi, u16* __restrict__ xlo,
                               const float* __restrict__ inp, const float* __restrict__ tag,
                               const float* __restrict__ sent) {
  int gid = blockIdx.x * 256 + threadIdx.x;     // 8388608
  int row = gid >> 10, c = gid & 1023;
  int b = row >> 8, s = row & 255;
  float v;
  if (s == 0) v = sent[c];
  else if (c < 768) v = inp[(size_t)(b * 255 + s - 1) * 768 + c];
  else v = tag[(size_t)(b * 255 + s - 1) * 256 + (c - 768)];
  u16 h = f2bf(v);
  xhi[gid] = h;
  xlo[gid] = f2bf(v - bf2f(h));
}

// ---- init tagged h double-buffer: slot0 = (tag1, h=0), slot1 = tag0 ----
__global__ void k_syncinit(u64* hbuf) {
  int i = blockIdx.x * 256 + threadIdx.x;       // 32768 = 32*2*512
  if (i < 32768) {
    int pos = i & 1023;
    hbuf[i] = (pos < 512) ? (1ull << 32) : 0ull;
  }
}

// ======== multi-block g-RNN scan, tagged sync + wave-internal k-slices ========
// Block (b,q) owns cols [q*128,q*128+128). Wave wv: cols wv*16+(lane&15); p=(lane>>4)&3
// is the k-slice (128 k each, all in VGPR). Reduce across p via shfl_xor(16/32).
// hls padded [4][132] so the 4 k-slice groups read disjoint bank quads.
__global__ __launch_bounds__(512, 1) void k_gscan_mb(
    float* __restrict__ XW, const float* __restrict__ WT,
    const int* __restrict__ mask, int layer, u64* hbuf)
{
  __shared__ float hls[528];
  const int blk = blockIdx.x;
  const int b = blk >> 2, q = blk & 3;
  const int tid = threadIdx.x;
  const int lane = tid & 63;
  const int wv = tid >> 6;
  const int colL = wv * 16 + (lane & 15);       // 0..127
  const int p = (lane >> 4) & 3;                // k-slice
  const int c = (q << 7) + colL;                // global col
  const bool fin = (p == 0);
  float wreg[128];
#pragma unroll
  for (int i = 0; i < 128; ++i)
    wreg[i] = WT[(size_t)(p * 128 + i) * 512 + c];
  u64* hb = hbuf + b * 1024;
  __syncthreads();

  for (int s = 0; s < 256; ++s) {
    // prefetch XW element (finishing lanes only), independent of the poll
    float xwv = 0.f;
    size_t xwoff = 0;
    if (fin) {
      xwoff = (size_t)(b * 256 + s) * 512 + c;
      xwv = XW[xwoff];
    }
    // poll own h element: tag travels with data (single round trip)
    const u32 want = (u32)(s + 1);
    u64 v;
    do {
      v = __hip_atomic_load(&hb[(s & 1) * 512 + tid], __ATOMIC_RELAXED,
                            __HIP_MEMORY_SCOPE_AGENT);
    } while ((u32)(v >> 32) < want);
    hls[(tid >> 7) * 132 + (tid & 127)] = __uint_as_float((u32)v);
    __syncthreads();
    const float* hk = &hls[p * 132];
    float a0 = 0.f, a1 = 0.f, a2 = 0.f, a3 = 0.f;
#pragma unroll
    for (int i = 0; i < 128; i += 4) {
      a0 = fmaf(wreg[i],     hk[i],     a0);
      a1 = fmaf(wreg[i + 1], hk[i + 1], a1);
      a2 = fmaf(wreg[i + 2], hk[i + 2], a2);
      a3 = fmaf(wreg[i + 3], hk[i + 3], a3);
    }
    float r = (a0 + a1) + (a2 + a3);
    r += __shfl_xor(r, 16);
    r += __shfl_xor(r, 32);
    if (fin) {
      float h = tanhf(r + xwv);
      u64 pk = ((u64)(u32)(s + 2) << 32) | (u64)__float_as_uint(h);
      __hip_atomic_store(&hb[((s + 1) & 1) * 512 + c], pk,
                         __ATOMIC_RELAXED, __HIP_MEMORY_SCOPE_AGENT);
      float ov = h;
      if (layer) ov *= (s == 0) ? 1.f : (float)mask[b * 255 + s - 1];
      XW[xwoff] = ov;
    }
    __syncthreads();   // hls stable until all lanes finished reading
  }
}

// ---------------- f32 -> bf16 convert / zero ----------------
__global__ void k_cvt(u16* __restrict__ dst, const float* __restrict__ src) {
  int i = blockIdx.x * 256 + threadIdx.x;
  dst[i] = f2bf(src[i]);
}
__global__ void k_zero(uint4* p) {
  p[(size_t)blockIdx.x * 256 + threadIdx.x] = uint4{0u, 0u, 0u, 0u};
}

// XCD-local tile mapping: all 8 col-tiles of a row-panel land on the same XCD
// (blk%64 = row-panel -> XCD (blk%64)%8; per-XCD A working set fits 4MB L2).
__device__ inline void tile_map(int blk, int& m0, int& n0) {
  n0 = (blk >> 6) << 6;     // 8 col-tiles
  m0 = (blk & 63) << 7;     // 64 row-panels
}

// ======== Split-precision MFMA GEMM (gload_lds + XOR-swizzle staging) ========
template<int KD>
__global__ __launch_bounds__(256, 2) void gemm_s(
    const u16* __restrict__ Ahi, const u16* __restrict__ Alo,
    const u16* __restrict__ Whi, const u16* __restrict__ Wlo,
    const float* __restrict__ b1, const float* __restrict__ b2,
    float* __restrict__ outf)
{
  __shared__ __attribute__((aligned(16))) u16 Ah[128 * 64];
  __shared__ __attribute__((aligned(16))) u16 Al[128 * 64];
  __shared__ __attribute__((aligned(16))) u16 Wh[64 * 64];
  __shared__ __attribute__((aligned(16))) u16 Wl[64 * 64];
  const int tid = threadIdx.x;
  const int lane = tid & 63, wid = tid >> 6;
  const int wr = wid >> 1, wc = wid & 1;
  int m0, n0;
  tile_map(blockIdx.x, m0, n0);
  const int rsub = lane >> 3;
  const int swz = (((lane & 7) ^ rsub) << 3);   // source col offset (elements)

  f32x4 zero4 = {0.f, 0.f, 0.f, 0.f};
  f32x4 acc[4][2];
#pragma unroll
  for (int i = 0; i < 4; ++i)
#pragma unroll
    for (int j = 0; j < 2; ++j) acc[i][j] = zero4;

  for (int kt = 0; kt < KD / 64; ++kt) {
    __syncthreads();
#pragma unroll
    for (int cc = 0; cc < 4; ++cc) {
      int row = wid * 32 + cc * 8 + rsub;
      size_t g = (size_t)(m0 + row) * KD + kt * 64 + swz;
      gload16(Ahi + g, &Ah[(wid * 32 + cc * 8) * 64]);
      gload16(Alo + g, &Al[(wid * 32 + cc * 8) * 64]);
    }
#pragma unroll
    for (int cc = 0; cc < 2; ++cc) {
      int row = wid * 16 + cc * 8 + rsub;
      size_t g = (size_t)(n0 + row) * KD + kt * 64 + swz;
      gload16(Whi + g, &Wh[(wid * 16 + cc * 8) * 64]);
      gload16(Wlo + g, &Wl[(wid * 16 + cc * 8) * 64]);
    }
    __syncthreads();
#pragma unroll
    for (int ks = 0; ks < 2; ++ks) {
      short8 ah[4], al[4], wh[2], wl[2];
#pragma unroll
      for (int mm = 0; mm < 4; ++mm) {
        int row = wr * 64 + mm * 16 + (lane & 15);
        int kb = (ks * 64 + ((lane >> 4) << 4)) ^ ((row & 7) << 4);
        ah[mm] = *(const short8*)((const char*)Ah + row * 128 + kb);
        al[mm] = *(const short8*)((const char*)Al + row * 128 + kb);
      }
#pragma unroll
      for (int nn = 0; nn < 2; ++nn) {
        int row = wc * 32 + nn * 16 + (lane & 15);
        int kb = (ks * 64 + ((lane >> 4) << 4)) ^ ((row & 7) << 4);
        wh[nn] = *(const short8*)((const char*)Wh + row * 128 + kb);
        wl[nn] = *(const short8*)((const char*)Wl + row * 128 + kb);
      }
#pragma unroll
      for (int mm = 0; mm < 4; ++mm)
#pragma unroll
        for (int nn = 0; nn < 2; ++nn) {
          acc[mm][nn] = __builtin_amdgcn_mfma_f32_16x16x32_bf16(ah[mm], wh[nn], acc[mm][nn], 0, 0, 0);
          acc[mm][nn] = __builtin_amdgcn_mfma_f32_16x16x32_bf16(ah[mm], wl[nn], acc[mm][nn], 0, 0, 0);
          acc[mm][nn] = __builtin_amdgcn_mfma_f32_16x16x32_bf16(al[mm], wh[nn], acc[mm][nn], 0, 0, 0);
        }
    }
  }

  float bcol[2];
#pragma unroll
  for (int nn = 0; nn < 2; ++nn) {
    int col = n0 + wc * 32 + nn * 16 + (lane & 15);
    bcol[nn] = b1[col] + b2[col];
  }
#pragma unroll
  for (int mm = 0; mm < 4; ++mm)
#pragma unroll
    for (int r = 0; r < 4; ++r) {
      int grow = m0 + wr * 64 + mm * 16 + ((lane >> 4) << 2) + r;
#pragma unroll
      for (int nn = 0; nn < 2; ++nn) {
        int col = n0 + wc * 32 + nn * 16 + (lane & 15);
        outf[(size_t)grow * 512 + col] = acc[mm][nn][r] + bcol[nn];
      }
    }
}

// ======== bf16 MFMA GEMM modes 1/2/3 (gload_lds + XOR-swizzle staging) ========
template<int MODE, int KD>
__global__ __launch_bounds__(256, 2) void gemm_k(
    const u16* __restrict__ Ag, const u16* __restrict__ Ag2,
    const u16* __restrict__ Wg, const u16* __restrict__ W2g,
    const float* __restrict__ b1, const float* __restrict__ b2,
    u16* __restrict__ outb, float* __restrict__ outh, float* __restrict__ outd,
    float* __restrict__ abuf, const float* __restrict__ vecw, int estep)
{
  __shared__ __attribute__((aligned(16))) u16 As[128 * 64];
  __shared__ __attribute__((aligned(16))) u16 Ws[64 * 64];
  __shared__ float xes[128];
  const int tid = threadIdx.x;
  const int lane = tid & 63, wid = tid >> 6;
  const int wr = wid >> 1, wc = wid & 1;
  int m0, n0;
  tile_map(blockIdx.x, m0, n0);
  const int rsub = lane >> 3;
  const int swz = (((lane & 7) ^ rsub) << 3);

  if constexpr (MODE == 2) {
    if (tid < 128) xes[tid] = abuf[(size_t)(m0 + tid) * 26 + estep];
  }

  f32x4 zero4 = {0.f, 0.f, 0.f, 0.f};
  f32x4 acc[4][2];
#pragma unroll
  for (int i = 0; i < 4; ++i)
#pragma unroll
    for (int j = 0; j < 2; ++j) acc[i][j] = zero4;

  for (int kt = 0; kt < KD / 64; ++kt) {
    const u16* Asrc; int ka;
    if (kt < 8) { Asrc = Ag;  ka = kt; }
    else        { Asrc = Ag2; ka = kt - 8; }
    const u16* Wsrc; int kw, rowoff;
    if constexpr (MODE == 1) {
      if (n0 >= 256) { Wsrc = W2g; rowoff = n0 - 256; }
      else           { Wsrc = Wg;  rowoff = n0; }
      kw = kt;
    } else {
      if (kt < 8) { Wsrc = Wg;  kw = kt; }
      else        { Wsrc = W2g; kw = kt - 8; }
      rowoff = n0;
    }
    __syncthreads();
#pragma unroll
    for (int cc = 0; cc < 4; ++cc) {
      int row = wid * 32 + cc * 8 + rsub;
      gload16(Asrc + (size_t)(m0 + row) * 512 + ka * 64 + swz, &As[(wid * 32 + cc * 8) * 64]);
    }
#pragma unroll
    for (int cc = 0; cc < 2; ++cc) {
      int row = wid * 16 + cc * 8 + rsub;
      gload16(Wsrc + (size_t)(rowoff + row) * 512 + kw * 64 + swz, &Ws[(wid * 16 + cc * 8) * 64]);
    }
    __syncthreads();
#pragma unroll
    for (int ks = 0; ks < 2; ++ks) {
      short8 af[4], bfv[2];
#pragma unroll
      for (int mm = 0; mm < 4; ++mm) {
        int row = wr * 64 + mm * 16 + (lane & 15);
        int kb = (ks * 64 + ((lane >> 4) << 4)) ^ ((row & 7) << 4);
        af[mm] = *(const short8*)((const char*)As + row * 128 + kb);
      }
#pragma unroll
      for (int nn = 0; nn < 2; ++nn) {
        int row = wc * 32 + nn * 16 + (lane & 15);
        int kb = (ks * 64 + ((lane >> 4) << 4)) ^ ((row & 7) << 4);
        bfv[nn] = *(const short8*)((const char*)Ws + row * 128 + kb);
      }
#pragma unroll
      for (int mm = 0; mm < 4; ++mm)
#pragma unroll
        for (int nn = 0; nn < 2; ++nn)
          acc[mm][nn] = __builtin_amdgcn_mfma_f32_16x16x32_bf16(af[mm], bfv[nn], acc[mm][nn], 0, 0, 0);
    }
  }

  float bcol[2], vcol[2];
#pragma unroll
  for (int nn = 0; nn < 2; ++nn) {
    int col = n0 + wc * 32 + nn * 16 + (lane & 15);
    if constexpr (MODE == 1) bcol[nn] = (col < 256) ? b1[col] : b2[col - 256];
    else                     bcol[nn] = b1[col] + b2[col];
    vcol[nn] = 0.0f;
    if constexpr (MODE == 2 || MODE == 3) vcol[nn] = vecw[col];
  }
  float pp[4][4];
#pragma unroll
  for (int i = 0; i < 4; ++i)
#pragma unroll
    for (int j = 0; j < 4; ++j) pp[i][j] = 0.0f;

#pragma unroll
  for (int mm = 0; mm < 4; ++mm) {
#pragma unroll
    for (int r = 0; r < 4; ++r) {
      int lrow = wr * 64 + mm * 16 + ((lane >> 4) << 2) + r;
      int grow = m0 + lrow;
#pragma unroll
      for (int nn = 0; nn < 2; ++nn) {
        int col = n0 + wc * 32 + nn * 16 + (lane & 15);
        float v = acc[mm][nn][r] + bcol[nn];
        if constexpr (MODE == 1) {
          float e = v > 0.f ? v : (expf(v) - 1.f);
          if (col < 256) outh[(size_t)grow * 256 + col] = e;
          else           outd[(size_t)grow * 256 + (col - 256)] = e;
        } else if constexpr (MODE == 2) {
          v += xes[lrow] * vcol[nn];
          outb[(size_t)grow * 512 + col] = f2bf(fast_tanh(v));
        } else {
          float h = fast_tanh(v);
          outb[(size_t)grow * 512 + col] = f2bf(h);
          pp[mm][r] += h * vcol[nn];
        }
      }
    }
  }
  if constexpr (MODE == 3) {
#pragma unroll
    for (int mm = 0; mm < 4; ++mm)
#pragma unroll
      for (int r = 0; r < 4; ++r) {
        float p = pp[mm][r];
        p += __shfl_xor(p, 1); p += __shfl_xor(p, 2);
        p += __shfl_xor(p, 4); p += __shfl_xor(p, 8);
        if ((lane & 15) == 0) {
          int grow = m0 + wr * 64 + mm * 16 + ((lane >> 4) << 2) + r;
          atomicAdd(&abuf[(size_t)grow * 26 + estep + 1], p);
        }
      }
  }
}

// ---------------- small helpers ----------------
__global__ void k_ainit(float* abuf, const float* clsb) {
  int idx = blockIdx.x * 256 + threadIdx.x;     // 212992
  if (idx >= 212992) return;
  abuf[idx] = ((idx % 26) == 0) ? 1.0f : clsb[0];
}
__global__ void k_arc(float* __restrict__ outp, const float* __restrict__ abuf) {
  int idx = blockIdx.x * 256 + threadIdx.x;     // 2097152
  int j = idx & 255, i = (idx >> 8) & 255, b = idx >> 16;
  int k = i - j;
  outp[idx] = (k >= 0 && k <= 25) ? abuf[(size_t)(b * 256 + i) * 26 + k] : 0.0f;
}
__global__ void k_diag(float* __restrict__ outp, float code, int n) {
  int idx = blockIdx.x * 256 + threadIdx.x;
  if (idx < n) outp[idx] = (idx == 0) ? code : 0.0f;
}

extern "C" void kernel_launch(void* const* d_in, const int* in_sizes, int n_in,
                              void* d_out, int out_size, void* d_ws, size_t ws_size,
                              hipStream_t stream) {
  static const int SZ[26] = {6266880, 2088960, 8160, 1024, 524288, 262144, 512, 512,
                             262144, 262144, 512, 512, 512, 262144, 512, 512,
                             262144, 262144, 512, 512, 512, 1, 131072, 256, 131072, 256};
  float diag_code = 0.0f;
  if (n_in != 26) diag_code = 4096.0f + (float)n_in;
  else {
    for (int j = 0; j < 26; ++j)
      if (in_sizes[j] != SZ[j]) { diag_code = 2048.0f + (float)j; break; }
  }
  const size_t NEED = (size_t)(32u << 20);   // round 8 proved ws >= 34.4 MB
  if (ws_size < NEED && diag_code == 0.0f) diag_code = 8192.0f;
  if (diag_code != 0.0f) {
    k_diag<<<(out_size + 255) / 256, 256, 0, stream>>>((float*)d_out, diag_code, out_size);
    return;
  }

  const float* inp  = (const float*)d_in[0];
  const float* tag  = (const float*)d_in[1];
  const int*   mask = (const int*)d_in[2];
  const float* sent = (const float*)d_in[3];
  const float* g0_Wih = (const float*)d_in[4];
  const float* g0_Whh = (const float*)d_in[5];
  const float* g0_bih = (const float*)d_in[6];
  const float* g0_bhh = (const float*)d_in[7];
  const float* g1_Wih = (const float*)d_in[8];
  const float* g1_Whh = (const float*)d_in[9];
  const float* g1_bih = (const float*)d_in[10];
  const float* g1_bhh = (const float*)d_in[11];
  const float* e0_Wih = (const float*)d_in[12];
  const float* e0_Whh = (const float*)d_in[13];
  const float* e0_bih = (const float*)d_in[14];
  const float* e0_bhh = (const float*)d_in[15];
  const float* e1_Wih = (const float*)d_in[16];
  const float* e1_Whh = (const float*)d_in[17];
  const float* e1_bih = (const float*)d_in[18];
  const float* e1_bhh = (const float*)d_in[19];
  const float* cls_W  = (const float*)d_in[20];
  const float* cls_b  = (const float*)d_in[21];
  const float* ht_W   = (const float*)d_in[22];
  const float* ht_b   = (const float*)d_in[23];
  const float* dt_W   = (const float*)d_in[24];
  const float* dt_b   = (const float*)d_in[25];

  float* out = (float*)d_out;               // 24 MB: [arc | head | dep] f32
  char*  ob  = (char*)d_out;
  char*  ws  = (char*)d_ws;

  // ---- d_out overlays (pre-output lifetimes) ----
  u16*  W0hi = (u16*)(ob);                  // [0,1M) g0_Wih hi
  u16*  W0lo = (u16*)(ob + (1u << 20));     // [1,2M)
  float* XW0 = (float*)(ob + (2u << 20));   // [2,18M) xW0 -> Y0 -> GS
  float* WT0 = (float*)(ob + (18u << 20));  // [18,19M)
  float* WT1 = (float*)(ob + (19u << 20));  // [19,20M)
  u16*  G1hi = (u16*)(ob + (20u << 20));    // [20,20.5M)
  u16*  G1lo = (u16*)(ob + (20u << 20) + (512u << 10));
  // ---- ws overlays ----
  u16*  Xhi  = (u16*)(ws);                  // [0,16M)
  u16*  Xlo  = (u16*)(ws + (16u << 20));    // [16,32M)
  u16*  Y0hi = (u16*)(ws);                  // [0,8M)   after X dead; later S0
  u16*  Y0lo = (u16*)(ws + (8u << 20));     // [8,16M)  later S1
  u16*  S0   = Y0hi;
  u16*  S1   = Y0lo;
  u16*  S2   = (u16*)(ws + (16u << 20));    // [16,24M)
  float* ABUF = (float*)(ws + (24u << 20)); // 852 KB
  u16*  W0b  = (u16*)(ws + (25u << 20));                      // e0_Whh bf16
  u16*  W1b  = (u16*)(ws + (25u << 20) + (512u << 10));       // e1_Wih
  u16*  W2b  = (u16*)(ws + (26u << 20));                      // e1_Whh
  u16*  W3b  = (u16*)(ws + (26u << 20) + (512u << 10));       // ht_W
  u16*  W4b  = (u16*)(ws + (26u << 20) + (768u << 10));       // dt_W
  u64*  HBUF = (u64*)(ws + (28u << 20));                      // [32][2][512] u64

  // 1) splits + transposes
  k_concat_split<<<32768, 256, 0, stream>>>(Xhi, Xlo, inp, tag, sent);
  k_split<<<2048, 256, 0, stream>>>(W0hi, W0lo, g0_Wih, 524288);
  k_transw<<<1024, 256, 0, stream>>>(WT0, g0_Whh);
  k_transw<<<1024, 256, 0, stream>>>(WT1, g1_Whh);
  k_split<<<1024, 256, 0, stream>>>(G1hi, G1lo, g1_Wih, 262144);

  // 2) xW0 (split-precision MFMA) -> XW0 ; multi-block scan0 in place -> Y0
  gemm_s<1024><<<512, 256, 0, stream>>>(Xhi, Xlo, W0hi, W0lo, g0_bih, g0_bhh, XW0);
  k_syncinit<<<128, 256, 0, stream>>>(HBUF);
  k_gscan_mb<<<128, 512, 0, stream>>>(XW0, WT0, mask, 0, HBUF);

  // 3) split Y0 (X dead); xW1 -> XW0; multi-block scan1 in place -> GS (masked)
  k_split<<<16384, 256, 0, stream>>>(Y0hi, Y0lo, XW0, 4194304);
  gemm_s<512><<<512, 256, 0, stream>>>(Y0hi, Y0lo, G1hi, G1lo, g1_bih, g1_bhh, XW0);
  k_syncinit<<<128, 256, 0, stream>>>(HBUF);
  k_gscan_mb<<<128, 512, 0, stream>>>(XW0, WT1, mask, 1, HBUF);

  // 4) GS -> bf16 S0; S1 = 0; edge/head weights -> bf16
  k_cvt<<<16384, 256, 0, stream>>>(S0, XW0);
  k_zero<<<2048, 256, 0, stream>>>((uint4*)S1);
  k_cvt<<<1024, 256, 0, stream>>>(W0b, e0_Whh);
  k_cvt<<<1024, 256, 0, stream>>>(W1b, e1_Wih);
  k_cvt<<<1024, 256, 0, stream>>>(W2b, e1_Whh);
  k_cvt<<<512, 256, 0, stream>>>(W3b, ht_W);
  k_cvt<<<512, 256, 0, stream>>>(W4b, dt_W);

  // 5) tag heads -> f32 head/dep in d_out (GS f32 dead)
  gemm_k<1, 512><<<512, 256, 0, stream>>>(S0, nullptr, W3b, W4b, ht_b, dt_b,
                                          nullptr, out + 2097152, out + 4194304,
                                          nullptr, nullptr, 0);

  // 6) edge scan: 25 x (E0, E1), triple-buffer rotation
  k_ainit<<<832, 256, 0, stream>>>(ABUF, cls_b);
  u16* r0 = S0; u16* r1 = S1; u16* r2 = S2;
  for (int st = 0; st < 25; ++st) {
    gemm_k<2, 512><<<512, 256, 0, stream>>>(r0, nullptr, W0b, nullptr, e0_bih, e0_bhh,
                                            r2, nullptr, nullptr, ABUF, e0_Wih, st);
    gemm_k<3, 1024><<<512, 256, 0, stream>>>(r2, r1, W1b, W2b, e1_bih, e1_bhh,
                                             r0, nullptr, nullptr, ABUF, cls_W, st);
    u16* t0 = r2; u16* t1 = r0; u16* t2 = r1;
    r0 = t0; r1 = t1; r2 = t2;
  }
  // 7) arc gather
  k_arc<<<8192, 256, 0, stream>>>(out, ABUF);
}

// Round 19
// 1667.603 us; speedup vs baseline: 18.8847x; 1.0781x over previous
//
#include <hip/hip_runtime.h>
#include <math.h>

typedef unsigned int u32;
typedef unsigned short u16;
typedef unsigned long long u64;
typedef __attribute__((ext_vector_type(8))) short short8;
typedef __attribute__((ext_vector_type(4))) float f32x4;

__device__ inline float bf2f(u16 v) { return __uint_as_float(((u32)v) << 16); }
__device__ inline u16 f2bf(float f) {
  u32 u = __float_as_uint(f);
  return (u16)((u + 0x7fffu + ((u >> 16) & 1u)) >> 16);
}
__device__ inline float fast_tanh(float x) {
  x = fminf(9.0f, fmaxf(-9.0f, x));
  float e = __builtin_amdgcn_exp2f(x * 2.8853900817779268f);
  return (e - 1.0f) * __builtin_amdgcn_rcpf(e + 1.0f);
}
__device__ inline void gload16(const void* g, void* l) {
  __builtin_amdgcn_global_load_lds((const __attribute__((address_space(1))) u32*)g,
                                   (__attribute__((address_space(3))) u32*)l, 16, 0, 0);
}

// XCD-local tile mapping (128x128 tiles): row-panel m = blk&63 -> XCD m%8.
__device__ inline void tile_map(int blk, int& m0, int& n0) {
  n0 = (blk >> 6) << 7;     // 4 col-tiles (N=512)
  m0 = (blk & 63) << 7;     // 64 row-panels
}

// ======== prep kernels (range-dispatched merges) ========
__global__ void k_prep1(u16* __restrict__ xhi, u16* __restrict__ xlo,
                        const float* __restrict__ inp, const float* __restrict__ tag,
                        const float* __restrict__ sent,
                        u16* __restrict__ w0hi, u16* __restrict__ w0lo,
                        const float* __restrict__ g0wih,
                        float* __restrict__ wt0, const float* __restrict__ g0whh,
                        float* __restrict__ wt1, const float* __restrict__ g1whh,
                        u16* __restrict__ g1hi, u16* __restrict__ g1lo,
                        const float* __restrict__ g1wih) {
  int blk = blockIdx.x, t = threadIdx.x;
  if (blk < 32768) {                      // concat + split X
    int gid = blk * 256 + t;
    int row = gid >> 10, c = gid & 1023;
    int b = row >> 8, s = row & 255;
    float v;
    if (s == 0) v = sent[c];
    else if (c < 768) v = inp[(size_t)(b * 255 + s - 1) * 768 + c];
    else v = tag[(size_t)(b * 255 + s - 1) * 256 + (c - 768)];
    u16 h = f2bf(v);
    xhi[gid] = h;
    xlo[gid] = f2bf(v - bf2f(h));
  } else if (blk < 34816) {               // g0_Wih hi/lo split
    int i = (blk - 32768) * 256 + t;
    float v = g0wih[i];
    u16 h = f2bf(v);
    w0hi[i] = h;
    w0lo[i] = f2bf(v - bf2f(h));
  } else if (blk < 35840) {               // WT0 transpose
    int i = (blk - 34816) * 256 + t;
    int k = i & 511, tt = i >> 9;
    wt0[(size_t)k * 512 + tt] = g0whh[(size_t)tt * 512 + k];
  } else if (blk < 36864) {               // WT1 transpose
    int i = (blk - 35840) * 256 + t;
    int k = i & 511, tt = i >> 9;
    wt1[(size_t)k * 512 + tt] = g1whh[(size_t)tt * 512 + k];
  } else {                                // g1_Wih hi/lo split
    int i = (blk - 36864) * 256 + t;
    float v = g1wih[i];
    u16 h = f2bf(v);
    g1hi[i] = h;
    g1lo[i] = f2bf(v - bf2f(h));
  }
}

__global__ void k_prep2(u64* __restrict__ hbuf,
                        u16* __restrict__ w0b, const float* __restrict__ e0whh,
                        u16* __restrict__ w1b, const float* __restrict__ e1wih,
                        u16* __restrict__ w2b, const float* __restrict__ e1whh,
                        u16* __restrict__ w3b, const float* __restrict__ htw,
                        u16* __restrict__ w4b, const float* __restrict__ dtw,
                        float* __restrict__ abuf, const float* __restrict__ clsb) {
  int blk = blockIdx.x, t = threadIdx.x;
  if (blk < 128) {                        // syncinit
    int i = blk * 256 + t;
    int pos = i & 1023;
    hbuf[i] = (pos < 512) ? (1ull << 32) : 0ull;
  } else if (blk < 1152) {
    int i = (blk - 128) * 256 + t;  w0b[i] = f2bf(e0whh[i]);
  } else if (blk < 2176) {
    int i = (blk - 1152) * 256 + t; w1b[i] = f2bf(e1wih[i]);
  } else if (blk < 3200) {
    int i = (blk - 2176) * 256 + t; w2b[i] = f2bf(e1whh[i]);
  } else if (blk < 3712) {
    int i = (blk - 3200) * 256 + t; w3b[i] = f2bf(htw[i]);
  } else if (blk < 4224) {
    int i = (blk - 3712) * 256 + t; w4b[i] = f2bf(dtw[i]);
  } else {
    int i = (blk - 4224) * 256 + t;       // ainit
    if (i < 212992) abuf[i] = ((i % 26) == 0) ? 1.0f : clsb[0];
  }
}

__global__ void k_prep3(u64* __restrict__ hbuf, uint4* __restrict__ s1) {
  int blk = blockIdx.x, t = threadIdx.x;
  if (blk < 128) {
    int i = blk * 256 + t;
    int pos = i & 1023;
    hbuf[i] = (pos < 512) ? (1ull << 32) : 0ull;
  } else {
    s1[(size_t)(blk - 128) * 256 + t] = uint4{0u, 0u, 0u, 0u};
  }
}

// ======== multi-block g-RNN scan: tagged sync, fused epilogue, dbuf hls ========
// layer 0: writes Y0 hi/lo (o16a/o16b). layer 1: writes masked bf16 state (o16a).
__global__ __launch_bounds__(512, 1) void k_gscan_mb(
    const float* __restrict__ XW, const float* __restrict__ WT,
    const int* __restrict__ mask, int layer, u64* hbuf,
    u16* __restrict__ o16a, u16* __restrict__ o16b)
{
  __shared__ float hls[2][528];
  const int blk = blockIdx.x;
  const int b = blk >> 2, q = blk & 3;
  const int tid = threadIdx.x;
  const int lane = tid & 63;
  const int wv = tid >> 6;
  const int colL = wv * 16 + (lane & 15);
  const int p = (lane >> 4) & 3;
  const int c = (q << 7) + colL;
  const bool fin = (p == 0);
  float wreg[128];
#pragma unroll
  for (int i = 0; i < 128; ++i)
    wreg[i] = WT[(size_t)(p * 128 + i) * 512 + c];
  u64* hb = hbuf + b * 1024;

  for (int s = 0; s < 256; ++s) {
    float xwv = 0.f;
    size_t off = 0;
    if (fin) {
      off = (size_t)(b * 256 + s) * 512 + c;
      xwv = XW[off];
    }
    const u32 want = (u32)(s + 1);
    u64 v;
    do {
      v = __hip_atomic_load(&hb[(s & 1) * 512 + tid], __ATOMIC_RELAXED,
                            __HIP_MEMORY_SCOPE_AGENT);
    } while ((u32)(v >> 32) < want);
    hls[s & 1][(tid >> 7) * 132 + (tid & 127)] = __uint_as_float((u32)v);
    __syncthreads();
    const float* hk = &hls[s & 1][p * 132];
    float a0 = 0.f, a1 = 0.f, a2 = 0.f, a3 = 0.f;
#pragma unroll
    for (int i = 0; i < 128; i += 4) {
      a0 = fmaf(wreg[i],     hk[i],     a0);
      a1 = fmaf(wreg[i + 1], hk[i + 1], a1);
      a2 = fmaf(wreg[i + 2], hk[i + 2], a2);
      a3 = fmaf(wreg[i + 3], hk[i + 3], a3);
    }
    float r = (a0 + a1) + (a2 + a3);
    r += __shfl_xor(r, 16);
    r += __shfl_xor(r, 32);
    if (fin) {
      float h = tanhf(r + xwv);
      u64 pk = ((u64)(u32)(s + 2) << 32) | (u64)__float_as_uint(h);
      __hip_atomic_store(&hb[((s + 1) & 1) * 512 + c], pk,
                         __ATOMIC_RELAXED, __HIP_MEMORY_SCOPE_AGENT);
      if (layer) {
        float mv = (s == 0) ? 1.f : (float)mask[b * 255 + s - 1];
        o16a[off] = f2bf(h * mv);
      } else {
        u16 hi = f2bf(h);
        o16a[off] = hi;
        o16b[off] = f2bf(h - bf2f(hi));
      }
    }
    // no trailing barrier: hls is double-buffered (max skew = 1 step)
  }
}

// ======== Split-precision MFMA GEMM, 128x128 tiles ========
template<int KD>
__global__ __launch_bounds__(256, 2) void gemm_s(
    const u16* __restrict__ Ahi, const u16* __restrict__ Alo,
    const u16* __restrict__ Whi, const u16* __restrict__ Wlo,
    const float* __restrict__ b1, const float* __restrict__ b2,
    float* __restrict__ outf)
{
  __shared__ __attribute__((aligned(16))) u16 Ah[128 * 64];
  __shared__ __attribute__((aligned(16))) u16 Al[128 * 64];
  __shared__ __attribute__((aligned(16))) u16 Wh[128 * 64];
  __shared__ __attribute__((aligned(16))) u16 Wl[128 * 64];
  const int tid = threadIdx.x;
  const int lane = tid & 63, wid = tid >> 6;
  const int wr = wid >> 1, wc = wid & 1;
  int m0, n0;
  tile_map(blockIdx.x, m0, n0);
  const int rsub = lane >> 3;
  const int swz = (((lane & 7) ^ rsub) << 3);

  f32x4 zero4 = {0.f, 0.f, 0.f, 0.f};
  f32x4 acc[4][4];
#pragma unroll
  for (int i = 0; i < 4; ++i)
#pragma unroll
    for (int j = 0; j < 4; ++j) acc[i][j] = zero4;

  for (int kt = 0; kt < KD / 64; ++kt) {
    __syncthreads();
#pragma unroll
    for (int cc = 0; cc < 4; ++cc) {
      int row = wid * 32 + cc * 8 + rsub;
      size_t ga = (size_t)(m0 + row) * KD + kt * 64 + swz;
      size_t gw = (size_t)(n0 + row) * KD + kt * 64 + swz;
      gload16(Ahi + ga, &Ah[(wid * 32 + cc * 8) * 64]);
      gload16(Alo + ga, &Al[(wid * 32 + cc * 8) * 64]);
      gload16(Whi + gw, &Wh[(wid * 32 + cc * 8) * 64]);
      gload16(Wlo + gw, &Wl[(wid * 32 + cc * 8) * 64]);
    }
    __syncthreads();
#pragma unroll
    for (int ks = 0; ks < 2; ++ks) {
      short8 ah[4], al[4], wh[4], wl[4];
#pragma unroll
      for (int mm = 0; mm < 4; ++mm) {
        int row = wr * 64 + mm * 16 + (lane & 15);
        int kb = (ks * 64 + ((lane >> 4) << 4)) ^ ((row & 7) << 4);
        ah[mm] = *(const short8*)((const char*)Ah + row * 128 + kb);
        al[mm] = *(const short8*)((const char*)Al + row * 128 + kb);
      }
#pragma unroll
      for (int nn = 0; nn < 4; ++nn) {
        int row = wc * 64 + nn * 16 + (lane & 15);
        int kb = (ks * 64 + ((lane >> 4) << 4)) ^ ((row & 7) << 4);
        wh[nn] = *(const short8*)((const char*)Wh + row * 128 + kb);
        wl[nn] = *(const short8*)((const char*)Wl + row * 128 + kb);
      }
#pragma unroll
      for (int mm = 0; mm < 4; ++mm)
#pragma unroll
        for (int nn = 0; nn < 4; ++nn) {
          acc[mm][nn] = __builtin_amdgcn_mfma_f32_16x16x32_bf16(ah[mm], wh[nn], acc[mm][nn], 0, 0, 0);
          acc[mm][nn] = __builtin_amdgcn_mfma_f32_16x16x32_bf16(ah[mm], wl[nn], acc[mm][nn], 0, 0, 0);
          acc[mm][nn] = __builtin_amdgcn_mfma_f32_16x16x32_bf16(al[mm], wh[nn], acc[mm][nn], 0, 0, 0);
        }
    }
  }

  float bcol[4];
#pragma unroll
  for (int nn = 0; nn < 4; ++nn) {
    int col = n0 + wc * 64 + nn * 16 + (lane & 15);
    bcol[nn] = b1[col] + b2[col];
  }
#pragma unroll
  for (int mm = 0; mm < 4; ++mm)
#pragma unroll
    for (int r = 0; r < 4; ++r) {
      int grow = m0 + wr * 64 + mm * 16 + ((lane >> 4) << 2) + r;
#pragma unroll
      for (int nn = 0; nn < 4; ++nn) {
        int col = n0 + wc * 64 + nn * 16 + (lane & 15);
        outf[(size_t)grow * 512 + col] = acc[mm][nn][r] + bcol[nn];
      }
    }
}

// ======== bf16 MFMA GEMM modes 1/2/3, 128x128 tiles ========
template<int MODE, int KD>
__global__ __launch_bounds__(256, 2) void gemm_k(
    const u16* __restrict__ Ag, const u16* __restrict__ Ag2,
    const u16* __restrict__ Wg, const u16* __restrict__ W2g,
    const float* __restrict__ b1, const float* __restrict__ b2,
    u16* __restrict__ outb, float* __restrict__ outh, float* __restrict__ outd,
    float* __restrict__ abuf, const float* __restrict__ vecw, int estep)
{
  __shared__ __attribute__((aligned(16))) u16 As[128 * 64];
  __shared__ __attribute__((aligned(16))) u16 Ws[128 * 64];
  __shared__ float xes[128];
  const int tid = threadIdx.x;
  const int lane = tid & 63, wid = tid >> 6;
  const int wr = wid >> 1, wc = wid & 1;
  int m0, n0;
  tile_map(blockIdx.x, m0, n0);
  const int rsub = lane >> 3;
  const int swz = (((lane & 7) ^ rsub) << 3);

  if constexpr (MODE == 2) {
    if (tid < 128) xes[tid] = abuf[(size_t)(m0 + tid) * 26 + estep];
  }

  f32x4 zero4 = {0.f, 0.f, 0.f, 0.f};
  f32x4 acc[4][4];
#pragma unroll
  for (int i = 0; i < 4; ++i)
#pragma unroll
    for (int j = 0; j < 4; ++j) acc[i][j] = zero4;

  for (int kt = 0; kt < KD / 64; ++kt) {
    const u16* Asrc; int ka;
    if (kt < 8) { Asrc = Ag;  ka = kt; }
    else        { Asrc = Ag2; ka = kt - 8; }
    const u16* Wsrc; int kw, rowoff;
    if constexpr (MODE == 1) {
      if (n0 >= 256) { Wsrc = W2g; rowoff = n0 - 256; }
      else           { Wsrc = Wg;  rowoff = n0; }
      kw = kt;
    } else {
      if (kt < 8) { Wsrc = Wg;  kw = kt; }
      else        { Wsrc = W2g; kw = kt - 8; }
      rowoff = n0;
    }
    __syncthreads();
#pragma unroll
    for (int cc = 0; cc < 4; ++cc) {
      int row = wid * 32 + cc * 8 + rsub;
      gload16(Asrc + (size_t)(m0 + row) * 512 + ka * 64 + swz, &As[(wid * 32 + cc * 8) * 64]);
      gload16(Wsrc + (size_t)(rowoff + row) * 512 + kw * 64 + swz, &Ws[(wid * 32 + cc * 8) * 64]);
    }
    __syncthreads();
#pragma unroll
    for (int ks = 0; ks < 2; ++ks) {
      short8 af[4], wf[4];
#pragma unroll
      for (int mm = 0; mm < 4; ++mm) {
        int row = wr * 64 + mm * 16 + (lane & 15);
        int kb = (ks * 64 + ((lane >> 4) << 4)) ^ ((row & 7) << 4);
        af[mm] = *(const short8*)((const char*)As + row * 128 + kb);
      }
#pragma unroll
      for (int nn = 0; nn < 4; ++nn) {
        int row = wc * 64 + nn * 16 + (lane & 15);
        int kb = (ks * 64 + ((lane >> 4) << 4)) ^ ((row & 7) << 4);
        wf[nn] = *(const short8*)((const char*)Ws + row * 128 + kb);
      }
#pragma unroll
      for (int mm = 0; mm < 4; ++mm)
#pragma unroll
        for (int nn = 0; nn < 4; ++nn)
          acc[mm][nn] = __builtin_amdgcn_mfma_f32_16x16x32_bf16(af[mm], wf[nn], acc[mm][nn], 0, 0, 0);
    }
  }

  float bcol[4], vcol[4];
#pragma unroll
  for (int nn = 0; nn < 4; ++nn) {
    int col = n0 + wc * 64 + nn * 16 + (lane & 15);
    if constexpr (MODE == 1) bcol[nn] = (col < 256) ? b1[col] : b2[col - 256];
    else                     bcol[nn] = b1[col] + b2[col];
    vcol[nn] = 0.0f;
    if constexpr (MODE == 2 || MODE == 3) vcol[nn] = vecw[col];
  }
  float pp[4][4];
#pragma unroll
  for (int i = 0; i < 4; ++i)
#pragma unroll
    for (int j = 0; j < 4; ++j) pp[i][j] = 0.0f;

#pragma unroll
  for (int mm = 0; mm < 4; ++mm) {
#pragma unroll
    for (int r = 0; r < 4; ++r) {
      int lrow = wr * 64 + mm * 16 + ((lane >> 4) << 2) + r;
      int grow = m0 + lrow;
#pragma unroll
      for (int nn = 0; nn < 4; ++nn) {
        int col = n0 + wc * 64 + nn * 16 + (lane & 15);
        float v = acc[mm][nn][r] + bcol[nn];
        if constexpr (MODE == 1) {
          float e = v > 0.f ? v : (expf(v) - 1.f);
          if (col < 256) outh[(size_t)grow * 256 + col] = e;
          else           outd[(size_t)grow * 256 + (col - 256)] = e;
        } else if constexpr (MODE == 2) {
          v += xes[lrow] * vcol[nn];
          outb[(size_t)grow * 512 + col] = f2bf(fast_tanh(v));
        } else {
          float h = fast_tanh(v);
          outb[(size_t)grow * 512 + col] = f2bf(h);
          pp[mm][r] += h * vcol[nn];
        }
      }
    }
  }
  if constexpr (MODE == 3) {
#pragma unroll
    for (int mm = 0; mm < 4; ++mm)
#pragma unroll
      for (int r = 0; r < 4; ++r) {
        float p = pp[mm][r];
        p += __shfl_xor(p, 1); p += __shfl_xor(p, 2);
        p += __shfl_xor(p, 4); p += __shfl_xor(p, 8);
        if ((lane & 15) == 0) {
          int grow = m0 + wr * 64 + mm * 16 + ((lane >> 4) << 2) + r;
          atomicAdd(&abuf[(size_t)grow * 26 + estep + 1], p);
        }
      }
  }
}

// ---------------- small helpers ----------------
__global__ void k_arc(float* __restrict__ outp, const float* __restrict__ abuf) {
  int idx = blockIdx.x * 256 + threadIdx.x;     // 2097152
  int j = idx & 255, i = (idx >> 8) & 255, b = idx >> 16;
  int k = i - j;
  outp[idx] = (k >= 0 && k <= 25) ? abuf[(size_t)(b * 256 + i) * 26 + k] : 0.0f;
}
__global__ void k_diag(float* __restrict__ outp, float code, int n) {
  int idx = blockIdx.x * 256 + threadIdx.x;
  if (idx < n) outp[idx] = (idx == 0) ? code : 0.0f;
}

extern "C" void kernel_launch(void* const* d_in, const int* in_sizes, int n_in,
                              void* d_out, int out_size, void* d_ws, size_t ws_size,
                              hipStream_t stream) {
  static const int SZ[26] = {6266880, 2088960, 8160, 1024, 524288, 262144, 512, 512,
                             262144, 262144, 512, 512, 512, 262144, 512, 512,
                             262144, 262144, 512, 512, 512, 1, 131072, 256, 131072, 256};
  float diag_code = 0.0f;
  if (n_in != 26) diag_code = 4096.0f + (float)n_in;
  else {
    for (int j = 0; j < 26; ++j)
      if (in_sizes[j] != SZ[j]) { diag_code = 2048.0f + (float)j; break; }
  }
  const size_t NEED = (size_t)(32u << 20);
  if (ws_size < NEED && diag_code == 0.0f) diag_code = 8192.0f;
  if (diag_code != 0.0f) {
    k_diag<<<(out_size + 255) / 256, 256, 0, stream>>>((float*)d_out, diag_code, out_size);
    return;
  }

  const float* inp  = (const float*)d_in[0];
  const float* tag  = (const float*)d_in[1];
  const int*   mask = (const int*)d_in[2];
  const float* sent = (const float*)d_in[3];
  const float* g0_Wih = (const float*)d_in[4];
  const float* g0_Whh = (const float*)d_in[5];
  const float* g0_bih = (const float*)d_in[6];
  const float* g0_bhh = (const float*)d_in[7];
  const float* g1_Wih = (const float*)d_in[8];
  const float* g1_Whh = (const float*)d_in[9];
  const float* g1_bih = (const float*)d_in[10];
  const float* g1_bhh = (const float*)d_in[11];
  const float* e0_Wih = (const float*)d_in[12];
  const float* e0_Whh = (const float*)d_in[13];
  const float* e0_bih = (const float*)d_in[14];
  const float* e0_bhh = (const float*)d_in[15];
  const float* e1_Wih = (const float*)d_in[16];
  const float* e1_Whh = (const float*)d_in[17];
  const float* e1_bih = (const float*)d_in[18];
  const float* e1_bhh = (const float*)d_in[19];
  const float* cls_W  = (const float*)d_in[20];
  const float* cls_b  = (const float*)d_in[21];
  const float* ht_W   = (const float*)d_in[22];
  const float* ht_b   = (const float*)d_in[23];
  const float* dt_W   = (const float*)d_in[24];
  const float* dt_b   = (const float*)d_in[25];

  float* out = (float*)d_out;               // 24 MB: [arc | head | dep] f32
  char*  ob  = (char*)d_out;
  char*  ws  = (char*)d_ws;

  // ---- d_out overlays ----
  u16*  W0hi = (u16*)(ob);                  // [0,1M)
  u16*  W0lo = (u16*)(ob + (1u << 20));     // [1,2M)
  float* XW0 = (float*)(ob + (2u << 20));   // [2,18M) xW0 -> xW1
  float* WT0 = (float*)(ob + (18u << 20));  // [18,19M)
  float* WT1 = (float*)(ob + (19u << 20));  // [19,20M)
  u16*  G1hi = (u16*)(ob + (20u << 20));    // [20,20.5M)
  u16*  G1lo = (u16*)(ob + (20u << 20) + (512u << 10));
  // ---- ws overlays ----
  u16*  Xhi  = (u16*)(ws);                  // [0,16M)
  u16*  Xlo  = (u16*)(ws + (16u << 20));    // [16,32M)
  u16*  Y0hi = (u16*)(ws);                  // [0,8M)   (over Xhi, after X dead)
  u16*  Y0lo = (u16*)(ws + (8u << 20));     // [8,16M)
  u16*  S0   = Y0hi;
  u16*  S1   = Y0lo;
  u16*  S2   = (u16*)(ws + (16u << 20));    // [16,24M)
  float* ABUF = (float*)(ws + (24u << 20)); // 852 KB
  u16*  W0b  = (u16*)(ws + (25u << 20));
  u16*  W1b  = (u16*)(ws + (25u << 20) + (512u << 10));
  u16*  W2b  = (u16*)(ws + (26u << 20));
  u16*  W3b  = (u16*)(ws + (26u << 20) + (512u << 10));
  u16*  W4b  = (u16*)(ws + (26u << 20) + (768u << 10));
  u64*  HBUF = (u64*)(ws + (28u << 20));    // [32][2][512] u64

  // 1) prep1: concat+split X, g0_Wih split, WT0/WT1 transposes, g1_Wih split
  k_prep1<<<37888, 256, 0, stream>>>(Xhi, Xlo, inp, tag, sent,
                                     W0hi, W0lo, g0_Wih, WT0, g0_Whh, WT1, g1_Whh,
                                     G1hi, G1lo, g1_Wih);
  // 2) xW0 -> XW0
  gemm_s<1024><<<256, 256, 0, stream>>>(Xhi, Xlo, W0hi, W0lo, g0_bih, g0_bhh, XW0);
  // 3) prep2: syncinit + edge/head weight cvts + ainit (X dead after gemm_s)
  k_prep2<<<5056, 256, 0, stream>>>(HBUF, W0b, e0_Whh, W1b, e1_Wih, W2b, e1_Whh,
                                    W3b, ht_W, W4b, dt_W, ABUF, cls_b);
  // 4) scan0 (fused Y0 hi/lo epilogue)
  k_gscan_mb<<<128, 512, 0, stream>>>(XW0, WT0, mask, 0, HBUF, Y0hi, Y0lo);
  // 5) xW1 -> XW0
  gemm_s<512><<<256, 256, 0, stream>>>(Y0hi, Y0lo, G1hi, G1lo, g1_bih, g1_bhh, XW0);
  // 6) prep3: syncinit reset + S1 zero
  k_prep3<<<2176, 256, 0, stream>>>(HBUF, (uint4*)S1);
  // 7) scan1 (fused masked-bf16 epilogue -> S0)
  k_gscan_mb<<<128, 512, 0, stream>>>(XW0, WT1, mask, 1, HBUF, S0, nullptr);
  // 8) tag heads -> f32 head/dep in d_out (XW0 dead)
  gemm_k<1, 512><<<256, 256, 0, stream>>>(S0, nullptr, W3b, W4b, ht_b, dt_b,
                                          nullptr, out + 2097152, out + 4194304,
                                          nullptr, nullptr, 0);
  // 9) edge scan: 25 x (E0, E1), triple-buffer rotation
  u16* r0 = S0; u16* r1 = S1; u16* r2 = S2;
  for (int st = 0; st < 25; ++st) {
    gemm_k<2, 512><<<256, 256, 0, stream>>>(r0, nullptr, W0b, nullptr, e0_bih, e0_bhh,
                                            r2, nullptr, nullptr, ABUF, e0_Wih, st);
    gemm_k<3, 1024><<<256, 256, 0, stream>>>(r2, r1, W1b, W2b, e1_bih, e1_bhh,
                                             r0, nullptr, nullptr, ABUF, cls_W, st);
    u16* t0 = r2; u16* t1 = r0; u16* t2 = r1;
    r0 = t0; r1 = t1; r2 = t2;
  }
  // 10) arc gather
  k_arc<<<8192, 256, 0, stream>>>(out, ABUF);
}